// Round 1
// baseline (2951.610 us; speedup 1.0000x reference)
//
#include <hip/hip_runtime.h>
#include <math.h>

constexpr int Nn  = 4096;
constexpr int Ne  = 32768;
constexpr int NEf = Ne + Nn;     // real edges + self loops

// ---------------- ws layout (float offsets) ----------------
constexpr size_t OFF_X   = 0;            // [N,512]     concat input
constexpr size_t OFF_Z1  = 2097152;      // [N,4,512]   layer1 aggregated input-space
constexpr size_t OFF_Z2H = 2097152;      // [N,2048]    per-head layer2 agg (overlays z1, dead by then)
constexpr size_t OFF_X2  = 10485760;     // [N,2048]    layer1 output
constexpr size_t OFF_X3H = 18874368;     // [N,2048]    per-head layer2 output
constexpr size_t OFF_YP  = 27262976;     // 4 x [N,256] fc split-K partials
constexpr size_t OFF_LP  = 31457280;     // [N,16]      self-loop edge attr
constexpr size_t OFF_WS1 = OFF_LP  + 65536;   // [512,4]
constexpr size_t OFF_WD1 = OFF_WS1 + 2048;    // [512,4]
constexpr size_t OFF_WS2 = OFF_WD1 + 2048;    // [2048,4]
constexpr size_t OFF_WD2 = OFF_WS2 + 8192;    // [2048,4]
constexpr size_t OFF_AE1 = OFF_WD2 + 8192;    // [16,4]
constexpr size_t OFF_AE2 = OFF_AE1 + 64;      // [16,4]
constexpr size_t OFF_AS1 = OFF_AE2 + 64;      // [N,4]
constexpr size_t OFF_AD1 = OFF_AS1 + 16384;
constexpr size_t OFF_AS2 = OFF_AD1 + 16384;
constexpr size_t OFF_AD2 = OFF_AS2 + 16384;
constexpr size_t OFF_EB  = OFF_AD2 + 16384;          // [Ef,4] logits
constexpr size_t OFF_AL  = OFF_EB  + (size_t)NEf*4;  // [Ef,4] alpha
constexpr size_t OFF_I   = OFF_AL  + (size_t)NEf*4;  // int region
// int offsets within (int*)(ws + OFF_I)
constexpr size_t I_DEG = 0;       // [N]
constexpr size_t I_RP  = 4096;    // [N+1] (+pad)
constexpr size_t I_CUR = 8200;    // [N]
constexpr size_t I_EID = 12296;   // [Ef]
constexpr size_t WS_FLOATS = OFF_I + I_EID + (size_t)NEf + 64;

__device__ __forceinline__ float wred64(float v){
#pragma unroll
  for (int o = 32; o > 0; o >>= 1) v += __shfl_down(v, o, 64);
  return v;
}
__device__ __forceinline__ float lrelu(float v, float s){ return v > 0.f ? v : s * v; }

// ---------------- small prep kernels ----------------
__global__ void k_concat(const float* __restrict__ xg, const float* __restrict__ ac,
                         const float* __restrict__ ti, float* __restrict__ x){
  int i = blockIdx.x * 256 + threadIdx.x;          // over N*512
  int n = i >> 9, c = i & 511;
  float v;
  if (c < 256)      v = xg[(size_t)n*256 + c];
  else if (c < 384) v = ac[(size_t)n*128 + (c-256)];
  else              v = ti[(size_t)n*128 + (c-384)];
  x[i] = v;
}

__global__ void k_count(const int* __restrict__ ei, int* __restrict__ deg){
  int e = blockIdx.x * 256 + threadIdx.x;
  if (e < Ne) atomicAdd(&deg[ei[Ne + e]], 1);
}

__global__ void k_scan(const int* __restrict__ deg, int* __restrict__ rowptr, int* __restrict__ cursor){
  __shared__ int sd[1024];
  int t = threadIdx.x;
  int v[4]; int s = 0;
#pragma unroll
  for (int i = 0; i < 4; i++){ v[i] = s; s += deg[t*4 + i] + 1; }   // +1 self loop
  sd[t] = s;
  __syncthreads();
  for (int off = 1; off < 1024; off <<= 1){
    int x = (t >= off) ? sd[t - off] : 0;
    __syncthreads();
    sd[t] += x;
    __syncthreads();
  }
  int base = (t == 0) ? 0 : sd[t - 1];
#pragma unroll
  for (int i = 0; i < 4; i++){ int rp = base + v[i]; rowptr[t*4 + i] = rp; cursor[t*4 + i] = rp; }
  if (t == 1023) rowptr[4096] = sd[1023];
}

__global__ void k_fill(const int* __restrict__ ei, int* __restrict__ cursor, int* __restrict__ eids){
  int e = blockIdx.x * 256 + threadIdx.x;
  if (e >= NEf) return;
  int d = (e < Ne) ? ei[Ne + e] : (e - Ne);
  int p = atomicAdd(&cursor[d], 1);
  eids[p] = e;
}

__global__ void k_sort(const int* __restrict__ rowptr, int* __restrict__ eids){
  int n = blockIdx.x * 256 + threadIdx.x;
  if (n >= Nn) return;
  int b = rowptr[n], e = rowptr[n + 1];
  for (int i = b + 1; i < e; i++){
    int key = eids[i]; int j = i - 1;
    while (j >= b && eids[j] > key){ eids[j+1] = eids[j]; j--; }
    eids[j+1] = key;
  }
}

__global__ void k_loopattr(const float* __restrict__ eattr, const int* __restrict__ rowptr,
                           const int* __restrict__ eids, float* __restrict__ lp){
  int idx = blockIdx.x * 256 + threadIdx.x;        // N*16
  int n = idx >> 4, a = idx & 15;
  if (n >= Nn) return;
  int b = rowptr[n], e = rowptr[n + 1];
  float s = 0.f; int cnt = 0;
  for (int j = b; j < e; ++j){
    int id = eids[j];
    if (id < Ne){ s += eattr[(size_t)id*16 + a]; cnt++; }
  }
  lp[(size_t)n*16 + a] = s / fmaxf((float)cnt, 1.f);
}

// Ws[k,h] = sum_c W[k, h*C+c]*a_s[h,c] ; Wd likewise. One wave per (k,h); blocks = K.
__global__ void k_proj(const float* __restrict__ W, const float* __restrict__ a_s,
                       const float* __restrict__ a_d, float* __restrict__ Ws,
                       float* __restrict__ Wd, int K, int C){
  int gid = blockIdx.x * 256 + threadIdx.x;
  int wave = gid >> 6, lane = gid & 63;
  int h = wave & 3, k = wave >> 2;
  if (k >= K) return;
  const float* wrow = W + (size_t)k * (4*C) + (size_t)h * C;
  const float* ar = a_s + (size_t)h * C;
  const float* dr = a_d + (size_t)h * C;
  float ps = 0.f, pd = 0.f;
  for (int c = lane; c < C; c += 64){ float w = wrow[c]; ps += w * ar[c]; pd += w * dr[c]; }
  ps = wred64(ps); pd = wred64(pd);
  if (lane == 0){ Ws[k*4 + h] = ps; Wd[k*4 + h] = pd; }
}

__global__ void k_aeproj(const float* __restrict__ We, const float* __restrict__ ae,
                         float* __restrict__ outp, int C){
  int t = threadIdx.x;           // 64 threads: k=t>>2, h=t&3
  int k = t >> 2, h = t & 3;
  const float* wrow = We + (size_t)k * (4*C) + (size_t)h * C;
  const float* ar = ae + (size_t)h * C;
  float s = 0.f;
  for (int c = 0; c < C; c++) s += wrow[c] * ar[c];
  outp[k*4 + h] = s;
}

// as[n,h], ad[n,h] = x[n,:] @ Ws/Wd. Block per node.
__global__ __launch_bounds__(256) void k_asad(const float* __restrict__ x, const float* __restrict__ Ws,
                      const float* __restrict__ Wd, float* __restrict__ as_,
                      float* __restrict__ ad_, int D){
  int n = blockIdx.x, t = threadIdx.x;
  const float* row = x + (size_t)n * D;
  float p[8] = {0,0,0,0,0,0,0,0};
  for (int c = t; c < D; c += 256){
    float xv = row[c];
    float4 ws4 = *(const float4*)&Ws[c*4];
    float4 wd4 = *(const float4*)&Wd[c*4];
    p[0] += xv * ws4.x; p[1] += xv * ws4.y; p[2] += xv * ws4.z; p[3] += xv * ws4.w;
    p[4] += xv * wd4.x; p[5] += xv * wd4.y; p[6] += xv * wd4.z; p[7] += xv * wd4.w;
  }
  __shared__ float sm[4][8];
  int lane = t & 63, wid = t >> 6;
#pragma unroll
  for (int q = 0; q < 8; q++){
    float v = wred64(p[q]);
    if (lane == 0) sm[wid][q] = v;
  }
  __syncthreads();
  if (t < 8){
    float s = sm[0][t] + sm[1][t] + sm[2][t] + sm[3][t];
    if (t < 4) as_[(size_t)n*4 + t] = s;
    else       ad_[(size_t)n*4 + (t-4)] = s;
  }
}

__global__ void k_edge(const float* __restrict__ eattr, const float* __restrict__ lp,
                       const int* __restrict__ ei, const float* __restrict__ as_,
                       const float* __restrict__ ad_, const float* __restrict__ aep,
                       float* __restrict__ ebuf){
  int e = blockIdx.x * 256 + threadIdx.x;
  if (e >= NEf) return;
  int s, d; const float* ea;
  if (e < Ne){ s = ei[e]; d = ei[Ne + e]; ea = eattr + (size_t)e * 16; }
  else { s = e - Ne; d = e - Ne; ea = lp + (size_t)(e - Ne) * 16; }
  float eav[16];
#pragma unroll
  for (int k = 0; k < 16; k++) eav[k] = ea[k];
#pragma unroll
  for (int h = 0; h < 4; h++){
    float v = as_[(size_t)s*4 + h] + ad_[(size_t)d*4 + h];
#pragma unroll
    for (int k = 0; k < 16; k++) v += eav[k] * aep[k*4 + h];
    ebuf[(size_t)e*4 + h] = lrelu(v, 0.2f);
  }
}

__global__ void k_softmax(const int* __restrict__ rowptr, const int* __restrict__ eids,
                          const float* __restrict__ ebuf, float* __restrict__ alpha){
  int n = blockIdx.x * 256 + threadIdx.x;
  if (n >= Nn) return;
  int b = rowptr[n], e = rowptr[n + 1];
#pragma unroll
  for (int h = 0; h < 4; h++){
    float m = -1e30f;
    for (int j = b; j < e; ++j) m = fmaxf(m, ebuf[(size_t)eids[j]*4 + h]);
    float ss = 0.f;
    for (int j = b; j < e; ++j){
      float ex = expf(ebuf[(size_t)eids[j]*4 + h] - m);
      alpha[(size_t)eids[j]*4 + h] = ex; ss += ex;
    }
    for (int j = b; j < e; ++j) alpha[(size_t)eids[j]*4 + h] /= ss;
  }
}

// z1[n,h,0:512] = sum_e alpha[e,h] * x[src(e),:]   (block per dst node)
__global__ __launch_bounds__(256) void k_agg1(const float* __restrict__ x, const float* __restrict__ alpha,
                      const int* __restrict__ rowptr, const int* __restrict__ eids,
                      const int* __restrict__ ei, float* __restrict__ z1){
  int n = blockIdx.x, t = threadIdx.x;
  float2 a0 = {0,0}, a1 = {0,0}, a2 = {0,0}, a3 = {0,0};
  int b = rowptr[n], e = rowptr[n + 1];
  for (int j = b; j < e; ++j){
    int eid = eids[j];
    int s = (eid < Ne) ? ei[eid] : (eid - Ne);
    float4 av = *(const float4*)&alpha[(size_t)eid*4];
    float2 xv = *(const float2*)&x[(size_t)s*512 + t*2];
    a0.x += av.x*xv.x; a0.y += av.x*xv.y;
    a1.x += av.y*xv.x; a1.y += av.y*xv.y;
    a2.x += av.z*xv.x; a2.y += av.z*xv.y;
    a3.x += av.w*xv.x; a3.y += av.w*xv.y;
  }
  size_t base = (size_t)n*2048 + t*2;
  *(float2*)&z1[base +    0] = a0;
  *(float2*)&z1[base +  512] = a1;
  *(float2*)&z1[base + 1024] = a2;
  *(float2*)&z1[base + 1536] = a3;
}

// z2h[n,0:2048] = sum_e alpha[e,h] * x2[src(e),:]  for ONE head h
__global__ __launch_bounds__(256) void k_agg2h(const float* __restrict__ x2, const float* __restrict__ alpha,
                       const int* __restrict__ rowptr, const int* __restrict__ eids,
                       const int* __restrict__ ei, float* __restrict__ z2h, int h){
  int n = blockIdx.x, t = threadIdx.x;
  float4 acc0 = {0,0,0,0}, acc1 = {0,0,0,0};
  int b = rowptr[n], e = rowptr[n + 1];
  for (int j = b; j < e; ++j){
    int eid = eids[j];
    int s = (eid < Ne) ? ei[eid] : (eid - Ne);
    float a = alpha[(size_t)eid*4 + h];
    const float* xr = x2 + (size_t)s*2048 + t*8;
    float4 xa = *(const float4*)xr;
    float4 xb = *(const float4*)(xr + 4);
    acc0.x += a*xa.x; acc0.y += a*xa.y; acc0.z += a*xa.z; acc0.w += a*xa.w;
    acc1.x += a*xb.x; acc1.y += a*xb.y; acc1.z += a*xb.z; acc1.w += a*xb.w;
  }
  size_t base = (size_t)n*2048 + t*8;
  *(float4*)&z2h[base]     = acc0;
  *(float4*)&z2h[base + 4] = acc1;
}

// ---------------- fp32 tiled GEMM: C[z] = op(A[z] @ B[z] (+bias)(+C_old)) ----------------
template<int ACT, bool HASBIAS, bool BETA1>
__global__ __launch_bounds__(256) void k_gemm(
    const float* __restrict__ A, int lda, size_t az,
    const float* __restrict__ B, int ldb, size_t bz,
    float* __restrict__ C, int ldc, size_t cz,
    const float* __restrict__ bias, int biasz, int K)
{
  constexpr int BM = 128, BN = 128, BK = 16, TM = 8, TN = 8;
  __shared__ float As[BK][BM + 4];
  __shared__ float Bs[BK][BN + 4];
  const int z = blockIdx.z;
  A += (size_t)z * az; B += (size_t)z * bz; C += (size_t)z * cz;
  const int brow = blockIdx.y * BM, bcol = blockIdx.x * BN;
  const int tid = threadIdx.x;
  const int tx = tid & 15, ty = tid >> 4;
  const int ar = tid >> 2, ac4 = (tid & 3) * 4;
  const int br = tid >> 5, bc4 = (tid & 31) * 4;
  float acc[TM][TN] = {};

  for (int kt = 0; kt < K; kt += BK){
#pragma unroll
    for (int rr = 0; rr < BM; rr += 64){
      float4 v = *(const float4*)&A[(size_t)(brow + ar + rr) * lda + kt + ac4];
      As[ac4 + 0][ar + rr] = v.x; As[ac4 + 1][ar + rr] = v.y;
      As[ac4 + 2][ar + rr] = v.z; As[ac4 + 3][ar + rr] = v.w;
    }
#pragma unroll
    for (int rr = 0; rr < BK; rr += 8){
      *(float4*)&Bs[br + rr][bc4] = *(const float4*)&B[(size_t)(kt + br + rr) * ldb + bcol + bc4];
    }
    __syncthreads();
#pragma unroll
    for (int k = 0; k < BK; k++){
      float af[TM], bf[TN];
#pragma unroll
      for (int i = 0; i < TM; i++) af[i] = As[k][ty*TM + i];
#pragma unroll
      for (int j = 0; j < TN; j++) bf[j] = Bs[k][tx*TN + j];
#pragma unroll
      for (int i = 0; i < TM; i++)
#pragma unroll
        for (int j = 0; j < TN; j++) acc[i][j] = fmaf(af[i], bf[j], acc[i][j]);
    }
    __syncthreads();
  }
#pragma unroll
  for (int i = 0; i < TM; i++){
    const int row = brow + ty*TM + i;
#pragma unroll
    for (int j = 0; j < TN; j += 4){
      const int col = bcol + tx*TN + j;
      float4 v = { acc[i][j], acc[i][j+1], acc[i][j+2], acc[i][j+3] };
      if (HASBIAS){
        v.x += bias[(size_t)z*biasz + col + 0]; v.y += bias[(size_t)z*biasz + col + 1];
        v.z += bias[(size_t)z*biasz + col + 2]; v.w += bias[(size_t)z*biasz + col + 3];
      }
      if (ACT == 1){
        v.x = lrelu(v.x, 0.01f); v.y = lrelu(v.y, 0.01f);
        v.z = lrelu(v.z, 0.01f); v.w = lrelu(v.w, 0.01f);
      }
      float* cp = &C[(size_t)row * ldc + col];
      if (BETA1){
        float4 o = *(const float4*)cp;
        v.x += o.x; v.y += o.y; v.z += o.z; v.w += o.w;
      }
      *(float4*)cp = v;
    }
  }
}

// final: y = leaky(sum_z ypart[z] + bout); per-graph mean over sorted batch
__global__ void k_final(const float* __restrict__ yp, const float* __restrict__ bout,
                        const int* __restrict__ batch, float* __restrict__ out){
  const int g = blockIdx.x, t = threadIdx.x;
  __shared__ int sb[2];
  if (t < 2){
    int key = g + t, lo = 0, hi = Nn;
    while (lo < hi){ int mid = (lo + hi) >> 1; if (batch[mid] < key) lo = mid + 1; else hi = mid; }
    sb[t] = lo;
  }
  __syncthreads();
  const int b = sb[0], e = sb[1];
  const size_t P = (size_t)Nn * 256;
  float s = 0.f;
  for (int n = b; n < e; ++n){
    size_t i = (size_t)n*256 + t;
    float v = yp[i] + yp[P + i] + yp[2*P + i] + yp[3*P + i] + bout[t];
    s += lrelu(v, 0.01f);
  }
  out[g*256 + t] = s / fmaxf((float)(e - b), 1.f);
}

// ---------------- launch ----------------
extern "C" void kernel_launch(void* const* d_in, const int* in_sizes, int n_in,
                              void* d_out, int out_size, void* d_ws, size_t ws_size,
                              hipStream_t stream){
  const float* xg    = (const float*)d_in[0];
  const float* ac    = (const float*)d_in[1];
  const float* ti    = (const float*)d_in[2];
  const float* eattr = (const float*)d_in[3];
  const int*   ei    = (const int*)  d_in[4];
  const int*   batch = (const int*)  d_in[5];
  const float* W1    = (const float*)d_in[6];
  const float* as1w  = (const float*)d_in[7];
  const float* ad1w  = (const float*)d_in[8];
  const float* ae1w  = (const float*)d_in[9];
  const float* We1   = (const float*)d_in[10];
  const float* b1    = (const float*)d_in[11];
  const float* W2    = (const float*)d_in[12];
  const float* as2w  = (const float*)d_in[13];
  const float* ad2w  = (const float*)d_in[14];
  const float* ae2w  = (const float*)d_in[15];
  const float* We2   = (const float*)d_in[16];
  const float* b2    = (const float*)d_in[17];
  const float* Wout  = (const float*)d_in[18];
  const float* bout  = (const float*)d_in[19];
  float* out = (float*)d_out;
  float* ws  = (float*)d_ws;
  if (ws_size < WS_FLOATS * sizeof(float)) return;  // fail visibly (absmax) rather than corrupt
  int* iws = (int*)(ws + OFF_I);

  hipMemsetAsync(iws + I_DEG, 0, Nn * sizeof(int), stream);
  k_concat <<<8192, 256, 0, stream>>>(xg, ac, ti, ws + OFF_X);
  k_count  <<<128,  256, 0, stream>>>(ei, iws + I_DEG);
  k_scan   <<<1,   1024, 0, stream>>>(iws + I_DEG, iws + I_RP, iws + I_CUR);
  k_fill   <<<144,  256, 0, stream>>>(ei, iws + I_CUR, iws + I_EID);
  k_sort   <<<16,   256, 0, stream>>>(iws + I_RP, iws + I_EID);
  k_loopattr<<<256, 256, 0, stream>>>(eattr, iws + I_RP, iws + I_EID, ws + OFF_LP);

  k_proj   <<<512,  256, 0, stream>>>(W1, as1w, ad1w, ws + OFF_WS1, ws + OFF_WD1, 512, 512);
  k_proj   <<<2048, 256, 0, stream>>>(W2, as2w, ad2w, ws + OFF_WS2, ws + OFF_WD2, 2048, 2048);
  k_aeproj <<<1,     64, 0, stream>>>(We1, ae1w, ws + OFF_AE1, 512);
  k_aeproj <<<1,     64, 0, stream>>>(We2, ae2w, ws + OFF_AE2, 2048);

  // ---- layer 1 ----
  k_asad   <<<4096, 256, 0, stream>>>(ws + OFF_X, ws + OFF_WS1, ws + OFF_WD1, ws + OFF_AS1, ws + OFF_AD1, 512);
  k_edge   <<<144,  256, 0, stream>>>(eattr, ws + OFF_LP, ei, ws + OFF_AS1, ws + OFF_AD1, ws + OFF_AE1, ws + OFF_EB);
  k_softmax<<<16,   256, 0, stream>>>(iws + I_RP, iws + I_EID, ws + OFF_EB, ws + OFF_AL);
  k_agg1   <<<4096, 256, 0, stream>>>(ws + OFF_X, ws + OFF_AL, iws + I_RP, iws + I_EID, ei, ws + OFF_Z1);
  k_gemm<1, true, false><<<dim3(4, 32, 4), 256, 0, stream>>>(
      ws + OFF_Z1, 2048, 512,  W1, 2048, 512,  ws + OFF_X2, 2048, 512,  b1, 512, 512);

  // ---- layer 2 attention ----
  k_asad   <<<4096, 256, 0, stream>>>(ws + OFF_X2, ws + OFF_WS2, ws + OFF_WD2, ws + OFF_AS2, ws + OFF_AD2, 2048);
  k_edge   <<<144,  256, 0, stream>>>(eattr, ws + OFF_LP, ei, ws + OFF_AS2, ws + OFF_AD2, ws + OFF_AE2, ws + OFF_EB);
  k_softmax<<<16,   256, 0, stream>>>(iws + I_RP, iws + I_EID, ws + OFF_EB, ws + OFF_AL);

  // ---- layer 2 + fc, per head (keeps ws small) ----
  for (int h = 0; h < 4; ++h){
    k_agg2h<<<4096, 256, 0, stream>>>(ws + OFF_X2, ws + OFF_AL, iws + I_RP, iws + I_EID, ei, ws + OFF_Z2H, h);
    k_gemm<1, true, false><<<dim3(16, 32, 1), 256, 0, stream>>>(
        ws + OFF_Z2H, 2048, 0,  W2 + (size_t)h*2048, 8192, 0,
        ws + OFF_X3H, 2048, 0,  b2 + (size_t)h*2048, 0, 2048);
    if (h == 0)
      k_gemm<0, false, false><<<dim3(2, 32, 4), 256, 0, stream>>>(
          ws + OFF_X3H, 2048, 512,  Wout + (size_t)h*2048*256, 256, (size_t)512*256,
          ws + OFF_YP, 256, (size_t)Nn*256,  nullptr, 0, 512);
    else
      k_gemm<0, false, true><<<dim3(2, 32, 4), 256, 0, stream>>>(
          ws + OFF_X3H, 2048, 512,  Wout + (size_t)h*2048*256, 256, (size_t)512*256,
          ws + OFF_YP, 256, (size_t)Nn*256,  nullptr, 0, 512);
  }

  k_final<<<8, 256, 0, stream>>>(ws + OFF_YP, bout, batch, out);
}

// Round 2
// 1720.004 us; speedup vs baseline: 1.7160x; 1.7160x over previous
//
#include <hip/hip_runtime.h>
#include <math.h>

constexpr int Nn  = 4096;
constexpr int Ne  = 32768;
constexpr int NEf = Ne + Nn;     // real edges + self loops

// ---------------- ws layout (float offsets) ----------------
// region reuse:
//   [0..2097152)          X fp32 (prep/L1)          -> wh_hi bf16 [2048n][2048k] (L2 loop)
//   [2097152..10485760)   Z1 fp32 (L1)              -> zh_hi/zh_lo bf16 [4096][2048] (L2 loop)
//   [10485760..18874368)  X2 fp32
//   [18874368..23068672)  x3h bf16 [4096][2048]
//   [23068672..25165824)  wh_lo bf16
//   [27262976..31457280)  YP 4x[4096][256] fp32
constexpr size_t OFF_X   = 0;
constexpr size_t OFF_Z1  = 2097152;
constexpr size_t OFF_ZHI = 2097152;      // ushort* region
constexpr size_t OFF_ZLO = 6291456;      // ushort* region
constexpr size_t OFF_X2  = 10485760;
constexpr size_t OFF_X3H = 18874368;     // ushort* region (bf16)
constexpr size_t OFF_WLO = 23068672;     // ushort* region
constexpr size_t OFF_YP  = 27262976;
constexpr size_t OFF_LP  = 31457280;     // [N,16] self-loop edge attr
constexpr size_t OFF_WS1 = OFF_LP  + 65536;   // [512,4]
constexpr size_t OFF_WD1 = OFF_WS1 + 2048;    // [512,4]
constexpr size_t OFF_WS2 = OFF_WD1 + 2048;    // [2048,4]
constexpr size_t OFF_WD2 = OFF_WS2 + 8192;    // [2048,4]
constexpr size_t OFF_AE1 = OFF_WD2 + 8192;    // [16,4]
constexpr size_t OFF_AE2 = OFF_AE1 + 64;      // [16,4]
constexpr size_t OFF_AS1 = OFF_AE2 + 64;      // [N,4]
constexpr size_t OFF_AD1 = OFF_AS1 + 16384;
constexpr size_t OFF_AS2 = OFF_AD1 + 16384;
constexpr size_t OFF_AD2 = OFF_AS2 + 16384;
constexpr size_t OFF_EB  = OFF_AD2 + 16384;          // [Ef,4] logits
constexpr size_t OFF_AL  = OFF_EB  + (size_t)NEf*4;  // [Ef,4] alpha
constexpr size_t OFF_I   = OFF_AL  + (size_t)NEf*4;  // int region
constexpr size_t I_DEG = 0;       // [N]
constexpr size_t I_RP  = 4096;    // [N+1] (+pad)
constexpr size_t I_CUR = 8200;    // [N]
constexpr size_t I_EID = 12296;   // [Ef]
constexpr size_t WS_FLOATS = OFF_I + I_EID + (size_t)NEf + 64;

using bf16x8 = __bf16 __attribute__((ext_vector_type(8)));
using f32x4  = float __attribute__((ext_vector_type(4)));

__device__ __forceinline__ float wred64(float v){
#pragma unroll
  for (int o = 32; o > 0; o >>= 1) v += __shfl_down(v, o, 64);
  return v;
}
__device__ __forceinline__ float lrelu(float v, float s){ return v > 0.f ? v : s * v; }

__device__ __forceinline__ unsigned short f2bf(float x){  // RTNE
  unsigned int u = __float_as_uint(x);
  unsigned int r = (u + 0x7FFFu + ((u >> 16) & 1u)) >> 16;
  return (unsigned short)r;
}
__device__ __forceinline__ float bf2f(unsigned short h){
  return __uint_as_float((unsigned int)h << 16);
}
__device__ __forceinline__ void split2(float x, unsigned short& h, unsigned short& l){
  h = f2bf(x);
  l = f2bf(x - bf2f(h));
}
__device__ __forceinline__ void gload16(const void* g, void* l){
  __builtin_amdgcn_global_load_lds((const __attribute__((address_space(1))) void*)g,
                                   (__attribute__((address_space(3))) void*)l, 16, 0, 0);
}

// ---------------- small prep kernels ----------------
__global__ void k_concat(const float* __restrict__ xg, const float* __restrict__ ac,
                         const float* __restrict__ ti, float* __restrict__ x){
  int i = blockIdx.x * 256 + threadIdx.x;          // over N*512
  int n = i >> 9, c = i & 511;
  float v;
  if (c < 256)      v = xg[(size_t)n*256 + c];
  else if (c < 384) v = ac[(size_t)n*128 + (c-256)];
  else              v = ti[(size_t)n*128 + (c-384)];
  x[i] = v;
}

__global__ void k_count(const int* __restrict__ ei, int* __restrict__ deg){
  int e = blockIdx.x * 256 + threadIdx.x;
  if (e < Ne) atomicAdd(&deg[ei[Ne + e]], 1);
}

__global__ void k_scan(const int* __restrict__ deg, int* __restrict__ rowptr, int* __restrict__ cursor){
  __shared__ int sd[1024];
  int t = threadIdx.x;
  int v[4]; int s = 0;
#pragma unroll
  for (int i = 0; i < 4; i++){ v[i] = s; s += deg[t*4 + i] + 1; }   // +1 self loop
  sd[t] = s;
  __syncthreads();
  for (int off = 1; off < 1024; off <<= 1){
    int x = (t >= off) ? sd[t - off] : 0;
    __syncthreads();
    sd[t] += x;
    __syncthreads();
  }
  int base = (t == 0) ? 0 : sd[t - 1];
#pragma unroll
  for (int i = 0; i < 4; i++){ int rp = base + v[i]; rowptr[t*4 + i] = rp; cursor[t*4 + i] = rp; }
  if (t == 1023) rowptr[4096] = sd[1023];
}

__global__ void k_fill(const int* __restrict__ ei, int* __restrict__ cursor, int* __restrict__ eids){
  int e = blockIdx.x * 256 + threadIdx.x;
  if (e >= NEf) return;
  int d = (e < Ne) ? ei[Ne + e] : (e - Ne);
  int p = atomicAdd(&cursor[d], 1);
  eids[p] = e;
}

__global__ void k_sort(const int* __restrict__ rowptr, int* __restrict__ eids){
  int n = blockIdx.x * 256 + threadIdx.x;
  if (n >= Nn) return;
  int b = rowptr[n], e = rowptr[n + 1];
  for (int i = b + 1; i < e; i++){
    int key = eids[i]; int j = i - 1;
    while (j >= b && eids[j] > key){ eids[j+1] = eids[j]; j--; }
    eids[j+1] = key;
  }
}

__global__ void k_loopattr(const float* __restrict__ eattr, const int* __restrict__ rowptr,
                           const int* __restrict__ eids, float* __restrict__ lp){
  int idx = blockIdx.x * 256 + threadIdx.x;        // N*16
  int n = idx >> 4, a = idx & 15;
  if (n >= Nn) return;
  int b = rowptr[n], e = rowptr[n + 1];
  float s = 0.f; int cnt = 0;
  for (int j = b; j < e; ++j){
    int id = eids[j];
    if (id < Ne){ s += eattr[(size_t)id*16 + a]; cnt++; }
  }
  lp[(size_t)n*16 + a] = s / fmaxf((float)cnt, 1.f);
}

// Ws[k,h] = sum_c W[k, h*C+c]*a_s[h,c] ; Wd likewise.
__global__ void k_proj(const float* __restrict__ W, const float* __restrict__ a_s,
                       const float* __restrict__ a_d, float* __restrict__ Ws,
                       float* __restrict__ Wd, int K, int C){
  int gid = blockIdx.x * 256 + threadIdx.x;
  int wave = gid >> 6, lane = gid & 63;
  int h = wave & 3, k = wave >> 2;
  if (k >= K) return;
  const float* wrow = W + (size_t)k * (4*C) + (size_t)h * C;
  const float* ar = a_s + (size_t)h * C;
  const float* dr = a_d + (size_t)h * C;
  float ps = 0.f, pd = 0.f;
  for (int c = lane; c < C; c += 64){ float w = wrow[c]; ps += w * ar[c]; pd += w * dr[c]; }
  ps = wred64(ps); pd = wred64(pd);
  if (lane == 0){ Ws[k*4 + h] = ps; Wd[k*4 + h] = pd; }
}

__global__ void k_aeproj(const float* __restrict__ We, const float* __restrict__ ae,
                         float* __restrict__ outp, int C){
  int t = threadIdx.x;           // 64 threads: k=t>>2, h=t&3
  int k = t >> 2, h = t & 3;
  const float* wrow = We + (size_t)k * (4*C) + (size_t)h * C;
  const float* ar = ae + (size_t)h * C;
  float s = 0.f;
  for (int c = 0; c < C; c++) s += wrow[c] * ar[c];
  outp[k*4 + h] = s;
}

// as[n,h], ad[n,h] = x[n,:] @ Ws/Wd. Block per node.
__global__ __launch_bounds__(256) void k_asad(const float* __restrict__ x, const float* __restrict__ Ws,
                      const float* __restrict__ Wd, float* __restrict__ as_,
                      float* __restrict__ ad_, int D){
  int n = blockIdx.x, t = threadIdx.x;
  const float* row = x + (size_t)n * D;
  float p[8] = {0,0,0,0,0,0,0,0};
  for (int c = t; c < D; c += 256){
    float xv = row[c];
    float4 ws4 = *(const float4*)&Ws[c*4];
    float4 wd4 = *(const float4*)&Wd[c*4];
    p[0] += xv * ws4.x; p[1] += xv * ws4.y; p[2] += xv * ws4.z; p[3] += xv * ws4.w;
    p[4] += xv * wd4.x; p[5] += xv * wd4.y; p[6] += xv * wd4.z; p[7] += xv * wd4.w;
  }
  __shared__ float sm[4][8];
  int lane = t & 63, wid = t >> 6;
#pragma unroll
  for (int q = 0; q < 8; q++){
    float v = wred64(p[q]);
    if (lane == 0) sm[wid][q] = v;
  }
  __syncthreads();
  if (t < 8){
    float s = sm[0][t] + sm[1][t] + sm[2][t] + sm[3][t];
    if (t < 4) as_[(size_t)n*4 + t] = s;
    else       ad_[(size_t)n*4 + (t-4)] = s;
  }
}

__global__ void k_edge(const float* __restrict__ eattr, const float* __restrict__ lp,
                       const int* __restrict__ ei, const float* __restrict__ as_,
                       const float* __restrict__ ad_, const float* __restrict__ aep,
                       float* __restrict__ ebuf){
  int e = blockIdx.x * 256 + threadIdx.x;
  if (e >= NEf) return;
  int s, d; const float* ea;
  if (e < Ne){ s = ei[e]; d = ei[Ne + e]; ea = eattr + (size_t)e * 16; }
  else { s = e - Ne; d = e - Ne; ea = lp + (size_t)(e - Ne) * 16; }
  float eav[16];
#pragma unroll
  for (int k = 0; k < 16; k++) eav[k] = ea[k];
#pragma unroll
  for (int h = 0; h < 4; h++){
    float v = as_[(size_t)s*4 + h] + ad_[(size_t)d*4 + h];
#pragma unroll
    for (int k = 0; k < 16; k++) v += eav[k] * aep[k*4 + h];
    ebuf[(size_t)e*4 + h] = lrelu(v, 0.2f);
  }
}

__global__ void k_softmax(const int* __restrict__ rowptr, const int* __restrict__ eids,
                          const float* __restrict__ ebuf, float* __restrict__ alpha){
  int n = blockIdx.x * 256 + threadIdx.x;
  if (n >= Nn) return;
  int b = rowptr[n], e = rowptr[n + 1];
#pragma unroll
  for (int h = 0; h < 4; h++){
    float m = -1e30f;
    for (int j = b; j < e; ++j) m = fmaxf(m, ebuf[(size_t)eids[j]*4 + h]);
    float ss = 0.f;
    for (int j = b; j < e; ++j){
      float ex = expf(ebuf[(size_t)eids[j]*4 + h] - m);
      alpha[(size_t)eids[j]*4 + h] = ex; ss += ex;
    }
    for (int j = b; j < e; ++j) alpha[(size_t)eids[j]*4 + h] /= ss;
  }
}

// z1[n,h,0:512] = sum_e alpha[e,h] * x[src(e),:]
__global__ __launch_bounds__(256) void k_agg1(const float* __restrict__ x, const float* __restrict__ alpha,
                      const int* __restrict__ rowptr, const int* __restrict__ eids,
                      const int* __restrict__ ei, float* __restrict__ z1){
  int n = blockIdx.x, t = threadIdx.x;
  float2 a0 = {0,0}, a1 = {0,0}, a2 = {0,0}, a3 = {0,0};
  int b = rowptr[n], e = rowptr[n + 1];
  for (int j = b; j < e; ++j){
    int eid = eids[j];
    int s = (eid < Ne) ? ei[eid] : (eid - Ne);
    float4 av = *(const float4*)&alpha[(size_t)eid*4];
    float2 xv = *(const float2*)&x[(size_t)s*512 + t*2];
    a0.x += av.x*xv.x; a0.y += av.x*xv.y;
    a1.x += av.y*xv.x; a1.y += av.y*xv.y;
    a2.x += av.z*xv.x; a2.y += av.z*xv.y;
    a3.x += av.w*xv.x; a3.y += av.w*xv.y;
  }
  size_t base = (size_t)n*2048 + t*2;
  *(float2*)&z1[base +    0] = a0;
  *(float2*)&z1[base +  512] = a1;
  *(float2*)&z1[base + 1024] = a2;
  *(float2*)&z1[base + 1536] = a3;
}

// z2h = sum_e alpha[e,h] * x2[src(e),:] for ONE head, written as bf16 hi/lo split
__global__ __launch_bounds__(256) void k_agg2h_split(const float* __restrict__ x2, const float* __restrict__ alpha,
                       const int* __restrict__ rowptr, const int* __restrict__ eids,
                       const int* __restrict__ ei, unsigned short* __restrict__ zhi,
                       unsigned short* __restrict__ zlo, int h){
  int n = blockIdx.x, t = threadIdx.x;
  float acc[8] = {0,0,0,0,0,0,0,0};
  int b = rowptr[n], e = rowptr[n + 1];
  for (int j = b; j < e; ++j){
    int eid = eids[j];
    int s = (eid < Ne) ? ei[eid] : (eid - Ne);
    float a = alpha[(size_t)eid*4 + h];
    const float* xr = x2 + (size_t)s*2048 + t*8;
    float4 xa = *(const float4*)xr;
    float4 xb = *(const float4*)(xr + 4);
    acc[0] += a*xa.x; acc[1] += a*xa.y; acc[2] += a*xa.z; acc[3] += a*xa.w;
    acc[4] += a*xb.x; acc[5] += a*xb.y; acc[6] += a*xb.z; acc[7] += a*xb.w;
  }
  size_t base = (size_t)n*2048 + t*8;
  ushort4 h0, h1, l0, l1;
  split2(acc[0], h0.x, l0.x); split2(acc[1], h0.y, l0.y);
  split2(acc[2], h0.z, l0.z); split2(acc[3], h0.w, l0.w);
  split2(acc[4], h1.x, l1.x); split2(acc[5], h1.y, l1.y);
  split2(acc[6], h1.z, l1.z); split2(acc[7], h1.w, l1.w);
  *(ushort4*)&zhi[base]     = h0; *(ushort4*)&zhi[base + 4] = h1;
  *(ushort4*)&zlo[base]     = l0; *(ushort4*)&zlo[base + 4] = l1;
}

// W2 head slice -> transposed bf16 split: wh[n][k] = split(W2[k][h*2048+n])
__global__ __launch_bounds__(256) void k_wsplit_t(const float* __restrict__ W2, int h,
                        unsigned short* __restrict__ whi, unsigned short* __restrict__ wlo){
  __shared__ float tile[32][33];
  int bk = blockIdx.x * 32, bn = blockIdx.y * 32;
  int tx = threadIdx.x & 31, ty = threadIdx.x >> 5;
#pragma unroll
  for (int i = 0; i < 4; i++){
    int k = bk + ty + i*8;
    tile[ty + i*8][tx] = W2[(size_t)k*8192 + h*2048 + bn + tx];
  }
  __syncthreads();
#pragma unroll
  for (int i = 0; i < 4; i++){
    int n = bn + ty + i*8;
    float v = tile[tx][ty + i*8];
    unsigned short hh, ll; split2(v, hh, ll);
    whi[(size_t)n*2048 + bk + tx] = hh;
    wlo[(size_t)n*2048 + bk + tx] = ll;
  }
}

// ---------------- layer-2 MFMA GEMM: 3-term bf16 split ----------------
// C[4096][2048] = (Ah+Al)[4096][2048k] x (Bh+Bl)^T[2048n][2048k], bias+lrelu, bf16 out.
// LDS tile: [128 rows][8 chunks of 16B] per matrix; chunks 0-3 hi(k0..31), 4-7 lo.
// physical chunk = logical ^ (row&7); swizzle folded into global source, LDS dest linear.
__global__ __launch_bounds__(256) void k_gemm2(
    const unsigned short* __restrict__ Ah, const unsigned short* __restrict__ Al,
    const unsigned short* __restrict__ Bh, const unsigned short* __restrict__ Bl,
    unsigned short* __restrict__ Cout, const float* __restrict__ bias)
{
  __shared__ unsigned short lds[16384];   // A: [0,8192) ushorts, B: [8192,16384)
  const int t = threadIdx.x;
  const int brow = blockIdx.y * 128, bcol = blockIdx.x * 128;
  const int wid = t >> 6, lane = t & 63;
  const int wm = (wid >> 1) * 64, wn = (wid & 1) * 64;

  // ---- staging mapping: slot s = i*256+t -> row=i*32+(t>>3), phys chunk c=t&7
  const int sr = t >> 3, sc = t & 7;
  const int scc = sc ^ (sr & 7);   // logical chunk (invariant over i since 32%8==0)
  const unsigned short* asrc = (scc < 4 ? Ah : Al) + (size_t)(brow + sr)*2048 + (size_t)(scc & 3)*8;
  const unsigned short* bsrc = (scc < 4 ? Bh : Bl) + (size_t)(bcol + sr)*2048 + (size_t)(scc & 3)*8;
  unsigned short* adst = &lds[(size_t)wid * 512];          // + i*2048 ; lane*16B implicit
  unsigned short* bdst = &lds[8192 + (size_t)wid * 512];

  // ---- fragment read addressing (ushort units)
  const int fr = lane & 15, kc = lane >> 4;
  const int swz = ((kc ^ (lane & 7)) << 3);
  int aoff[4], boff[4];
#pragma unroll
  for (int m = 0; m < 4; m++) aoff[m] = (wm + m*16 + fr)*64 + swz;
#pragma unroll
  for (int n = 0; n < 4; n++) boff[n] = 8192 + (wn + n*16 + fr)*64 + swz;

  f32x4 acc[4][4];
#pragma unroll
  for (int m = 0; m < 4; m++)
#pragma unroll
    for (int n = 0; n < 4; n++) acc[m][n] = f32x4{0.f, 0.f, 0.f, 0.f};

  for (int kt = 0; kt < 64; ++kt){
    const size_t ko = (size_t)kt * 32;
#pragma unroll
    for (int i = 0; i < 4; i++){
      gload16(asrc + (size_t)i*65536 + ko, adst + i*2048);
      gload16(bsrc + (size_t)i*65536 + ko, bdst + i*2048);
    }
    __syncthreads();   // drains vmcnt, LDS(kt) ready

    bf16x8 ah[4], al[4], bh[4], bl[4];
#pragma unroll
    for (int m = 0; m < 4; m++){
      ah[m] = *(const bf16x8*)&lds[aoff[m]];
      al[m] = *(const bf16x8*)&lds[aoff[m] ^ 32];
    }
#pragma unroll
    for (int n = 0; n < 4; n++){
      bh[n] = *(const bf16x8*)&lds[boff[n]];
      bl[n] = *(const bf16x8*)&lds[boff[n] ^ 32];
    }
#pragma unroll
    for (int m = 0; m < 4; m++)
#pragma unroll
      for (int n = 0; n < 4; n++){
        acc[m][n] = __builtin_amdgcn_mfma_f32_16x16x32_bf16(ah[m], bh[n], acc[m][n], 0, 0, 0);
        acc[m][n] = __builtin_amdgcn_mfma_f32_16x16x32_bf16(ah[m], bl[n], acc[m][n], 0, 0, 0);
        acc[m][n] = __builtin_amdgcn_mfma_f32_16x16x32_bf16(al[m], bh[n], acc[m][n], 0, 0, 0);
      }
    __syncthreads();   // all waves done reading before next stage overwrites
  }

  // ---- epilogue: bias + leakyrelu(0.01) + bf16 store. C/D: col=lane&15, row=(lane>>4)*4+reg
  float bv[4];
#pragma unroll
  for (int n = 0; n < 4; n++) bv[n] = bias[bcol + wn + n*16 + fr];
#pragma unroll
  for (int m = 0; m < 4; m++){
    const int row0 = brow + wm + m*16 + kc*4;
#pragma unroll
    for (int n = 0; n < 4; n++){
      const int col = bcol + wn + n*16 + fr;
#pragma unroll
      for (int r = 0; r < 4; r++){
        float v = acc[m][n][r] + bv[n];
        v = lrelu(v, 0.01f);
        Cout[(size_t)(row0 + r)*2048 + col] = f2bf(v);
      }
    }
  }
}

// ---------------- fp32 tiled GEMM (optionally bf16 A): C[z] = op(A[z] @ B[z] ...) ----------------
template<int ACT, bool HASBIAS, bool BETA1, bool BF16A>
__global__ __launch_bounds__(256) void k_gemm(
    const float* __restrict__ A, int lda, size_t az,
    const float* __restrict__ B, int ldb, size_t bz,
    float* __restrict__ C, int ldc, size_t cz,
    const float* __restrict__ bias, int biasz, int K)
{
  constexpr int BM = 128, BN = 128, BK = 16, TM = 8, TN = 8;
  __shared__ float As[BK][BM + 4];
  __shared__ float Bs[BK][BN + 4];
  const int z = blockIdx.z;
  B += (size_t)z * bz; C += (size_t)z * cz;
  const unsigned short* Au = (const unsigned short*)A + (size_t)z * az;
  const float* Af = A + (size_t)z * az;
  const int brow = blockIdx.y * BM, bcol = blockIdx.x * BN;
  const int tid = threadIdx.x;
  const int tx = tid & 15, ty = tid >> 4;
  const int ar = tid >> 2, ac4 = (tid & 3) * 4;
  const int br = tid >> 5, bc4 = (tid & 31) * 4;
  float acc[TM][TN] = {};

  for (int kt = 0; kt < K; kt += BK){
#pragma unroll
    for (int rr = 0; rr < BM; rr += 64){
      if (BF16A){
        ushort4 u = *(const ushort4*)&Au[(size_t)(brow + ar + rr) * lda + kt + ac4];
        As[ac4 + 0][ar + rr] = bf2f(u.x); As[ac4 + 1][ar + rr] = bf2f(u.y);
        As[ac4 + 2][ar + rr] = bf2f(u.z); As[ac4 + 3][ar + rr] = bf2f(u.w);
      } else {
        float4 v = *(const float4*)&Af[(size_t)(brow + ar + rr) * lda + kt + ac4];
        As[ac4 + 0][ar + rr] = v.x; As[ac4 + 1][ar + rr] = v.y;
        As[ac4 + 2][ar + rr] = v.z; As[ac4 + 3][ar + rr] = v.w;
      }
    }
#pragma unroll
    for (int rr = 0; rr < BK; rr += 8){
      *(float4*)&Bs[br + rr][bc4] = *(const float4*)&B[(size_t)(kt + br + rr) * ldb + bcol + bc4];
    }
    __syncthreads();
#pragma unroll
    for (int k = 0; k < BK; k++){
      float af[TM], bf[TN];
#pragma unroll
      for (int i = 0; i < TM; i++) af[i] = As[k][ty*TM + i];
#pragma unroll
      for (int j = 0; j < TN; j++) bf[j] = Bs[k][tx*TN + j];
#pragma unroll
      for (int i = 0; i < TM; i++)
#pragma unroll
        for (int j = 0; j < TN; j++) acc[i][j] = fmaf(af[i], bf[j], acc[i][j]);
    }
    __syncthreads();
  }
#pragma unroll
  for (int i = 0; i < TM; i++){
    const int row = brow + ty*TM + i;
#pragma unroll
    for (int j = 0; j < TN; j += 4){
      const int col = bcol + tx*TN + j;
      float4 v = { acc[i][j], acc[i][j+1], acc[i][j+2], acc[i][j+3] };
      if (HASBIAS){
        v.x += bias[(size_t)z*biasz + col + 0]; v.y += bias[(size_t)z*biasz + col + 1];
        v.z += bias[(size_t)z*biasz + col + 2]; v.w += bias[(size_t)z*biasz + col + 3];
      }
      if (ACT == 1){
        v.x = lrelu(v.x, 0.01f); v.y = lrelu(v.y, 0.01f);
        v.z = lrelu(v.z, 0.01f); v.w = lrelu(v.w, 0.01f);
      }
      float* cp = &C[(size_t)row * ldc + col];
      if (BETA1){
        float4 o = *(const float4*)cp;
        v.x += o.x; v.y += o.y; v.z += o.z; v.w += o.w;
      }
      *(float4*)cp = v;
    }
  }
}

// final: y = leaky(sum_z ypart[z] + bout); per-graph mean over sorted batch
__global__ void k_final(const float* __restrict__ yp, const float* __restrict__ bout,
                        const int* __restrict__ batch, float* __restrict__ out){
  const int g = blockIdx.x, t = threadIdx.x;
  __shared__ int sb[2];
  if (t < 2){
    int key = g + t, lo = 0, hi = Nn;
    while (lo < hi){ int mid = (lo + hi) >> 1; if (batch[mid] < key) lo = mid + 1; else hi = mid; }
    sb[t] = lo;
  }
  __syncthreads();
  const int b = sb[0], e = sb[1];
  const size_t P = (size_t)Nn * 256;
  float s = 0.f;
  for (int n = b; n < e; ++n){
    size_t i = (size_t)n*256 + t;
    float v = yp[i] + yp[P + i] + yp[2*P + i] + yp[3*P + i] + bout[t];
    s += lrelu(v, 0.01f);
  }
  out[g*256 + t] = s / fmaxf((float)(e - b), 1.f);
}

// ---------------- launch ----------------
extern "C" void kernel_launch(void* const* d_in, const int* in_sizes, int n_in,
                              void* d_out, int out_size, void* d_ws, size_t ws_size,
                              hipStream_t stream){
  const float* xg    = (const float*)d_in[0];
  const float* ac    = (const float*)d_in[1];
  const float* ti    = (const float*)d_in[2];
  const float* eattr = (const float*)d_in[3];
  const int*   ei    = (const int*)  d_in[4];
  const int*   batch = (const int*)  d_in[5];
  const float* W1    = (const float*)d_in[6];
  const float* as1w  = (const float*)d_in[7];
  const float* ad1w  = (const float*)d_in[8];
  const float* ae1w  = (const float*)d_in[9];
  const float* We1   = (const float*)d_in[10];
  const float* b1    = (const float*)d_in[11];
  const float* W2    = (const float*)d_in[12];
  const float* as2w  = (const float*)d_in[13];
  const float* ad2w  = (const float*)d_in[14];
  const float* ae2w  = (const float*)d_in[15];
  const float* We2   = (const float*)d_in[16];
  const float* b2    = (const float*)d_in[17];
  const float* Wout  = (const float*)d_in[18];
  const float* bout  = (const float*)d_in[19];
  float* out = (float*)d_out;
  float* ws  = (float*)d_ws;
  if (ws_size < WS_FLOATS * sizeof(float)) return;
  int* iws = (int*)(ws + OFF_I);

  unsigned short* zhi = (unsigned short*)(ws + OFF_ZHI);
  unsigned short* zlo = (unsigned short*)(ws + OFF_ZLO);
  unsigned short* whi = (unsigned short*)(ws + OFF_X);
  unsigned short* wlo = (unsigned short*)(ws + OFF_WLO);
  unsigned short* x3h = (unsigned short*)(ws + OFF_X3H);

  hipMemsetAsync(iws + I_DEG, 0, Nn * sizeof(int), stream);
  k_concat <<<8192, 256, 0, stream>>>(xg, ac, ti, ws + OFF_X);
  k_count  <<<128,  256, 0, stream>>>(ei, iws + I_DEG);
  k_scan   <<<1,   1024, 0, stream>>>(iws + I_DEG, iws + I_RP, iws + I_CUR);
  k_fill   <<<144,  256, 0, stream>>>(ei, iws + I_CUR, iws + I_EID);
  k_sort   <<<16,   256, 0, stream>>>(iws + I_RP, iws + I_EID);
  k_loopattr<<<256, 256, 0, stream>>>(eattr, iws + I_RP, iws + I_EID, ws + OFF_LP);

  k_proj   <<<512,  256, 0, stream>>>(W1, as1w, ad1w, ws + OFF_WS1, ws + OFF_WD1, 512, 512);
  k_proj   <<<2048, 256, 0, stream>>>(W2, as2w, ad2w, ws + OFF_WS2, ws + OFF_WD2, 2048, 2048);
  k_aeproj <<<1,     64, 0, stream>>>(We1, ae1w, ws + OFF_AE1, 512);
  k_aeproj <<<1,     64, 0, stream>>>(We2, ae2w, ws + OFF_AE2, 2048);

  // ---- layer 1 ----
  k_asad   <<<4096, 256, 0, stream>>>(ws + OFF_X, ws + OFF_WS1, ws + OFF_WD1, ws + OFF_AS1, ws + OFF_AD1, 512);
  k_edge   <<<144,  256, 0, stream>>>(eattr, ws + OFF_LP, ei, ws + OFF_AS1, ws + OFF_AD1, ws + OFF_AE1, ws + OFF_EB);
  k_softmax<<<16,   256, 0, stream>>>(iws + I_RP, iws + I_EID, ws + OFF_EB, ws + OFF_AL);
  k_agg1   <<<4096, 256, 0, stream>>>(ws + OFF_X, ws + OFF_AL, iws + I_RP, iws + I_EID, ei, ws + OFF_Z1);
  k_gemm<1, true, false, false><<<dim3(4, 32, 4), 256, 0, stream>>>(
      ws + OFF_Z1, 2048, 512,  W1, 2048, 512,  ws + OFF_X2, 2048, 512,  b1, 512, 512);

  // ---- layer 2 attention ----
  k_asad   <<<4096, 256, 0, stream>>>(ws + OFF_X2, ws + OFF_WS2, ws + OFF_WD2, ws + OFF_AS2, ws + OFF_AD2, 2048);
  k_edge   <<<144,  256, 0, stream>>>(eattr, ws + OFF_LP, ei, ws + OFF_AS2, ws + OFF_AD2, ws + OFF_AE2, ws + OFF_EB);
  k_softmax<<<16,   256, 0, stream>>>(iws + I_RP, iws + I_EID, ws + OFF_EB, ws + OFF_AL);

  // ---- layer 2 + fc, per head ----
  for (int h = 0; h < 4; ++h){
    k_wsplit_t    <<<dim3(64, 64), 256, 0, stream>>>(W2, h, whi, wlo);
    k_agg2h_split <<<4096, 256, 0, stream>>>(ws + OFF_X2, ws + OFF_AL, iws + I_RP, iws + I_EID, ei, zhi, zlo, h);
    k_gemm2       <<<dim3(16, 32), 256, 0, stream>>>(zhi, zlo, whi, wlo, x3h, b2 + (size_t)h*2048);
    if (h == 0)
      k_gemm<0, false, false, true><<<dim3(2, 32, 4), 256, 0, stream>>>(
          (const float*)x3h, 2048, 512,  Wout + (size_t)h*2048*256, 256, (size_t)512*256,
          ws + OFF_YP, 256, (size_t)Nn*256,  nullptr, 0, 512);
    else
      k_gemm<0, false, true, true><<<dim3(2, 32, 4), 256, 0, stream>>>(
          (const float*)x3h, 2048, 512,  Wout + (size_t)h*2048*256, 256, (size_t)512*256,
          ws + OFF_YP, 256, (size_t)Nn*256,  nullptr, 0, 512);
  }

  k_final<<<8, 256, 0, stream>>>(ws + OFF_YP, bout, batch, out);
}

// Round 3
// 1492.022 us; speedup vs baseline: 1.9783x; 1.1528x over previous
//
#include <hip/hip_runtime.h>
#include <math.h>

constexpr int Nn  = 4096;
constexpr int Ne  = 32768;
constexpr int NEf = Ne + Nn;     // real edges + self loops

// ---------------- ws layout (float offsets) ----------------
// region reuse:
//   [0..2097152)          X fp32 (prep/L1)          -> wh_hi bf16 [2048n][2048k] (L2 loop)
//   [2097152..10485760)   Z1 fp32 (L1)              -> zh_hi/zh_lo bf16 [4096][2048] (L2 loop)
//   [10485760..18874368)  X2 fp32
//   [18874368..23068672)  x3h bf16 [4096][2048]
//   [23068672..25165824)  wh_lo bf16
//   [27262976..31457280)  YP 4x[4096][256] fp32
constexpr size_t OFF_X   = 0;
constexpr size_t OFF_Z1  = 2097152;
constexpr size_t OFF_ZHI = 2097152;      // ushort* region
constexpr size_t OFF_ZLO = 6291456;      // ushort* region
constexpr size_t OFF_X2  = 10485760;
constexpr size_t OFF_X3H = 18874368;     // ushort* region (bf16)
constexpr size_t OFF_WLO = 23068672;     // ushort* region
constexpr size_t OFF_YP  = 27262976;
constexpr size_t OFF_LP  = 31457280;     // [N,16] self-loop edge attr
constexpr size_t OFF_WS1 = OFF_LP  + 65536;   // [512,4]
constexpr size_t OFF_WD1 = OFF_WS1 + 2048;    // [512,4]
constexpr size_t OFF_WS2 = OFF_WD1 + 2048;    // [2048,4]
constexpr size_t OFF_WD2 = OFF_WS2 + 8192;    // [2048,4]
constexpr size_t OFF_AE1 = OFF_WD2 + 8192;    // [16,4]
constexpr size_t OFF_AE2 = OFF_AE1 + 64;      // [16,4]
constexpr size_t OFF_AS1 = OFF_AE2 + 64;      // [N,4]
constexpr size_t OFF_AD1 = OFF_AS1 + 16384;
constexpr size_t OFF_AS2 = OFF_AD1 + 16384;
constexpr size_t OFF_AD2 = OFF_AS2 + 16384;
constexpr size_t OFF_EB  = OFF_AD2 + 16384;          // [Ef,4] logits
constexpr size_t OFF_AL  = OFF_EB  + (size_t)NEf*4;  // [Ef,4] alpha
constexpr size_t OFF_I   = OFF_AL  + (size_t)NEf*4;  // int region
constexpr size_t I_DEG = 0;       // [N]
constexpr size_t I_RP  = 4096;    // [N+1] (+pad)
constexpr size_t I_CUR = 8200;    // [N]
constexpr size_t I_EID = 12296;   // [Ef]
constexpr size_t WS_FLOATS = OFF_I + I_EID + (size_t)NEf + 64;

using bf16x8 = __bf16 __attribute__((ext_vector_type(8)));
using f32x4  = float __attribute__((ext_vector_type(4)));

__device__ __forceinline__ float wred64(float v){
#pragma unroll
  for (int o = 32; o > 0; o >>= 1) v += __shfl_down(v, o, 64);
  return v;
}
__device__ __forceinline__ float lrelu(float v, float s){ return v > 0.f ? v : s * v; }

__device__ __forceinline__ unsigned short f2bf(float x){  // RTNE
  unsigned int u = __float_as_uint(x);
  unsigned int r = (u + 0x7FFFu + ((u >> 16) & 1u)) >> 16;
  return (unsigned short)r;
}
__device__ __forceinline__ float bf2f(unsigned short h){
  return __uint_as_float((unsigned int)h << 16);
}
__device__ __forceinline__ void split2(float x, unsigned short& h, unsigned short& l){
  h = f2bf(x);
  l = f2bf(x - bf2f(h));
}
__device__ __forceinline__ void gload16(const void* g, void* l){
  __builtin_amdgcn_global_load_lds((const __attribute__((address_space(1))) void*)g,
                                   (__attribute__((address_space(3))) void*)l, 16, 0, 0);
}

// ---------------- small prep kernels ----------------
__global__ void k_concat(const float* __restrict__ xg, const float* __restrict__ ac,
                         const float* __restrict__ ti, float* __restrict__ x){
  int i = blockIdx.x * 256 + threadIdx.x;          // over N*512
  int n = i >> 9, c = i & 511;
  float v;
  if (c < 256)      v = xg[(size_t)n*256 + c];
  else if (c < 384) v = ac[(size_t)n*128 + (c-256)];
  else              v = ti[(size_t)n*128 + (c-384)];
  x[i] = v;
}

__global__ void k_count(const int* __restrict__ ei, int* __restrict__ deg){
  int e = blockIdx.x * 256 + threadIdx.x;
  if (e < Ne) atomicAdd(&deg[ei[Ne + e]], 1);
}

__global__ void k_scan(const int* __restrict__ deg, int* __restrict__ rowptr, int* __restrict__ cursor){
  __shared__ int sd[1024];
  int t = threadIdx.x;
  int v[4]; int s = 0;
#pragma unroll
  for (int i = 0; i < 4; i++){ v[i] = s; s += deg[t*4 + i] + 1; }   // +1 self loop
  sd[t] = s;
  __syncthreads();
  for (int off = 1; off < 1024; off <<= 1){
    int x = (t >= off) ? sd[t - off] : 0;
    __syncthreads();
    sd[t] += x;
    __syncthreads();
  }
  int base = (t == 0) ? 0 : sd[t - 1];
#pragma unroll
  for (int i = 0; i < 4; i++){ int rp = base + v[i]; rowptr[t*4 + i] = rp; cursor[t*4 + i] = rp; }
  if (t == 1023) rowptr[4096] = sd[1023];
}

__global__ void k_fill(const int* __restrict__ ei, int* __restrict__ cursor, int* __restrict__ eids){
  int e = blockIdx.x * 256 + threadIdx.x;
  if (e >= NEf) return;
  int d = (e < Ne) ? ei[Ne + e] : (e - Ne);
  int p = atomicAdd(&cursor[d], 1);
  eids[p] = e;
}

__global__ void k_sort(const int* __restrict__ rowptr, int* __restrict__ eids){
  int n = blockIdx.x * 256 + threadIdx.x;
  if (n >= Nn) return;
  int b = rowptr[n], e = rowptr[n + 1];
  for (int i = b + 1; i < e; i++){
    int key = eids[i]; int j = i - 1;
    while (j >= b && eids[j] > key){ eids[j+1] = eids[j]; j--; }
    eids[j+1] = key;
  }
}

__global__ void k_loopattr(const float* __restrict__ eattr, const int* __restrict__ rowptr,
                           const int* __restrict__ eids, float* __restrict__ lp){
  int idx = blockIdx.x * 256 + threadIdx.x;        // N*16
  int n = idx >> 4, a = idx & 15;
  if (n >= Nn) return;
  int b = rowptr[n], e = rowptr[n + 1];
  float s = 0.f; int cnt = 0;
  for (int j = b; j < e; ++j){
    int id = eids[j];
    if (id < Ne){ s += eattr[(size_t)id*16 + a]; cnt++; }
  }
  lp[(size_t)n*16 + a] = s / fmaxf((float)cnt, 1.f);
}

// Ws[k,h] = sum_c W[k, h*C+c]*a_s[h,c] ; Wd likewise.
__global__ void k_proj(const float* __restrict__ W, const float* __restrict__ a_s,
                       const float* __restrict__ a_d, float* __restrict__ Ws,
                       float* __restrict__ Wd, int K, int C){
  int gid = blockIdx.x * 256 + threadIdx.x;
  int wave = gid >> 6, lane = gid & 63;
  int h = wave & 3, k = wave >> 2;
  if (k >= K) return;
  const float* wrow = W + (size_t)k * (4*C) + (size_t)h * C;
  const float* ar = a_s + (size_t)h * C;
  const float* dr = a_d + (size_t)h * C;
  float ps = 0.f, pd = 0.f;
  for (int c = lane; c < C; c += 64){ float w = wrow[c]; ps += w * ar[c]; pd += w * dr[c]; }
  ps = wred64(ps); pd = wred64(pd);
  if (lane == 0){ Ws[k*4 + h] = ps; Wd[k*4 + h] = pd; }
}

// one wave per (k,h): outp[k*4+h] = dot(We[k, h*C:(h+1)*C], ae[h,:])
__global__ void k_aeproj(const float* __restrict__ We, const float* __restrict__ ae,
                         float* __restrict__ outp, int C){
  int gid = blockIdx.x * 256 + threadIdx.x;
  int wave = gid >> 6, lane = gid & 63;
  int h = wave & 3, k = wave >> 2;
  if (k >= 16) return;
  const float* wrow = We + (size_t)k * (4*C) + (size_t)h * C;
  const float* ar = ae + (size_t)h * C;
  float s = 0.f;
  for (int c = lane; c < C; c += 64) s += wrow[c] * ar[c];
  s = wred64(s);
  if (lane == 0) outp[k*4 + h] = s;
}

// as[n,h], ad[n,h] = x[n,:] @ Ws/Wd. Block per node.
__global__ __launch_bounds__(256) void k_asad(const float* __restrict__ x, const float* __restrict__ Ws,
                      const float* __restrict__ Wd, float* __restrict__ as_,
                      float* __restrict__ ad_, int D){
  int n = blockIdx.x, t = threadIdx.x;
  const float* row = x + (size_t)n * D;
  float p[8] = {0,0,0,0,0,0,0,0};
  for (int c = t; c < D; c += 256){
    float xv = row[c];
    float4 ws4 = *(const float4*)&Ws[c*4];
    float4 wd4 = *(const float4*)&Wd[c*4];
    p[0] += xv * ws4.x; p[1] += xv * ws4.y; p[2] += xv * ws4.z; p[3] += xv * ws4.w;
    p[4] += xv * wd4.x; p[5] += xv * wd4.y; p[6] += xv * wd4.z; p[7] += xv * wd4.w;
  }
  __shared__ float sm[4][8];
  int lane = t & 63, wid = t >> 6;
#pragma unroll
  for (int q = 0; q < 8; q++){
    float v = wred64(p[q]);
    if (lane == 0) sm[wid][q] = v;
  }
  __syncthreads();
  if (t < 8){
    float s = sm[0][t] + sm[1][t] + sm[2][t] + sm[3][t];
    if (t < 4) as_[(size_t)n*4 + t] = s;
    else       ad_[(size_t)n*4 + (t-4)] = s;
  }
}

__global__ void k_edge(const float* __restrict__ eattr, const float* __restrict__ lp,
                       const int* __restrict__ ei, const float* __restrict__ as_,
                       const float* __restrict__ ad_, const float* __restrict__ aep,
                       float* __restrict__ ebuf){
  int e = blockIdx.x * 256 + threadIdx.x;
  if (e >= NEf) return;
  int s, d; const float* ea;
  if (e < Ne){ s = ei[e]; d = ei[Ne + e]; ea = eattr + (size_t)e * 16; }
  else { s = e - Ne; d = e - Ne; ea = lp + (size_t)(e - Ne) * 16; }
  float eav[16];
#pragma unroll
  for (int k = 0; k < 16; k++) eav[k] = ea[k];
#pragma unroll
  for (int h = 0; h < 4; h++){
    float v = as_[(size_t)s*4 + h] + ad_[(size_t)d*4 + h];
#pragma unroll
    for (int k = 0; k < 16; k++) v += eav[k] * aep[k*4 + h];
    ebuf[(size_t)e*4 + h] = lrelu(v, 0.2f);
  }
}

__global__ void k_softmax(const int* __restrict__ rowptr, const int* __restrict__ eids,
                          const float* __restrict__ ebuf, float* __restrict__ alpha){
  int n = blockIdx.x * 256 + threadIdx.x;
  if (n >= Nn) return;
  int b = rowptr[n], e = rowptr[n + 1];
#pragma unroll
  for (int h = 0; h < 4; h++){
    float m = -1e30f;
    for (int j = b; j < e; ++j) m = fmaxf(m, ebuf[(size_t)eids[j]*4 + h]);
    float ss = 0.f;
    for (int j = b; j < e; ++j){
      float ex = expf(ebuf[(size_t)eids[j]*4 + h] - m);
      alpha[(size_t)eids[j]*4 + h] = ex; ss += ex;
    }
    for (int j = b; j < e; ++j) alpha[(size_t)eids[j]*4 + h] /= ss;
  }
}

// z1[n,h,0:512] = sum_e alpha[e,h] * x[src(e),:]
__global__ __launch_bounds__(256) void k_agg1(const float* __restrict__ x, const float* __restrict__ alpha,
                      const int* __restrict__ rowptr, const int* __restrict__ eids,
                      const int* __restrict__ ei, float* __restrict__ z1){
  int n = blockIdx.x, t = threadIdx.x;
  float2 a0 = {0,0}, a1 = {0,0}, a2 = {0,0}, a3 = {0,0};
  int b = rowptr[n], e = rowptr[n + 1];
  for (int j = b; j < e; ++j){
    int eid = eids[j];
    int s = (eid < Ne) ? ei[eid] : (eid - Ne);
    float4 av = *(const float4*)&alpha[(size_t)eid*4];
    float2 xv = *(const float2*)&x[(size_t)s*512 + t*2];
    a0.x += av.x*xv.x; a0.y += av.x*xv.y;
    a1.x += av.y*xv.x; a1.y += av.y*xv.y;
    a2.x += av.z*xv.x; a2.y += av.z*xv.y;
    a3.x += av.w*xv.x; a3.y += av.w*xv.y;
  }
  size_t base = (size_t)n*2048 + t*2;
  *(float2*)&z1[base +    0] = a0;
  *(float2*)&z1[base +  512] = a1;
  *(float2*)&z1[base + 1024] = a2;
  *(float2*)&z1[base + 1536] = a3;
}

// z2h = sum_e alpha[e,h] * x2[src(e),:] for ONE head, written as bf16 hi/lo split
__global__ __launch_bounds__(256) void k_agg2h_split(const float* __restrict__ x2, const float* __restrict__ alpha,
                       const int* __restrict__ rowptr, const int* __restrict__ eids,
                       const int* __restrict__ ei, unsigned short* __restrict__ zhi,
                       unsigned short* __restrict__ zlo, int h){
  int n = blockIdx.x, t = threadIdx.x;
  float acc[8] = {0,0,0,0,0,0,0,0};
  int b = rowptr[n], e = rowptr[n + 1];
  for (int j = b; j < e; ++j){
    int eid = eids[j];
    int s = (eid < Ne) ? ei[eid] : (eid - Ne);
    float a = alpha[(size_t)eid*4 + h];
    const float* xr = x2 + (size_t)s*2048 + t*8;
    float4 xa = *(const float4*)xr;
    float4 xb = *(const float4*)(xr + 4);
    acc[0] += a*xa.x; acc[1] += a*xa.y; acc[2] += a*xa.z; acc[3] += a*xa.w;
    acc[4] += a*xb.x; acc[5] += a*xb.y; acc[6] += a*xb.z; acc[7] += a*xb.w;
  }
  size_t base = (size_t)n*2048 + t*8;
  ushort4 h0, h1, l0, l1;
  split2(acc[0], h0.x, l0.x); split2(acc[1], h0.y, l0.y);
  split2(acc[2], h0.z, l0.z); split2(acc[3], h0.w, l0.w);
  split2(acc[4], h1.x, l1.x); split2(acc[5], h1.y, l1.y);
  split2(acc[6], h1.z, l1.z); split2(acc[7], h1.w, l1.w);
  *(ushort4*)&zhi[base]     = h0; *(ushort4*)&zhi[base + 4] = h1;
  *(ushort4*)&zlo[base]     = l0; *(ushort4*)&zlo[base + 4] = l1;
}

// W2 head slice -> transposed bf16 split: wh[n][k] = split(W2[k][h*2048+n])
__global__ __launch_bounds__(256) void k_wsplit_t(const float* __restrict__ W2, int h,
                        unsigned short* __restrict__ whi, unsigned short* __restrict__ wlo){
  __shared__ float tile[32][33];
  int bk = blockIdx.x * 32, bn = blockIdx.y * 32;
  int tx = threadIdx.x & 31, ty = threadIdx.x >> 5;
#pragma unroll
  for (int i = 0; i < 4; i++){
    int k = bk + ty + i*8;
    tile[ty + i*8][tx] = W2[(size_t)k*8192 + h*2048 + bn + tx];
  }
  __syncthreads();
#pragma unroll
  for (int i = 0; i < 4; i++){
    int n = bn + ty + i*8;
    float v = tile[tx][ty + i*8];
    unsigned short hh, ll; split2(v, hh, ll);
    whi[(size_t)n*2048 + bk + tx] = hh;
    wlo[(size_t)n*2048 + bk + tx] = ll;
  }
}

// ---------------- layer-2 MFMA GEMM: 3-term bf16 split ----------------
// C[4096][2048] = (Ah+Al)[4096][2048k] x (Bh+Bl)^T[2048n][2048k], bias+lrelu, bf16 out.
// LDS tile: [128 rows][8 chunks of 16B] per matrix; chunks 0-3 hi(k0..31), 4-7 lo.
// physical chunk = logical ^ (row&7); swizzle folded into global source, LDS dest linear.
__global__ __launch_bounds__(256) void k_gemm2(
    const unsigned short* __restrict__ Ah, const unsigned short* __restrict__ Al,
    const unsigned short* __restrict__ Bh, const unsigned short* __restrict__ Bl,
    unsigned short* __restrict__ Cout, const float* __restrict__ bias)
{
  __shared__ unsigned short lds[16384];   // A: [0,8192) ushorts, B: [8192,16384)
  const int t = threadIdx.x;
  const int brow = blockIdx.y * 128, bcol = blockIdx.x * 128;
  const int wid = t >> 6, lane = t & 63;
  const int wm = (wid >> 1) * 64, wn = (wid & 1) * 64;

  // ---- staging mapping: slot s = i*256+t -> row=i*32+(t>>3), phys chunk c=t&7
  const int sr = t >> 3, sc = t & 7;
  const int scc = sc ^ (sr & 7);   // logical chunk (invariant over i since 32%8==0)
  const unsigned short* asrc = (scc < 4 ? Ah : Al) + (size_t)(brow + sr)*2048 + (size_t)(scc & 3)*8;
  const unsigned short* bsrc = (scc < 4 ? Bh : Bl) + (size_t)(bcol + sr)*2048 + (size_t)(scc & 3)*8;
  unsigned short* adst = &lds[(size_t)wid * 512];          // + i*2048 ; lane*16B implicit
  unsigned short* bdst = &lds[8192 + (size_t)wid * 512];

  // ---- fragment read addressing (ushort units)
  const int fr = lane & 15, kc = lane >> 4;
  const int swz = ((kc ^ (lane & 7)) << 3);
  int aoff[4], boff[4];
#pragma unroll
  for (int m = 0; m < 4; m++) aoff[m] = (wm + m*16 + fr)*64 + swz;
#pragma unroll
  for (int n = 0; n < 4; n++) boff[n] = 8192 + (wn + n*16 + fr)*64 + swz;

  f32x4 acc[4][4];
#pragma unroll
  for (int m = 0; m < 4; m++)
#pragma unroll
    for (int n = 0; n < 4; n++) acc[m][n] = f32x4{0.f, 0.f, 0.f, 0.f};

  for (int kt = 0; kt < 64; ++kt){
    const size_t ko = (size_t)kt * 32;
#pragma unroll
    for (int i = 0; i < 4; i++){
      gload16(asrc + (size_t)i*65536 + ko, adst + i*2048);
      gload16(bsrc + (size_t)i*65536 + ko, bdst + i*2048);
    }
    __syncthreads();   // drains vmcnt, LDS(kt) ready

    bf16x8 ah[4], al[4], bh[4], bl[4];
#pragma unroll
    for (int m = 0; m < 4; m++){
      ah[m] = *(const bf16x8*)&lds[aoff[m]];
      al[m] = *(const bf16x8*)&lds[aoff[m] ^ 32];
    }
#pragma unroll
    for (int n = 0; n < 4; n++){
      bh[n] = *(const bf16x8*)&lds[boff[n]];
      bl[n] = *(const bf16x8*)&lds[boff[n] ^ 32];
    }
#pragma unroll
    for (int m = 0; m < 4; m++)
#pragma unroll
      for (int n = 0; n < 4; n++){
        acc[m][n] = __builtin_amdgcn_mfma_f32_16x16x32_bf16(ah[m], bh[n], acc[m][n], 0, 0, 0);
        acc[m][n] = __builtin_amdgcn_mfma_f32_16x16x32_bf16(ah[m], bl[n], acc[m][n], 0, 0, 0);
        acc[m][n] = __builtin_amdgcn_mfma_f32_16x16x32_bf16(al[m], bh[n], acc[m][n], 0, 0, 0);
      }
    __syncthreads();   // all waves done reading before next stage overwrites
  }

  // ---- epilogue: bias + leakyrelu(0.01) + bf16 store. C/D: col=lane&15, row=(lane>>4)*4+reg
  float bv[4];
#pragma unroll
  for (int n = 0; n < 4; n++) bv[n] = bias[bcol + wn + n*16 + fr];
#pragma unroll
  for (int m = 0; m < 4; m++){
    const int row0 = brow + wm + m*16 + kc*4;
#pragma unroll
    for (int n = 0; n < 4; n++){
      const int col = bcol + wn + n*16 + fr;
#pragma unroll
      for (int r = 0; r < 4; r++){
        float v = acc[m][n][r] + bv[n];
        v = lrelu(v, 0.01f);
        Cout[(size_t)(row0 + r)*2048 + col] = f2bf(v);
      }
    }
  }
}

// ---------------- fp32 tiled GEMM (optionally bf16 A): C[z] = op(A[z] @ B[z] ...) ----------------
template<int ACT, bool HASBIAS, bool BETA1, bool BF16A>
__global__ __launch_bounds__(256) void k_gemm(
    const float* __restrict__ A, int lda, size_t az,
    const float* __restrict__ B, int ldb, size_t bz,
    float* __restrict__ C, int ldc, size_t cz,
    const float* __restrict__ bias, int biasz, int K)
{
  constexpr int BM = 128, BN = 128, BK = 16, TM = 8, TN = 8;
  __shared__ float As[BK][BM + 4];
  __shared__ float Bs[BK][BN + 4];
  const int z = blockIdx.z;
  B += (size_t)z * bz; C += (size_t)z * cz;
  const unsigned short* Au = (const unsigned short*)A + (size_t)z * az;
  const float* Af = A + (size_t)z * az;
  const int brow = blockIdx.y * BM, bcol = blockIdx.x * BN;
  const int tid = threadIdx.x;
  const int tx = tid & 15, ty = tid >> 4;
  const int ar = tid >> 2, ac4 = (tid & 3) * 4;
  const int br = tid >> 5, bc4 = (tid & 31) * 4;
  float acc[TM][TN] = {};

  for (int kt = 0; kt < K; kt += BK){
#pragma unroll
    for (int rr = 0; rr < BM; rr += 64){
      if (BF16A){
        ushort4 u = *(const ushort4*)&Au[(size_t)(brow + ar + rr) * lda + kt + ac4];
        As[ac4 + 0][ar + rr] = bf2f(u.x); As[ac4 + 1][ar + rr] = bf2f(u.y);
        As[ac4 + 2][ar + rr] = bf2f(u.z); As[ac4 + 3][ar + rr] = bf2f(u.w);
      } else {
        float4 v = *(const float4*)&Af[(size_t)(brow + ar + rr) * lda + kt + ac4];
        As[ac4 + 0][ar + rr] = v.x; As[ac4 + 1][ar + rr] = v.y;
        As[ac4 + 2][ar + rr] = v.z; As[ac4 + 3][ar + rr] = v.w;
      }
    }
#pragma unroll
    for (int rr = 0; rr < BK; rr += 8){
      *(float4*)&Bs[br + rr][bc4] = *(const float4*)&B[(size_t)(kt + br + rr) * ldb + bcol + bc4];
    }
    __syncthreads();
#pragma unroll
    for (int k = 0; k < BK; k++){
      float af[TM], bf[TN];
#pragma unroll
      for (int i = 0; i < TM; i++) af[i] = As[k][ty*TM + i];
#pragma unroll
      for (int j = 0; j < TN; j++) bf[j] = Bs[k][tx*TN + j];
#pragma unroll
      for (int i = 0; i < TM; i++)
#pragma unroll
        for (int j = 0; j < TN; j++) acc[i][j] = fmaf(af[i], bf[j], acc[i][j]);
    }
    __syncthreads();
  }
#pragma unroll
  for (int i = 0; i < TM; i++){
    const int row = brow + ty*TM + i;
#pragma unroll
    for (int j = 0; j < TN; j += 4){
      const int col = bcol + tx*TN + j;
      float4 v = { acc[i][j], acc[i][j+1], acc[i][j+2], acc[i][j+3] };
      if (HASBIAS){
        v.x += bias[(size_t)z*biasz + col + 0]; v.y += bias[(size_t)z*biasz + col + 1];
        v.z += bias[(size_t)z*biasz + col + 2]; v.w += bias[(size_t)z*biasz + col + 3];
      }
      if (ACT == 1){
        v.x = lrelu(v.x, 0.01f); v.y = lrelu(v.y, 0.01f);
        v.z = lrelu(v.z, 0.01f); v.w = lrelu(v.w, 0.01f);
      }
      float* cp = &C[(size_t)row * ldc + col];
      if (BETA1){
        float4 o = *(const float4*)cp;
        v.x += o.x; v.y += o.y; v.z += o.z; v.w += o.w;
      }
      *(float4*)cp = v;
    }
  }
}

// final: y = leaky(sum_z ypart[z] + bout); per-graph mean over sorted batch
__global__ void k_final(const float* __restrict__ yp, const float* __restrict__ bout,
                        const int* __restrict__ batch, float* __restrict__ out){
  const int g = blockIdx.x, t = threadIdx.x;
  __shared__ int sb[2];
  if (t < 2){
    int key = g + t, lo = 0, hi = Nn;
    while (lo < hi){ int mid = (lo + hi) >> 1; if (batch[mid] < key) lo = mid + 1; else hi = mid; }
    sb[t] = lo;
  }
  __syncthreads();
  const int b = sb[0], e = sb[1];
  const size_t P = (size_t)Nn * 256;
  float s = 0.f;
  for (int n = b; n < e; ++n){
    size_t i = (size_t)n*256 + t;
    float v = yp[i] + yp[P + i] + yp[2*P + i] + yp[3*P + i] + bout[t];
    s += lrelu(v, 0.01f);
  }
  out[g*256 + t] = s / fmaxf((float)(e - b), 1.f);
}

// ---------------- launch ----------------
extern "C" void kernel_launch(void* const* d_in, const int* in_sizes, int n_in,
                              void* d_out, int out_size, void* d_ws, size_t ws_size,
                              hipStream_t stream){
  const float* xg    = (const float*)d_in[0];
  const float* ac    = (const float*)d_in[1];
  const float* ti    = (const float*)d_in[2];
  const float* eattr = (const float*)d_in[3];
  const int*   ei    = (const int*)  d_in[4];
  const int*   batch = (const int*)  d_in[5];
  const float* W1    = (const float*)d_in[6];
  const float* as1w  = (const float*)d_in[7];
  const float* ad1w  = (const float*)d_in[8];
  const float* ae1w  = (const float*)d_in[9];
  const float* We1   = (const float*)d_in[10];
  const float* b1    = (const float*)d_in[11];
  const float* W2    = (const float*)d_in[12];
  const float* as2w  = (const float*)d_in[13];
  const float* ad2w  = (const float*)d_in[14];
  const float* ae2w  = (const float*)d_in[15];
  const float* We2   = (const float*)d_in[16];
  const float* b2    = (const float*)d_in[17];
  const float* Wout  = (const float*)d_in[18];
  const float* bout  = (const float*)d_in[19];
  float* out = (float*)d_out;
  float* ws  = (float*)d_ws;
  if (ws_size < WS_FLOATS * sizeof(float)) return;
  int* iws = (int*)(ws + OFF_I);

  unsigned short* zhi = (unsigned short*)(ws + OFF_ZHI);
  unsigned short* zlo = (unsigned short*)(ws + OFF_ZLO);
  unsigned short* whi = (unsigned short*)(ws + OFF_X);
  unsigned short* wlo = (unsigned short*)(ws + OFF_WLO);
  unsigned short* x3h = (unsigned short*)(ws + OFF_X3H);

  hipMemsetAsync(iws + I_DEG, 0, Nn * sizeof(int), stream);
  k_concat <<<8192, 256, 0, stream>>>(xg, ac, ti, ws + OFF_X);
  k_count  <<<128,  256, 0, stream>>>(ei, iws + I_DEG);
  k_scan   <<<1,   1024, 0, stream>>>(iws + I_DEG, iws + I_RP, iws + I_CUR);
  k_fill   <<<144,  256, 0, stream>>>(ei, iws + I_CUR, iws + I_EID);
  k_sort   <<<16,   256, 0, stream>>>(iws + I_RP, iws + I_EID);
  k_loopattr<<<256, 256, 0, stream>>>(eattr, iws + I_RP, iws + I_EID, ws + OFF_LP);

  k_proj   <<<512,  256, 0, stream>>>(W1, as1w, ad1w, ws + OFF_WS1, ws + OFF_WD1, 512, 512);
  k_proj   <<<2048, 256, 0, stream>>>(W2, as2w, ad2w, ws + OFF_WS2, ws + OFF_WD2, 2048, 2048);
  k_aeproj <<<16,   256, 0, stream>>>(We1, ae1w, ws + OFF_AE1, 512);
  k_aeproj <<<16,   256, 0, stream>>>(We2, ae2w, ws + OFF_AE2, 2048);

  // ---- layer 1 ----
  k_asad   <<<4096, 256, 0, stream>>>(ws + OFF_X, ws + OFF_WS1, ws + OFF_WD1, ws + OFF_AS1, ws + OFF_AD1, 512);
  k_edge   <<<144,  256, 0, stream>>>(eattr, ws + OFF_LP, ei, ws + OFF_AS1, ws + OFF_AD1, ws + OFF_AE1, ws + OFF_EB);
  k_softmax<<<16,   256, 0, stream>>>(iws + I_RP, iws + I_EID, ws + OFF_EB, ws + OFF_AL);
  k_agg1   <<<4096, 256, 0, stream>>>(ws + OFF_X, ws + OFF_AL, iws + I_RP, iws + I_EID, ei, ws + OFF_Z1);
  k_gemm<1, true, false, false><<<dim3(4, 32, 4), 256, 0, stream>>>(
      ws + OFF_Z1, 2048, 512,  W1, 2048, 512,  ws + OFF_X2, 2048, 512,  b1, 512, 512);

  // ---- layer 2 attention ----
  k_asad   <<<4096, 256, 0, stream>>>(ws + OFF_X2, ws + OFF_WS2, ws + OFF_WD2, ws + OFF_AS2, ws + OFF_AD2, 2048);
  k_edge   <<<144,  256, 0, stream>>>(eattr, ws + OFF_LP, ei, ws + OFF_AS2, ws + OFF_AD2, ws + OFF_AE2, ws + OFF_EB);
  k_softmax<<<16,   256, 0, stream>>>(iws + I_RP, iws + I_EID, ws + OFF_EB, ws + OFF_AL);

  // ---- layer 2 + fc, per head ----
  for (int h = 0; h < 4; ++h){
    k_wsplit_t    <<<dim3(64, 64), 256, 0, stream>>>(W2, h, whi, wlo);
    k_agg2h_split <<<4096, 256, 0, stream>>>(ws + OFF_X2, ws + OFF_AL, iws + I_RP, iws + I_EID, ei, zhi, zlo, h);
    k_gemm2       <<<dim3(16, 32), 256, 0, stream>>>(zhi, zlo, whi, wlo, x3h, b2 + (size_t)h*2048);
    if (h == 0)
      k_gemm<0, false, false, true><<<dim3(2, 32, 4), 256, 0, stream>>>(
          (const float*)x3h, 2048, 512,  Wout + (size_t)h*2048*256, 256, (size_t)512*256,
          ws + OFF_YP, 256, (size_t)Nn*256,  nullptr, 0, 512);
    else
      k_gemm<0, false, true, true><<<dim3(2, 32, 4), 256, 0, stream>>>(
          (const float*)x3h, 2048, 512,  Wout + (size_t)h*2048*256, 256, (size_t)512*256,
          ws + OFF_YP, 256, (size_t)Nn*256,  nullptr, 0, 512);
  }

  k_final<<<8, 256, 0, stream>>>(ws + OFF_YP, bout, batch, out);
}

// Round 4
// 1107.140 us; speedup vs baseline: 2.6660x; 1.3476x over previous
//
#include <hip/hip_runtime.h>
#include <math.h>

constexpr int Nn  = 4096;
constexpr int Ne  = 32768;
constexpr int NEf = Ne + Nn;     // real edges + self loops

// ---------------- ws layout (float offsets) ----------------
// region reuse timeline:
//   [0..2097152)        X fp32 (prep/L1) -> wt1 hi/lo bf16 (L1 gemm) -> whi bf16 [2048][2048] (L2 loop)
//   [2097152..10485760) z1 hi/lo bf16 (L1) -> zhi/zlo bf16 [4096][2048] (L2 loop) -> part fp32 (final)
//   [10485760..18874368)  X2 fp32
//   [18874368..23068672)  x3h bf16 [4096][2048]
//   [23068672..25165824)  wh_lo bf16 (L2 loop)
//   [25165824..27262976)  wtout hi/lo bf16 [256][8192]
//   [27262976..31457280)  YP 4x [4096][256] fp32
constexpr size_t OFF_X    = 0;
constexpr size_t OFF_WT1H = 0;
constexpr size_t OFF_WT1L = 524288;
constexpr size_t OFF_Z1HI = 2097152;
constexpr size_t OFF_Z1LO = 6291456;
constexpr size_t OFF_ZHI  = 2097152;
constexpr size_t OFF_ZLO  = 6291456;
constexpr size_t OFF_PART = 2097152;     // 8*32*256 fp32 (final)
constexpr size_t OFF_X2   = 10485760;
constexpr size_t OFF_X3H  = 18874368;    // ushort region (bf16)
constexpr size_t OFF_WLO  = 23068672;    // ushort region
constexpr size_t OFF_WOH  = 25165824;    // ushort region [256][8192]
constexpr size_t OFF_WOL  = 26214400;    // ushort region
constexpr size_t OFF_YP   = 27262976;
constexpr size_t OFF_LP  = 31457280;     // [N,16] self-loop edge attr
constexpr size_t OFF_WS1 = OFF_LP  + 65536;   // [512,4]
constexpr size_t OFF_WD1 = OFF_WS1 + 2048;    // [512,4]
constexpr size_t OFF_WS2 = OFF_WD1 + 2048;    // [2048,4]
constexpr size_t OFF_WD2 = OFF_WS2 + 8192;    // [2048,4]
constexpr size_t OFF_AE1 = OFF_WD2 + 8192;    // [16,4]
constexpr size_t OFF_AE2 = OFF_AE1 + 64;      // [16,4]
constexpr size_t OFF_AS1 = OFF_AE2 + 64;      // [N,4]
constexpr size_t OFF_AD1 = OFF_AS1 + 16384;
constexpr size_t OFF_AS2 = OFF_AD1 + 16384;
constexpr size_t OFF_AD2 = OFF_AS2 + 16384;
constexpr size_t OFF_EB  = OFF_AD2 + 16384;          // [Ef,4] logits
constexpr size_t OFF_AL  = OFF_EB  + (size_t)NEf*4;  // [Ef,4] alpha
constexpr size_t OFF_I   = OFF_AL  + (size_t)NEf*4;  // int region
constexpr size_t I_DEG = 0;       // [N]
constexpr size_t I_RP  = 4096;    // [N+1] (+pad)
constexpr size_t I_CUR = 8200;    // [N]
constexpr size_t I_EID = 12296;   // [Ef]
constexpr size_t WS_FLOATS = OFF_I + I_EID + (size_t)NEf + 64;

using bf16x8 = __bf16 __attribute__((ext_vector_type(8)));
using f32x4  = float __attribute__((ext_vector_type(4)));

__device__ __forceinline__ float wred64(float v){
#pragma unroll
  for (int o = 32; o > 0; o >>= 1) v += __shfl_down(v, o, 64);
  return v;
}
__device__ __forceinline__ float lrelu(float v, float s){ return v > 0.f ? v : s * v; }

__device__ __forceinline__ unsigned short f2bf(float x){  // RTNE
  unsigned int u = __float_as_uint(x);
  unsigned int r = (u + 0x7FFFu + ((u >> 16) & 1u)) >> 16;
  return (unsigned short)r;
}
__device__ __forceinline__ float bf2f(unsigned short h){
  return __uint_as_float((unsigned int)h << 16);
}
__device__ __forceinline__ void split2(float x, unsigned short& h, unsigned short& l){
  h = f2bf(x);
  l = f2bf(x - bf2f(h));
}
__device__ __forceinline__ void gload16(const void* g, void* l){
  __builtin_amdgcn_global_load_lds((const __attribute__((address_space(1))) void*)g,
                                   (__attribute__((address_space(3))) void*)l, 16, 0, 0);
}

// ---------------- small prep kernels ----------------
__global__ void k_concat(const float* __restrict__ xg, const float* __restrict__ ac,
                         const float* __restrict__ ti, float* __restrict__ x){
  int i = blockIdx.x * 256 + threadIdx.x;          // over N*512
  int n = i >> 9, c = i & 511;
  float v;
  if (c < 256)      v = xg[(size_t)n*256 + c];
  else if (c < 384) v = ac[(size_t)n*128 + (c-256)];
  else              v = ti[(size_t)n*128 + (c-384)];
  x[i] = v;
}

__global__ void k_count(const int* __restrict__ ei, int* __restrict__ deg){
  int e = blockIdx.x * 256 + threadIdx.x;
  if (e < Ne) atomicAdd(&deg[ei[Ne + e]], 1);
}

__global__ void k_scan(const int* __restrict__ deg, int* __restrict__ rowptr, int* __restrict__ cursor){
  __shared__ int sd[1024];
  int t = threadIdx.x;
  int v[4]; int s = 0;
#pragma unroll
  for (int i = 0; i < 4; i++){ v[i] = s; s += deg[t*4 + i] + 1; }   // +1 self loop
  sd[t] = s;
  __syncthreads();
  for (int off = 1; off < 1024; off <<= 1){
    int x = (t >= off) ? sd[t - off] : 0;
    __syncthreads();
    sd[t] += x;
    __syncthreads();
  }
  int base = (t == 0) ? 0 : sd[t - 1];
#pragma unroll
  for (int i = 0; i < 4; i++){ int rp = base + v[i]; rowptr[t*4 + i] = rp; cursor[t*4 + i] = rp; }
  if (t == 1023) rowptr[4096] = sd[1023];
}

__global__ void k_fill(const int* __restrict__ ei, int* __restrict__ cursor, int* __restrict__ eids){
  int e = blockIdx.x * 256 + threadIdx.x;
  if (e >= NEf) return;
  int d = (e < Ne) ? ei[Ne + e] : (e - Ne);
  int p = atomicAdd(&cursor[d], 1);
  eids[p] = e;
}

__global__ void k_sort(const int* __restrict__ rowptr, int* __restrict__ eids){
  int n = blockIdx.x * 256 + threadIdx.x;
  if (n >= Nn) return;
  int b = rowptr[n], e = rowptr[n + 1];
  for (int i = b + 1; i < e; i++){
    int key = eids[i]; int j = i - 1;
    while (j >= b && eids[j] > key){ eids[j+1] = eids[j]; j--; }
    eids[j+1] = key;
  }
}

__global__ void k_loopattr(const float* __restrict__ eattr, const int* __restrict__ rowptr,
                           const int* __restrict__ eids, float* __restrict__ lp){
  int idx = blockIdx.x * 256 + threadIdx.x;        // N*16
  int n = idx >> 4, a = idx & 15;
  if (n >= Nn) return;
  int b = rowptr[n], e = rowptr[n + 1];
  float s = 0.f; int cnt = 0;
  for (int j = b; j < e; ++j){
    int id = eids[j];
    if (id < Ne){ s += eattr[(size_t)id*16 + a]; cnt++; }
  }
  lp[(size_t)n*16 + a] = s / fmaxf((float)cnt, 1.f);
}

// Ws[k,h] = sum_c W[k, h*C+c]*a_s[h,c] ; Wd likewise.
__global__ void k_proj(const float* __restrict__ W, const float* __restrict__ a_s,
                       const float* __restrict__ a_d, float* __restrict__ Ws,
                       float* __restrict__ Wd, int K, int C){
  int gid = blockIdx.x * 256 + threadIdx.x;
  int wave = gid >> 6, lane = gid & 63;
  int h = wave & 3, k = wave >> 2;
  if (k >= K) return;
  const float* wrow = W + (size_t)k * (4*C) + (size_t)h * C;
  const float* ar = a_s + (size_t)h * C;
  const float* dr = a_d + (size_t)h * C;
  float ps = 0.f, pd = 0.f;
  for (int c = lane; c < C; c += 64){ float w = wrow[c]; ps += w * ar[c]; pd += w * dr[c]; }
  ps = wred64(ps); pd = wred64(pd);
  if (lane == 0){ Ws[k*4 + h] = ps; Wd[k*4 + h] = pd; }
}

// one wave per (k,h): outp[k*4+h] = dot(We[k, h*C:(h+1)*C], ae[h,:])
__global__ void k_aeproj(const float* __restrict__ We, const float* __restrict__ ae,
                         float* __restrict__ outp, int C){
  int gid = blockIdx.x * 256 + threadIdx.x;
  int wave = gid >> 6, lane = gid & 63;
  int h = wave & 3, k = wave >> 2;
  if (k >= 16) return;
  const float* wrow = We + (size_t)k * (4*C) + (size_t)h * C;
  const float* ar = ae + (size_t)h * C;
  float s = 0.f;
  for (int c = lane; c < C; c += 64) s += wrow[c] * ar[c];
  s = wred64(s);
  if (lane == 0) outp[k*4 + h] = s;
}

// as[n,h], ad[n,h] = x[n,:] @ Ws/Wd. Block per node.
__global__ __launch_bounds__(256) void k_asad(const float* __restrict__ x, const float* __restrict__ Ws,
                      const float* __restrict__ Wd, float* __restrict__ as_,
                      float* __restrict__ ad_, int D){
  int n = blockIdx.x, t = threadIdx.x;
  const float* row = x + (size_t)n * D;
  float p[8] = {0,0,0,0,0,0,0,0};
  for (int c = t; c < D; c += 256){
    float xv = row[c];
    float4 ws4 = *(const float4*)&Ws[c*4];
    float4 wd4 = *(const float4*)&Wd[c*4];
    p[0] += xv * ws4.x; p[1] += xv * ws4.y; p[2] += xv * ws4.z; p[3] += xv * ws4.w;
    p[4] += xv * wd4.x; p[5] += xv * wd4.y; p[6] += xv * wd4.z; p[7] += xv * wd4.w;
  }
  __shared__ float sm[4][8];
  int lane = t & 63, wid = t >> 6;
#pragma unroll
  for (int q = 0; q < 8; q++){
    float v = wred64(p[q]);
    if (lane == 0) sm[wid][q] = v;
  }
  __syncthreads();
  if (t < 8){
    float s = sm[0][t] + sm[1][t] + sm[2][t] + sm[3][t];
    if (t < 4) as_[(size_t)n*4 + t] = s;
    else       ad_[(size_t)n*4 + (t-4)] = s;
  }
}

__global__ void k_edge(const float* __restrict__ eattr, const float* __restrict__ lp,
                       const int* __restrict__ ei, const float* __restrict__ as_,
                       const float* __restrict__ ad_, const float* __restrict__ aep,
                       float* __restrict__ ebuf){
  int e = blockIdx.x * 256 + threadIdx.x;
  if (e >= NEf) return;
  int s, d; const float* ea;
  if (e < Ne){ s = ei[e]; d = ei[Ne + e]; ea = eattr + (size_t)e * 16; }
  else { s = e - Ne; d = e - Ne; ea = lp + (size_t)(e - Ne) * 16; }
  float eav[16];
#pragma unroll
  for (int k = 0; k < 16; k++) eav[k] = ea[k];
#pragma unroll
  for (int h = 0; h < 4; h++){
    float v = as_[(size_t)s*4 + h] + ad_[(size_t)d*4 + h];
#pragma unroll
    for (int k = 0; k < 16; k++) v += eav[k] * aep[k*4 + h];
    ebuf[(size_t)e*4 + h] = lrelu(v, 0.2f);
  }
}

__global__ void k_softmax(const int* __restrict__ rowptr, const int* __restrict__ eids,
                          const float* __restrict__ ebuf, float* __restrict__ alpha){
  int n = blockIdx.x * 256 + threadIdx.x;
  if (n >= Nn) return;
  int b = rowptr[n], e = rowptr[n + 1];
#pragma unroll
  for (int h = 0; h < 4; h++){
    float m = -1e30f;
    for (int j = b; j < e; ++j) m = fmaxf(m, ebuf[(size_t)eids[j]*4 + h]);
    float ss = 0.f;
    for (int j = b; j < e; ++j){
      float ex = expf(ebuf[(size_t)eids[j]*4 + h] - m);
      alpha[(size_t)eids[j]*4 + h] = ex; ss += ex;
    }
    for (int j = b; j < e; ++j) alpha[(size_t)eids[j]*4 + h] /= ss;
  }
}

// z1[n, h*512+c] = sum_e alpha[e,h] * x[src(e),c], written bf16 hi/lo split
__global__ __launch_bounds__(256) void k_agg1_split(const float* __restrict__ x, const float* __restrict__ alpha,
                      const int* __restrict__ rowptr, const int* __restrict__ eids,
                      const int* __restrict__ ei, unsigned short* __restrict__ z1hi,
                      unsigned short* __restrict__ z1lo){
  int n = blockIdx.x, t = threadIdx.x;
  float2 a0 = {0,0}, a1 = {0,0}, a2 = {0,0}, a3 = {0,0};
  int b = rowptr[n], e = rowptr[n + 1];
  for (int j = b; j < e; ++j){
    int eid = eids[j];
    int s = (eid < Ne) ? ei[eid] : (eid - Ne);
    float4 av = *(const float4*)&alpha[(size_t)eid*4];
    float2 xv = *(const float2*)&x[(size_t)s*512 + t*2];
    a0.x += av.x*xv.x; a0.y += av.x*xv.y;
    a1.x += av.y*xv.x; a1.y += av.y*xv.y;
    a2.x += av.z*xv.x; a2.y += av.z*xv.y;
    a3.x += av.w*xv.x; a3.y += av.w*xv.y;
  }
  size_t base = (size_t)n*2048 + t*2;
  float2 av[4] = {a0, a1, a2, a3};
#pragma unroll
  for (int h = 0; h < 4; h++){
    ushort2 hh, ll;
    split2(av[h].x, hh.x, ll.x);
    split2(av[h].y, hh.y, ll.y);
    *(ushort2*)&z1hi[base + h*512] = hh;
    *(ushort2*)&z1lo[base + h*512] = ll;
  }
}

// z2h = sum_e alpha[e,h] * x2[src(e),:] for ONE head, written as bf16 hi/lo split
__global__ __launch_bounds__(256) void k_agg2h_split(const float* __restrict__ x2, const float* __restrict__ alpha,
                       const int* __restrict__ rowptr, const int* __restrict__ eids,
                       const int* __restrict__ ei, unsigned short* __restrict__ zhi,
                       unsigned short* __restrict__ zlo, int h){
  int n = blockIdx.x, t = threadIdx.x;
  float acc[8] = {0,0,0,0,0,0,0,0};
  int b = rowptr[n], e = rowptr[n + 1];
  for (int j = b; j < e; ++j){
    int eid = eids[j];
    int s = (eid < Ne) ? ei[eid] : (eid - Ne);
    float a = alpha[(size_t)eid*4 + h];
    const float* xr = x2 + (size_t)s*2048 + t*8;
    float4 xa = *(const float4*)xr;
    float4 xb = *(const float4*)(xr + 4);
    acc[0] += a*xa.x; acc[1] += a*xa.y; acc[2] += a*xa.z; acc[3] += a*xa.w;
    acc[4] += a*xb.x; acc[5] += a*xb.y; acc[6] += a*xb.z; acc[7] += a*xb.w;
  }
  size_t base = (size_t)n*2048 + t*8;
  ushort4 h0, h1, l0, l1;
  split2(acc[0], h0.x, l0.x); split2(acc[1], h0.y, l0.y);
  split2(acc[2], h0.z, l0.z); split2(acc[3], h0.w, l0.w);
  split2(acc[4], h1.x, l1.x); split2(acc[5], h1.y, l1.y);
  split2(acc[6], h1.z, l1.z); split2(acc[7], h1.w, l1.w);
  *(ushort4*)&zhi[base]     = h0; *(ushort4*)&zhi[base + 4] = h1;
  *(ushort4*)&zlo[base]     = l0; *(ushort4*)&zlo[base + 4] = l1;
}

// transpose + bf16-split: out[col][k] = split(W[k][coloff+col]); out stride K
__global__ __launch_bounds__(256) void k_wsplit(const float* __restrict__ W, int ldw, int coloff, int K,
                       unsigned short* __restrict__ whi, unsigned short* __restrict__ wlo){
  __shared__ float tile[32][33];
  int bk = blockIdx.x * 32, bn = blockIdx.y * 32;
  int tx = threadIdx.x & 31, ty = threadIdx.x >> 5;
#pragma unroll
  for (int i = 0; i < 4; i++){
    int k = bk + ty + i*8;
    tile[ty + i*8][tx] = W[(size_t)k*ldw + coloff + bn + tx];
  }
  __syncthreads();
#pragma unroll
  for (int i = 0; i < 4; i++){
    int n = bn + ty + i*8;
    float v = tile[tx][ty + i*8];
    unsigned short hh, ll; split2(v, hh, ll);
    whi[(size_t)n*K + bk + tx] = hh;
    wlo[(size_t)n*K + bk + tx] = ll;
  }
}

// ---------------- MFMA GEMM, 3-term (or 2-term exact-A) bf16 split ----------------
// C = act(A x B^T + bias [+C]); A[M rows][lda], B[cols][ldb] both bf16 hi/lo, K = KLEN per z.
// LDS tile/block: [128 rows][8 chunks of 16B]; chunks 0-3 hi(k0..31), 4-7 lo.
// physical chunk = logical ^ (row&7); swizzle folded into global source, LDS dest linear.
template<int KLEN, bool EXACTA, bool OUTF32, bool BETA1, bool ACT, bool HASBIAS>
__global__ __launch_bounds__(256) void k_gemm2(
    const unsigned short* __restrict__ Ah, const unsigned short* __restrict__ Al, int lda, size_t az,
    const unsigned short* __restrict__ Bh, const unsigned short* __restrict__ Bl, int ldb, size_t bz,
    void* __restrict__ Cout, int ldc, size_t cz,
    const float* __restrict__ bias, size_t biasz)
{
  __shared__ unsigned short lds[16384];   // A: [0,8192) ushorts, B: [8192,16384)
  const int t = threadIdx.x;
  const int z = blockIdx.z;
  const int brow = blockIdx.y * 128, bcol = blockIdx.x * 128;
  const int wid = t >> 6, lane = t & 63;
  const int wm = (wid >> 1) * 64, wn = (wid & 1) * 64;

  // ---- staging mapping: slot s = i*256+t -> row=i*32+(t>>3), phys chunk c=t&7
  const int sr = t >> 3, sc = t & 7;
  const int scc = sc ^ (sr & 7);   // logical chunk (invariant over i since 32%8==0)
  const unsigned short* asrc = (scc < 4 ? Ah : Al) + (size_t)(brow + sr)*lda + (size_t)z*az + (size_t)(scc & 3)*8;
  const unsigned short* bsrc = (scc < 4 ? Bh : Bl) + (size_t)(bcol + sr)*ldb + (size_t)z*bz + (size_t)(scc & 3)*8;
  unsigned short* adst = &lds[(size_t)wid * 512];          // + i*2048 ; lane*16B implicit
  unsigned short* bdst = &lds[8192 + (size_t)wid * 512];

  // ---- fragment read addressing (ushort units)
  const int fr = lane & 15, kc = lane >> 4;
  const int swz = ((kc ^ (lane & 7)) << 3);
  int aoff[4], boff[4];
#pragma unroll
  for (int m = 0; m < 4; m++) aoff[m] = (wm + m*16 + fr)*64 + swz;
#pragma unroll
  for (int n = 0; n < 4; n++) boff[n] = 8192 + (wn + n*16 + fr)*64 + swz;

  f32x4 acc[4][4];
#pragma unroll
  for (int m = 0; m < 4; m++)
#pragma unroll
    for (int n = 0; n < 4; n++) acc[m][n] = f32x4{0.f, 0.f, 0.f, 0.f};

  for (int kt = 0; kt < KLEN/32; ++kt){
    const size_t ko = (size_t)kt * 32;
#pragma unroll
    for (int i = 0; i < 4; i++){
      gload16(asrc + (size_t)i*32*lda + ko, adst + i*2048);
      gload16(bsrc + (size_t)i*32*ldb + ko, bdst + i*2048);
    }
    __syncthreads();   // drains vmcnt, LDS(kt) ready

    bf16x8 ah[4], al[4], bh[4], bl[4];
#pragma unroll
    for (int m = 0; m < 4; m++){
      ah[m] = *(const bf16x8*)&lds[aoff[m]];
      if (!EXACTA) al[m] = *(const bf16x8*)&lds[aoff[m] ^ 32];
    }
#pragma unroll
    for (int n = 0; n < 4; n++){
      bh[n] = *(const bf16x8*)&lds[boff[n]];
      bl[n] = *(const bf16x8*)&lds[boff[n] ^ 32];
    }
#pragma unroll
    for (int m = 0; m < 4; m++)
#pragma unroll
      for (int n = 0; n < 4; n++){
        acc[m][n] = __builtin_amdgcn_mfma_f32_16x16x32_bf16(ah[m], bh[n], acc[m][n], 0, 0, 0);
        acc[m][n] = __builtin_amdgcn_mfma_f32_16x16x32_bf16(ah[m], bl[n], acc[m][n], 0, 0, 0);
        if (!EXACTA)
          acc[m][n] = __builtin_amdgcn_mfma_f32_16x16x32_bf16(al[m], bh[n], acc[m][n], 0, 0, 0);
      }
    __syncthreads();   // all waves done reading before next stage overwrites
  }

  // ---- epilogue. C/D frag: col=lane&15, row=(lane>>4)*4+reg
  float bv[4] = {0.f, 0.f, 0.f, 0.f};
  if (HASBIAS){
#pragma unroll
    for (int n = 0; n < 4; n++) bv[n] = bias[(size_t)z*biasz + bcol + wn + n*16 + fr];
  }
  float* Cf = (float*)Cout + (size_t)z*cz;
  unsigned short* Cb = (unsigned short*)Cout + (size_t)z*cz;
#pragma unroll
  for (int m = 0; m < 4; m++){
    const int row0 = brow + wm + m*16 + kc*4;
#pragma unroll
    for (int n = 0; n < 4; n++){
      const int col = bcol + wn + n*16 + fr;
#pragma unroll
      for (int r = 0; r < 4; r++){
        float v = acc[m][n][r] + bv[n];
        if (ACT) v = lrelu(v, 0.01f);
        if (OUTF32){
          float* cp = &Cf[(size_t)(row0 + r)*ldc + col];
          if (BETA1) v += *cp;
          *cp = v;
        } else {
          Cb[(size_t)(row0 + r)*ldc + col] = f2bf(v);
        }
      }
    }
  }
}

// stage 1: per (slice, graph) partial sum of lrelu(sum_z YP + bout) over stride-32 node slices
__global__ void k_gsum(const float* __restrict__ yp, const float* __restrict__ bout,
                       const int* __restrict__ batch, float* __restrict__ part){
  const int s = blockIdx.x, g = blockIdx.y, t = threadIdx.x;
  __shared__ int sb[2];
  if (t < 2){
    int key = g + t, lo = 0, hi = Nn;
    while (lo < hi){ int mid = (lo + hi) >> 1; if (batch[mid] < key) lo = mid + 1; else hi = mid; }
    sb[t] = lo;
  }
  __syncthreads();
  const int b = sb[0], e = sb[1];
  const size_t P = (size_t)Nn * 256;
  float acc = 0.f;
  float bt = bout[t];
  for (int n = b + s; n < e; n += 32){
    size_t i = (size_t)n*256 + t;
    float v = yp[i] + yp[P + i] + yp[2*P + i] + yp[3*P + i] + bt;
    acc += lrelu(v, 0.01f);
  }
  part[(size_t)(g*32 + s)*256 + t] = acc;
}

// stage 2: sum 32 slices, divide by count
__global__ void k_gfin(const float* __restrict__ part, const int* __restrict__ batch,
                       float* __restrict__ out){
  const int g = blockIdx.x, t = threadIdx.x;
  __shared__ int sb[2];
  if (t < 2){
    int key = g + t, lo = 0, hi = Nn;
    while (lo < hi){ int mid = (lo + hi) >> 1; if (batch[mid] < key) lo = mid + 1; else hi = mid; }
    sb[t] = lo;
  }
  __syncthreads();
  const int cnt = sb[1] - sb[0];
  float s = 0.f;
#pragma unroll
  for (int k = 0; k < 32; k++) s += part[(size_t)(g*32 + k)*256 + t];
  out[g*256 + t] = s / fmaxf((float)cnt, 1.f);
}

// ---------------- launch ----------------
extern "C" void kernel_launch(void* const* d_in, const int* in_sizes, int n_in,
                              void* d_out, int out_size, void* d_ws, size_t ws_size,
                              hipStream_t stream){
  const float* xg    = (const float*)d_in[0];
  const float* ac    = (const float*)d_in[1];
  const float* ti    = (const float*)d_in[2];
  const float* eattr = (const float*)d_in[3];
  const int*   ei    = (const int*)  d_in[4];
  const int*   batch = (const int*)  d_in[5];
  const float* W1    = (const float*)d_in[6];
  const float* as1w  = (const float*)d_in[7];
  const float* ad1w  = (const float*)d_in[8];
  const float* ae1w  = (const float*)d_in[9];
  const float* We1   = (const float*)d_in[10];
  const float* b1    = (const float*)d_in[11];
  const float* W2    = (const float*)d_in[12];
  const float* as2w  = (const float*)d_in[13];
  const float* ad2w  = (const float*)d_in[14];
  const float* ae2w  = (const float*)d_in[15];
  const float* We2   = (const float*)d_in[16];
  const float* b2    = (const float*)d_in[17];
  const float* Wout  = (const float*)d_in[18];
  const float* bout  = (const float*)d_in[19];
  float* out = (float*)d_out;
  float* ws  = (float*)d_ws;
  if (ws_size < WS_FLOATS * sizeof(float)) return;
  int* iws = (int*)(ws + OFF_I);

  unsigned short* z1hi = (unsigned short*)(ws + OFF_Z1HI);
  unsigned short* z1lo = (unsigned short*)(ws + OFF_Z1LO);
  unsigned short* wt1h = (unsigned short*)(ws + OFF_WT1H);
  unsigned short* wt1l = (unsigned short*)(ws + OFF_WT1L);
  unsigned short* zhi  = (unsigned short*)(ws + OFF_ZHI);
  unsigned short* zlo  = (unsigned short*)(ws + OFF_ZLO);
  unsigned short* whi  = (unsigned short*)(ws + OFF_X);
  unsigned short* wlo  = (unsigned short*)(ws + OFF_WLO);
  unsigned short* woh  = (unsigned short*)(ws + OFF_WOH);
  unsigned short* wol  = (unsigned short*)(ws + OFF_WOL);
  unsigned short* x3h  = (unsigned short*)(ws + OFF_X3H);

  hipMemsetAsync(iws + I_DEG, 0, Nn * sizeof(int), stream);
  k_concat <<<8192, 256, 0, stream>>>(xg, ac, ti, ws + OFF_X);
  k_count  <<<128,  256, 0, stream>>>(ei, iws + I_DEG);
  k_scan   <<<1,   1024, 0, stream>>>(iws + I_DEG, iws + I_RP, iws + I_CUR);
  k_fill   <<<144,  256, 0, stream>>>(ei, iws + I_CUR, iws + I_EID);
  k_sort   <<<16,   256, 0, stream>>>(iws + I_RP, iws + I_EID);
  k_loopattr<<<256, 256, 0, stream>>>(eattr, iws + I_RP, iws + I_EID, ws + OFF_LP);

  k_proj   <<<512,  256, 0, stream>>>(W1, as1w, ad1w, ws + OFF_WS1, ws + OFF_WD1, 512, 512);
  k_proj   <<<2048, 256, 0, stream>>>(W2, as2w, ad2w, ws + OFF_WS2, ws + OFF_WD2, 2048, 2048);
  k_aeproj <<<16,   256, 0, stream>>>(We1, ae1w, ws + OFF_AE1, 512);
  k_aeproj <<<16,   256, 0, stream>>>(We2, ae2w, ws + OFF_AE2, 2048);
  k_wsplit <<<dim3(256, 8), 256, 0, stream>>>(Wout, 256, 0, 8192, woh, wol);   // wtout [256][8192]

  // ---- layer 1 ----
  k_asad      <<<4096, 256, 0, stream>>>(ws + OFF_X, ws + OFF_WS1, ws + OFF_WD1, ws + OFF_AS1, ws + OFF_AD1, 512);
  k_edge      <<<144,  256, 0, stream>>>(eattr, ws + OFF_LP, ei, ws + OFF_AS1, ws + OFF_AD1, ws + OFF_AE1, ws + OFF_EB);
  k_softmax   <<<16,   256, 0, stream>>>(iws + I_RP, iws + I_EID, ws + OFF_EB, ws + OFF_AL);
  k_agg1_split<<<4096, 256, 0, stream>>>(ws + OFF_X, ws + OFF_AL, iws + I_RP, iws + I_EID, ei, z1hi, z1lo);
  // X dead; wt1 overlays it
  k_wsplit <<<dim3(16, 64), 256, 0, stream>>>(W1, 2048, 0, 512, wt1h, wt1l);   // wt1 [2048][512]
  k_gemm2<512, false, true, false, true, true><<<dim3(4, 32, 4), 256, 0, stream>>>(
      z1hi, z1lo, 2048, 512,  wt1h, wt1l, 512, 512*512,
      ws + OFF_X2, 2048, 512,  b1, 512);

  // ---- layer 2 attention ----
  k_asad   <<<4096, 256, 0, stream>>>(ws + OFF_X2, ws + OFF_WS2, ws + OFF_WD2, ws + OFF_AS2, ws + OFF_AD2, 2048);
  k_edge   <<<144,  256, 0, stream>>>(eattr, ws + OFF_LP, ei, ws + OFF_AS2, ws + OFF_AD2, ws + OFF_AE2, ws + OFF_EB);
  k_softmax<<<16,   256, 0, stream>>>(iws + I_RP, iws + I_EID, ws + OFF_EB, ws + OFF_AL);

  // ---- layer 2 + fc, per head ----
  for (int h = 0; h < 4; ++h){
    k_wsplit      <<<dim3(64, 64), 256, 0, stream>>>(W2, 8192, h*2048, 2048, whi, wlo);
    k_agg2h_split <<<4096, 256, 0, stream>>>(ws + OFF_X2, ws + OFF_AL, iws + I_RP, iws + I_EID, ei, zhi, zlo, h);
    k_gemm2<2048, false, false, false, true, true><<<dim3(16, 32, 1), 256, 0, stream>>>(
        zhi, zlo, 2048, 0,  whi, wlo, 2048, 0,
        x3h, 2048, 0,  b2 + (size_t)h*2048, 0);
    if (h == 0)
      k_gemm2<512, true, true, false, false, false><<<dim3(2, 32, 4), 256, 0, stream>>>(
          x3h, x3h, 2048, 512,  woh + (size_t)h*2048, wol + (size_t)h*2048, 8192, 512,
          ws + OFF_YP, 256, (size_t)Nn*256,  nullptr, 0);
    else
      k_gemm2<512, true, true, true, false, false><<<dim3(2, 32, 4), 256, 0, stream>>>(
          x3h, x3h, 2048, 512,  woh + (size_t)h*2048, wol + (size_t)h*2048, 8192, 512,
          ws + OFF_YP, 256, (size_t)Nn*256,  nullptr, 0);
  }

  k_gsum<<<dim3(32, 8), 256, 0, stream>>>(ws + OFF_YP, bout, batch, ws + OFF_PART);
  k_gfin<<<8, 256, 0, stream>>>(ws + OFF_PART, batch, out);
}

// Round 5
// 1006.025 us; speedup vs baseline: 2.9339x; 1.1005x over previous
//
#include <hip/hip_runtime.h>
#include <math.h>

constexpr int Nn  = 4096;
constexpr int Ne  = 32768;
constexpr int NEf = Ne + Nn;     // real edges + self loops

// ---------------- ws layout (float offsets) ----------------
// region reuse timeline:
//   R0 [0..2097152)          X fp32 (prep/L1) -> wt1 hi/lo (L1 gemm) -> whi bf16 [2048][2048] (L2 loop)
//   R1 [2097152..10485760)   z1 hi/lo bf16 (L1) -> x2hi/x2lo bf16 [4096][2048] (L2) -> part fp32 (final)
//   R2 [10485760..18874368)  X2 fp32 -> x3h bf16 [4096][2048] (L2 loop, after split)
//   R3 [18874368..23068672)  H bf16 [4096][2048] (L2 loop)
//   R4 [23068672..25165824)  wlo bf16 (L2 loop)
//   R5 [25165824..27262976)  wtout hi/lo bf16 [256][8192]
//   R6 [27262976..31457280)  YP 4x [4096][256] fp32
constexpr size_t OFF_X    = 0;
constexpr size_t OFF_WT1H = 0;
constexpr size_t OFF_WT1L = 524288;
constexpr size_t OFF_Z1HI = 2097152;
constexpr size_t OFF_Z1LO = 6291456;
constexpr size_t OFF_X2HI = 2097152;
constexpr size_t OFF_X2LO = 6291456;
constexpr size_t OFF_PART = 2097152;     // 8*32*256 fp32 (final)
constexpr size_t OFF_X2   = 10485760;
constexpr size_t OFF_X3   = 10485760;    // ushort region (bf16), overlays dead X2
constexpr size_t OFF_H    = 18874368;    // ushort region (bf16) [4096][2048]
constexpr size_t OFF_WLO  = 23068672;    // ushort region
constexpr size_t OFF_WOH  = 25165824;    // ushort region [256][8192]
constexpr size_t OFF_WOL  = 26214400;    // ushort region
constexpr size_t OFF_YP   = 27262976;
constexpr size_t OFF_LP  = 31457280;     // [N,16] self-loop edge attr
constexpr size_t OFF_WS1 = OFF_LP  + 65536;   // [512,4]
constexpr size_t OFF_WD1 = OFF_WS1 + 2048;    // [512,4]
constexpr size_t OFF_WS2 = OFF_WD1 + 2048;    // [2048,4]
constexpr size_t OFF_WD2 = OFF_WS2 + 8192;    // [2048,4]
constexpr size_t OFF_AE1 = OFF_WD2 + 8192;    // [16,4]
constexpr size_t OFF_AE2 = OFF_AE1 + 64;      // [16,4]
constexpr size_t OFF_AS1 = OFF_AE2 + 64;      // [N,4]
constexpr size_t OFF_AD1 = OFF_AS1 + 16384;
constexpr size_t OFF_AS2 = OFF_AD1 + 16384;
constexpr size_t OFF_AD2 = OFF_AS2 + 16384;
constexpr size_t OFF_EB  = OFF_AD2 + 16384;          // [Ef,4] logits
constexpr size_t OFF_AL  = OFF_EB  + (size_t)NEf*4;  // [Ef,4] alpha
constexpr size_t OFF_I   = OFF_AL  + (size_t)NEf*4;  // int region
constexpr size_t I_DEG = 0;       // [N]
constexpr size_t I_RP  = 4096;    // [N+1] (+pad)
constexpr size_t I_CUR = 8200;    // [N]
constexpr size_t I_EID = 12296;   // [Ef]
constexpr size_t WS_FLOATS = OFF_I + I_EID + (size_t)NEf + 64;

using bf16x8 = __bf16 __attribute__((ext_vector_type(8)));
using f32x4  = float __attribute__((ext_vector_type(4)));

__device__ __forceinline__ float wred64(float v){
#pragma unroll
  for (int o = 32; o > 0; o >>= 1) v += __shfl_down(v, o, 64);
  return v;
}
__device__ __forceinline__ float lrelu(float v, float s){ return v > 0.f ? v : s * v; }

__device__ __forceinline__ unsigned short f2bf(float x){  // RTNE
  unsigned int u = __float_as_uint(x);
  unsigned int r = (u + 0x7FFFu + ((u >> 16) & 1u)) >> 16;
  return (unsigned short)r;
}
__device__ __forceinline__ float bf2f(unsigned short h){
  return __uint_as_float((unsigned int)h << 16);
}
__device__ __forceinline__ void split2(float x, unsigned short& h, unsigned short& l){
  h = f2bf(x);
  l = f2bf(x - bf2f(h));
}
__device__ __forceinline__ void gload16(const void* g, void* l){
  __builtin_amdgcn_global_load_lds((const __attribute__((address_space(1))) void*)g,
                                   (__attribute__((address_space(3))) void*)l, 16, 0, 0);
}

// ---------------- small prep kernels ----------------
__global__ void k_concat(const float* __restrict__ xg, const float* __restrict__ ac,
                         const float* __restrict__ ti, float* __restrict__ x){
  int i = blockIdx.x * 256 + threadIdx.x;          // over N*512
  int n = i >> 9, c = i & 511;
  float v;
  if (c < 256)      v = xg[(size_t)n*256 + c];
  else if (c < 384) v = ac[(size_t)n*128 + (c-256)];
  else              v = ti[(size_t)n*128 + (c-384)];
  x[i] = v;
}

__global__ void k_count(const int* __restrict__ ei, int* __restrict__ deg){
  int e = blockIdx.x * 256 + threadIdx.x;
  if (e < Ne) atomicAdd(&deg[ei[Ne + e]], 1);
}

__global__ void k_scan(const int* __restrict__ deg, int* __restrict__ rowptr, int* __restrict__ cursor){
  __shared__ int sd[1024];
  int t = threadIdx.x;
  int v[4]; int s = 0;
#pragma unroll
  for (int i = 0; i < 4; i++){ v[i] = s; s += deg[t*4 + i] + 1; }   // +1 self loop
  sd[t] = s;
  __syncthreads();
  for (int off = 1; off < 1024; off <<= 1){
    int x = (t >= off) ? sd[t - off] : 0;
    __syncthreads();
    sd[t] += x;
    __syncthreads();
  }
  int base = (t == 0) ? 0 : sd[t - 1];
#pragma unroll
  for (int i = 0; i < 4; i++){ int rp = base + v[i]; rowptr[t*4 + i] = rp; cursor[t*4 + i] = rp; }
  if (t == 1023) rowptr[4096] = sd[1023];
}

__global__ void k_fill(const int* __restrict__ ei, int* __restrict__ cursor, int* __restrict__ eids){
  int e = blockIdx.x * 256 + threadIdx.x;
  if (e >= NEf) return;
  int d = (e < Ne) ? ei[Ne + e] : (e - Ne);
  int p = atomicAdd(&cursor[d], 1);
  eids[p] = e;
}

__global__ void k_sort(const int* __restrict__ rowptr, int* __restrict__ eids){
  int n = blockIdx.x * 256 + threadIdx.x;
  if (n >= Nn) return;
  int b = rowptr[n], e = rowptr[n + 1];
  for (int i = b + 1; i < e; i++){
    int key = eids[i]; int j = i - 1;
    while (j >= b && eids[j] > key){ eids[j+1] = eids[j]; j--; }
    eids[j+1] = key;
  }
}

__global__ void k_loopattr(const float* __restrict__ eattr, const int* __restrict__ rowptr,
                           const int* __restrict__ eids, float* __restrict__ lp){
  int idx = blockIdx.x * 256 + threadIdx.x;        // N*16
  int n = idx >> 4, a = idx & 15;
  if (n >= Nn) return;
  int b = rowptr[n], e = rowptr[n + 1];
  float s = 0.f; int cnt = 0;
  for (int j = b; j < e; ++j){
    int id = eids[j];
    if (id < Ne){ s += eattr[(size_t)id*16 + a]; cnt++; }
  }
  lp[(size_t)n*16 + a] = s / fmaxf((float)cnt, 1.f);
}

// Ws[k,h] = sum_c W[k, h*C+c]*a_s[h,c] ; Wd likewise.
__global__ void k_proj(const float* __restrict__ W, const float* __restrict__ a_s,
                       const float* __restrict__ a_d, float* __restrict__ Ws,
                       float* __restrict__ Wd, int K, int C){
  int gid = blockIdx.x * 256 + threadIdx.x;
  int wave = gid >> 6, lane = gid & 63;
  int h = wave & 3, k = wave >> 2;
  if (k >= K) return;
  const float* wrow = W + (size_t)k * (4*C) + (size_t)h * C;
  const float* ar = a_s + (size_t)h * C;
  const float* dr = a_d + (size_t)h * C;
  float ps = 0.f, pd = 0.f;
  for (int c = lane; c < C; c += 64){ float w = wrow[c]; ps += w * ar[c]; pd += w * dr[c]; }
  ps = wred64(ps); pd = wred64(pd);
  if (lane == 0){ Ws[k*4 + h] = ps; Wd[k*4 + h] = pd; }
}

// one wave per (k,h): outp[k*4+h] = dot(We[k, h*C:(h+1)*C], ae[h,:])
__global__ void k_aeproj(const float* __restrict__ We, const float* __restrict__ ae,
                         float* __restrict__ outp, int C){
  int gid = blockIdx.x * 256 + threadIdx.x;
  int wave = gid >> 6, lane = gid & 63;
  int h = wave & 3, k = wave >> 2;
  if (k >= 16) return;
  const float* wrow = We + (size_t)k * (4*C) + (size_t)h * C;
  const float* ar = ae + (size_t)h * C;
  float s = 0.f;
  for (int c = lane; c < C; c += 64) s += wrow[c] * ar[c];
  s = wred64(s);
  if (lane == 0) outp[k*4 + h] = s;
}

// as[n,h], ad[n,h] = x[n,:] @ Ws/Wd. Block per node.
__global__ __launch_bounds__(256) void k_asad(const float* __restrict__ x, const float* __restrict__ Ws,
                      const float* __restrict__ Wd, float* __restrict__ as_,
                      float* __restrict__ ad_, int D){
  int n = blockIdx.x, t = threadIdx.x;
  const float* row = x + (size_t)n * D;
  float p[8] = {0,0,0,0,0,0,0,0};
  for (int c = t; c < D; c += 256){
    float xv = row[c];
    float4 ws4 = *(const float4*)&Ws[c*4];
    float4 wd4 = *(const float4*)&Wd[c*4];
    p[0] += xv * ws4.x; p[1] += xv * ws4.y; p[2] += xv * ws4.z; p[3] += xv * ws4.w;
    p[4] += xv * wd4.x; p[5] += xv * wd4.y; p[6] += xv * wd4.z; p[7] += xv * wd4.w;
  }
  __shared__ float sm[4][8];
  int lane = t & 63, wid = t >> 6;
#pragma unroll
  for (int q = 0; q < 8; q++){
    float v = wred64(p[q]);
    if (lane == 0) sm[wid][q] = v;
  }
  __syncthreads();
  if (t < 8){
    float s = sm[0][t] + sm[1][t] + sm[2][t] + sm[3][t];
    if (t < 4) as_[(size_t)n*4 + t] = s;
    else       ad_[(size_t)n*4 + (t-4)] = s;
  }
}

__global__ void k_edge(const float* __restrict__ eattr, const float* __restrict__ lp,
                       const int* __restrict__ ei, const float* __restrict__ as_,
                       const float* __restrict__ ad_, const float* __restrict__ aep,
                       float* __restrict__ ebuf){
  int e = blockIdx.x * 256 + threadIdx.x;
  if (e >= NEf) return;
  int s, d; const float* ea;
  if (e < Ne){ s = ei[e]; d = ei[Ne + e]; ea = eattr + (size_t)e * 16; }
  else { s = e - Ne; d = e - Ne; ea = lp + (size_t)(e - Ne) * 16; }
  float eav[16];
#pragma unroll
  for (int k = 0; k < 16; k++) eav[k] = ea[k];
#pragma unroll
  for (int h = 0; h < 4; h++){
    float v = as_[(size_t)s*4 + h] + ad_[(size_t)d*4 + h];
#pragma unroll
    for (int k = 0; k < 16; k++) v += eav[k] * aep[k*4 + h];
    ebuf[(size_t)e*4 + h] = lrelu(v, 0.2f);
  }
}

__global__ void k_softmax(const int* __restrict__ rowptr, const int* __restrict__ eids,
                          const float* __restrict__ ebuf, float* __restrict__ alpha){
  int n = blockIdx.x * 256 + threadIdx.x;
  if (n >= Nn) return;
  int b = rowptr[n], e = rowptr[n + 1];
#pragma unroll
  for (int h = 0; h < 4; h++){
    float m = -1e30f;
    for (int j = b; j < e; ++j) m = fmaxf(m, ebuf[(size_t)eids[j]*4 + h]);
    float ss = 0.f;
    for (int j = b; j < e; ++j){
      float ex = expf(ebuf[(size_t)eids[j]*4 + h] - m);
      alpha[(size_t)eids[j]*4 + h] = ex; ss += ex;
    }
    for (int j = b; j < e; ++j) alpha[(size_t)eids[j]*4 + h] /= ss;
  }
}

// z1[n, h*512+c] = sum_e alpha[e,h] * x[src(e),c], written bf16 hi/lo split
__global__ __launch_bounds__(256) void k_agg1_split(const float* __restrict__ x, const float* __restrict__ alpha,
                      const int* __restrict__ rowptr, const int* __restrict__ eids,
                      const int* __restrict__ ei, unsigned short* __restrict__ z1hi,
                      unsigned short* __restrict__ z1lo){
  int n = blockIdx.x, t = threadIdx.x;
  float2 a0 = {0,0}, a1 = {0,0}, a2 = {0,0}, a3 = {0,0};
  int b = rowptr[n], e = rowptr[n + 1];
  for (int j = b; j < e; ++j){
    int eid = eids[j];
    int s = (eid < Ne) ? ei[eid] : (eid - Ne);
    float4 av = *(const float4*)&alpha[(size_t)eid*4];
    float2 xv = *(const float2*)&x[(size_t)s*512 + t*2];
    a0.x += av.x*xv.x; a0.y += av.x*xv.y;
    a1.x += av.y*xv.x; a1.y += av.y*xv.y;
    a2.x += av.z*xv.x; a2.y += av.z*xv.y;
    a3.x += av.w*xv.x; a3.y += av.w*xv.y;
  }
  size_t base = (size_t)n*2048 + t*2;
  float2 av[4] = {a0, a1, a2, a3};
#pragma unroll
  for (int h = 0; h < 4; h++){
    ushort2 hh, ll;
    split2(av[h].x, hh.x, ll.x);
    split2(av[h].y, hh.y, ll.y);
    *(ushort2*)&z1hi[base + h*512] = hh;
    *(ushort2*)&z1lo[base + h*512] = ll;
  }
}

// x2 fp32 -> bf16 hi/lo split (one pass)
__global__ void k_splitx2(const float* __restrict__ x2, unsigned short* __restrict__ xh,
                          unsigned short* __restrict__ xl){
  int i = blockIdx.x * 256 + threadIdx.x;   // over (4096*2048)/4 float4s
  float4 v = ((const float4*)x2)[i];
  ushort4 h, l;
  split2(v.x, h.x, l.x); split2(v.y, h.y, l.y);
  split2(v.z, h.z, l.z); split2(v.w, h.w, l.w);
  ((ushort4*)xh)[i] = h;
  ((ushort4*)xl)[i] = l;
}

// x3[n,:] = lrelu( sum_e alpha[e,h]*H[src,:] + b2_h, 0.01 ), bf16 out. Block per dst node.
__global__ __launch_bounds__(256) void k_agg2b(const unsigned short* __restrict__ H,
                      const float* __restrict__ alpha,
                      const int* __restrict__ rowptr, const int* __restrict__ eids,
                      const int* __restrict__ ei, unsigned short* __restrict__ x3,
                      const float* __restrict__ b2, int h){
  int n = blockIdx.x, t = threadIdx.x;
  float acc[8] = {0,0,0,0,0,0,0,0};
  int b = rowptr[n], e = rowptr[n + 1];
  for (int j = b; j < e; ++j){
    int eid = eids[j];
    int s = (eid < Ne) ? ei[eid] : (eid - Ne);
    float a = alpha[(size_t)eid*4 + h];
    bf16x8 hv = *(const bf16x8*)&H[(size_t)s*2048 + t*8];
#pragma unroll
    for (int q = 0; q < 8; q++) acc[q] += a * (float)hv[q];
  }
  const float* bb = b2 + (size_t)h*2048 + t*8;
  ushort4 o0, o1;
  float4 b0 = *(const float4*)bb;
  float4 b1 = *(const float4*)(bb + 4);
  o0.x = f2bf(lrelu(acc[0] + b0.x, 0.01f)); o0.y = f2bf(lrelu(acc[1] + b0.y, 0.01f));
  o0.z = f2bf(lrelu(acc[2] + b0.z, 0.01f)); o0.w = f2bf(lrelu(acc[3] + b0.w, 0.01f));
  o1.x = f2bf(lrelu(acc[4] + b1.x, 0.01f)); o1.y = f2bf(lrelu(acc[5] + b1.y, 0.01f));
  o1.z = f2bf(lrelu(acc[6] + b1.z, 0.01f)); o1.w = f2bf(lrelu(acc[7] + b1.w, 0.01f));
  size_t base = (size_t)n*2048 + t*8;
  *(ushort4*)&x3[base]     = o0;
  *(ushort4*)&x3[base + 4] = o1;
}

// transpose + bf16-split: out[col][k] = split(W[k][coloff+col]); out stride K
__global__ __launch_bounds__(256) void k_wsplit(const float* __restrict__ W, int ldw, int coloff, int K,
                       unsigned short* __restrict__ whi, unsigned short* __restrict__ wlo){
  __shared__ float tile[32][33];
  int bk = blockIdx.x * 32, bn = blockIdx.y * 32;
  int tx = threadIdx.x & 31, ty = threadIdx.x >> 5;
#pragma unroll
  for (int i = 0; i < 4; i++){
    int k = bk + ty + i*8;
    tile[ty + i*8][tx] = W[(size_t)k*ldw + coloff + bn + tx];
  }
  __syncthreads();
#pragma unroll
  for (int i = 0; i < 4; i++){
    int n = bn + ty + i*8;
    float v = tile[tx][ty + i*8];
    unsigned short hh, ll; split2(v, hh, ll);
    whi[(size_t)n*K + bk + tx] = hh;
    wlo[(size_t)n*K + bk + tx] = ll;
  }
}

// ---------------- L2 dense GEMM: H[4096][2048] = (x2h+x2l)[4096][2048k] x (Wh+Wl)^T[2048n][2048k]
// 3-term bf16 split on MFMA. BM=128, BN=256, 8 waves, 4 phases/K-step, 3-buffer LDS,
// counted vmcnt(6) (2-deep prefetch, never drains in steady state). bf16 out, no bias/act.
__global__ __launch_bounds__(512) void k_gemm256(
    const unsigned short* __restrict__ Ah, const unsigned short* __restrict__ Al,
    const unsigned short* __restrict__ Bh, const unsigned short* __restrict__ Bl,
    unsigned short* __restrict__ Cout)
{
  __shared__ __align__(16) unsigned short lds[73728];   // 3 x (A 8192 + B 16384) ushorts
  const int t = threadIdx.x;
  const int brow = blockIdx.y * 128, bcol = blockIdx.x * 256;
  const int w = t >> 6, lane = t & 63;
  const int wm = (w >> 2) * 64, wn = (w & 3) * 64;

  // staging: slot = i*512+t -> row = i*64+(t>>3), phys chunk = t&7; logical chunk scc = (t&7)^(row&7)
  const int sr = t >> 3;
  const int scc = (t & 7) ^ (sr & 7);
  const unsigned short* asrc = (scc < 4 ? Ah : Al) + (size_t)(brow + sr)*2048 + (size_t)(scc & 3)*8;
  const unsigned short* bsrc = (scc < 4 ? Bh : Bl) + (size_t)(bcol + sr)*2048 + (size_t)(scc & 3)*8;
  const int adst = w * 512;           // + buf*24576 + i*4096 (+ lane*8 implicit in gload)
  const int bdst = 8192 + w * 512;

  // fragment read offsets (ushort units, within buffer)
  const int fr = lane & 15, kc = lane >> 4;
  const int cswz = (kc ^ (lane & 7)) * 8;
  int aoff[4], boff[4];
#pragma unroll
  for (int m = 0; m < 4; m++) aoff[m] = (wm + m*16 + fr)*64 + cswz;
#pragma unroll
  for (int n = 0; n < 4; n++) boff[n] = 8192 + (wn + n*16 + fr)*64 + cswz;

  f32x4 acc[4][4];
#pragma unroll
  for (int m = 0; m < 4; m++)
#pragma unroll
    for (int n = 0; n < 4; n++) acc[m][n] = f32x4{0.f, 0.f, 0.f, 0.f};

  // prologue: stage tiles 0 (buf0) and 1 (buf1)
#pragma unroll
  for (int i = 0; i < 2; i++) gload16(asrc + (size_t)i*64*2048,      &lds[i*4096 + adst]);
#pragma unroll
  for (int i = 0; i < 4; i++) gload16(bsrc + (size_t)i*64*2048,      &lds[i*4096 + bdst]);
#pragma unroll
  for (int i = 0; i < 2; i++) gload16(asrc + (size_t)i*64*2048 + 32, &lds[24576 + i*4096 + adst]);
#pragma unroll
  for (int i = 0; i < 4; i++) gload16(bsrc + (size_t)i*64*2048 + 32, &lds[24576 + i*4096 + bdst]);
  asm volatile("s_waitcnt vmcnt(6)" ::: "memory");     // tile 0 landed; tile 1 in flight
  __builtin_amdgcn_s_barrier();

  for (int kt = 0; kt < 64; ++kt){
    const int bufo = (kt % 3) * 24576;
    const int nbo  = ((kt + 2) % 3) * 24576;
    const size_t nko = (size_t)(kt + 2) * 32;
    const bool pf = (kt + 2) < 64;

    bf16x8 ah[4], al[4];
    // ---- phase 0: A frags + B0; prefetch A-part of tile kt+2
#pragma unroll
    for (int m = 0; m < 4; m++){
      ah[m] = *(const bf16x8*)&lds[bufo + aoff[m]];
      al[m] = *(const bf16x8*)&lds[bufo + (aoff[m] ^ 32)];
    }
    {
      bf16x8 bh = *(const bf16x8*)&lds[bufo + boff[0]];
      bf16x8 bl = *(const bf16x8*)&lds[bufo + (boff[0] ^ 32)];
      if (pf){
        gload16(asrc + nko,                   &lds[nbo + adst]);
        gload16(asrc + (size_t)64*2048 + nko, &lds[nbo + 4096 + adst]);
      }
      __builtin_amdgcn_s_barrier();
      asm volatile("s_waitcnt lgkmcnt(0)");
      __builtin_amdgcn_s_setprio(1);
#pragma unroll
      for (int m = 0; m < 4; m++) acc[m][0] = __builtin_amdgcn_mfma_f32_16x16x32_bf16(ah[m], bh, acc[m][0], 0, 0, 0);
#pragma unroll
      for (int m = 0; m < 4; m++) acc[m][0] = __builtin_amdgcn_mfma_f32_16x16x32_bf16(ah[m], bl, acc[m][0], 0, 0, 0);
#pragma unroll
      for (int m = 0; m < 4; m++) acc[m][0] = __builtin_amdgcn_mfma_f32_16x16x32_bf16(al[m], bh, acc[m][0], 0, 0, 0);
      __builtin_amdgcn_s_setprio(0);
      __builtin_amdgcn_s_barrier();
    }
    // ---- phases 1..3: B frag n; prefetch B-parts of tile kt+2
#pragma unroll
    for (int n = 1; n < 4; n++){
      bf16x8 bh = *(const bf16x8*)&lds[bufo + boff[n]];
      bf16x8 bl = *(const bf16x8*)&lds[bufo + (boff[n] ^ 32)];
      if (pf){
        if (n == 1){
          gload16(bsrc + nko,                   &lds[nbo + bdst]);
          gload16(bsrc + (size_t)64*2048 + nko, &lds[nbo + 4096 + bdst]);
        } else if (n == 2){
          gload16(bsrc + (size_t)128*2048 + nko, &lds[nbo + 8192 + bdst]);
        } else {
          gload16(bsrc + (size_t)192*2048 + nko, &lds[nbo + 12288 + bdst]);
        }
      }
      __builtin_amdgcn_s_barrier();
      asm volatile("s_waitcnt lgkmcnt(0)");
      __builtin_amdgcn_s_setprio(1);
#pragma unroll
      for (int m = 0; m < 4; m++) acc[m][n] = __builtin_amdgcn_mfma_f32_16x16x32_bf16(ah[m], bh, acc[m][n], 0, 0, 0);
#pragma unroll
      for (int m = 0; m < 4; m++) acc[m][n] = __builtin_amdgcn_mfma_f32_16x16x32_bf16(ah[m], bl, acc[m][n], 0, 0, 0);
#pragma unroll
      for (int m = 0; m < 4; m++) acc[m][n] = __builtin_amdgcn_mfma_f32_16x16x32_bf16(al[m], bh, acc[m][n], 0, 0, 0);
      __builtin_amdgcn_s_setprio(0);
      __builtin_amdgcn_s_barrier();
    }
    // ---- end of K-step: wait for tile kt+1 (oldest 6), keep tile kt+2 (newest 6) in flight
    if (pf) asm volatile("s_waitcnt vmcnt(6)" ::: "memory");
    else    asm volatile("s_waitcnt vmcnt(0)" ::: "memory");
    __builtin_amdgcn_s_barrier();
  }

  // ---- epilogue: bf16 store. C/D frag: col=lane&15, row=(lane>>4)*4+reg
#pragma unroll
  for (int m = 0; m < 4; m++){
    const int row0 = brow + wm + m*16 + kc*4;
#pragma unroll
    for (int n = 0; n < 4; n++){
      const int col = bcol + wn + n*16 + fr;
#pragma unroll
      for (int r = 0; r < 4; r++)
        Cout[(size_t)(row0 + r)*2048 + col] = f2bf(acc[m][n][r]);
    }
  }
}

// ---------------- MFMA GEMM (128x128), 3-term (or 2-term exact-A) bf16 split ----------------
template<int KLEN, bool EXACTA, bool OUTF32, bool BETA1, bool ACT, bool HASBIAS>
__global__ __launch_bounds__(256) void k_gemm2(
    const unsigned short* __restrict__ Ah, const unsigned short* __restrict__ Al, int lda, size_t az,
    const unsigned short* __restrict__ Bh, const unsigned short* __restrict__ Bl, int ldb, size_t bz,
    void* __restrict__ Cout, int ldc, size_t cz,
    const float* __restrict__ bias, size_t biasz)
{
  __shared__ unsigned short lds[16384];   // A: [0,8192) ushorts, B: [8192,16384)
  const int t = threadIdx.x;
  const int z = blockIdx.z;
  const int brow = blockIdx.y * 128, bcol = blockIdx.x * 128;
  const int wid = t >> 6, lane = t & 63;
  const int wm = (wid >> 1) * 64, wn = (wid & 1) * 64;

  const int sr = t >> 3, sc = t & 7;
  const int scc = sc ^ (sr & 7);
  const unsigned short* asrc = (scc < 4 ? Ah : Al) + (size_t)(brow + sr)*lda + (size_t)z*az + (size_t)(scc & 3)*8;
  const unsigned short* bsrc = (scc < 4 ? Bh : Bl) + (size_t)(bcol + sr)*ldb + (size_t)z*bz + (size_t)(scc & 3)*8;
  unsigned short* adst = &lds[(size_t)wid * 512];
  unsigned short* bdst = &lds[8192 + (size_t)wid * 512];

  const int fr = lane & 15, kc = lane >> 4;
  const int swz = ((kc ^ (lane & 7)) << 3);
  int aoff[4], boff[4];
#pragma unroll
  for (int m = 0; m < 4; m++) aoff[m] = (wm + m*16 + fr)*64 + swz;
#pragma unroll
  for (int n = 0; n < 4; n++) boff[n] = 8192 + (wn + n*16 + fr)*64 + swz;

  f32x4 acc[4][4];
#pragma unroll
  for (int m = 0; m < 4; m++)
#pragma unroll
    for (int n = 0; n < 4; n++) acc[m][n] = f32x4{0.f, 0.f, 0.f, 0.f};

  for (int kt = 0; kt < KLEN/32; ++kt){
    const size_t ko = (size_t)kt * 32;
#pragma unroll
    for (int i = 0; i < 4; i++){
      gload16(asrc + (size_t)i*32*lda + ko, adst + i*2048);
      gload16(bsrc + (size_t)i*32*ldb + ko, bdst + i*2048);
    }
    __syncthreads();

    bf16x8 ah[4], al[4], bh[4], bl[4];
#pragma unroll
    for (int m = 0; m < 4; m++){
      ah[m] = *(const bf16x8*)&lds[aoff[m]];
      if (!EXACTA) al[m] = *(const bf16x8*)&lds[aoff[m] ^ 32];
    }
#pragma unroll
    for (int n = 0; n < 4; n++){
      bh[n] = *(const bf16x8*)&lds[boff[n]];
      bl[n] = *(const bf16x8*)&lds[boff[n] ^ 32];
    }
#pragma unroll
    for (int m = 0; m < 4; m++)
#pragma unroll
      for (int n = 0; n < 4; n++){
        acc[m][n] = __builtin_amdgcn_mfma_f32_16x16x32_bf16(ah[m], bh[n], acc[m][n], 0, 0, 0);
        acc[m][n] = __builtin_amdgcn_mfma_f32_16x16x32_bf16(ah[m], bl[n], acc[m][n], 0, 0, 0);
        if (!EXACTA)
          acc[m][n] = __builtin_amdgcn_mfma_f32_16x16x32_bf16(al[m], bh[n], acc[m][n], 0, 0, 0);
      }
    __syncthreads();
  }

  float bv[4] = {0.f, 0.f, 0.f, 0.f};
  if (HASBIAS){
#pragma unroll
    for (int n = 0; n < 4; n++) bv[n] = bias[(size_t)z*biasz + bcol + wn + n*16 + fr];
  }
  float* Cf = (float*)Cout + (size_t)z*cz;
  unsigned short* Cb = (unsigned short*)Cout + (size_t)z*cz;
#pragma unroll
  for (int m = 0; m < 4; m++){
    const int row0 = brow + wm + m*16 + kc*4;
#pragma unroll
    for (int n = 0; n < 4; n++){
      const int col = bcol + wn + n*16 + fr;
#pragma unroll
      for (int r = 0; r < 4; r++){
        float v = acc[m][n][r] + bv[n];
        if (ACT) v = lrelu(v, 0.01f);
        if (OUTF32){
          float* cp = &Cf[(size_t)(row0 + r)*ldc + col];
          if (BETA1) v += *cp;
          *cp = v;
        } else {
          Cb[(size_t)(row0 + r)*ldc + col] = f2bf(v);
        }
      }
    }
  }
}

// stage 1: per (slice, graph) partial sums over stride-32 node slices
__global__ void k_gsum(const float* __restrict__ yp, const float* __restrict__ bout,
                       const int* __restrict__ batch, float* __restrict__ part){
  const int s = blockIdx.x, g = blockIdx.y, t = threadIdx.x;
  __shared__ int sb[2];
  if (t < 2){
    int key = g + t, lo = 0, hi = Nn;
    while (lo < hi){ int mid = (lo + hi) >> 1; if (batch[mid] < key) lo = mid + 1; else hi = mid; }
    sb[t] = lo;
  }
  __syncthreads();
  const int b = sb[0], e = sb[1];
  const size_t P = (size_t)Nn * 256;
  float acc = 0.f;
  float bt = bout[t];
  for (int n = b + s; n < e; n += 32){
    size_t i = (size_t)n*256 + t;
    float v = yp[i] + yp[P + i] + yp[2*P + i] + yp[3*P + i] + bt;
    acc += lrelu(v, 0.01f);
  }
  part[(size_t)(g*32 + s)*256 + t] = acc;
}

// stage 2: sum 32 slices, divide by count
__global__ void k_gfin(const float* __restrict__ part, const int* __restrict__ batch,
                       float* __restrict__ out){
  const int g = blockIdx.x, t = threadIdx.x;
  __shared__ int sb[2];
  if (t < 2){
    int key = g + t, lo = 0, hi = Nn;
    while (lo < hi){ int mid = (lo + hi) >> 1; if (batch[mid] < key) lo = mid + 1; else hi = mid; }
    sb[t] = lo;
  }
  __syncthreads();
  const int cnt = sb[1] - sb[0];
  float s = 0.f;
#pragma unroll
  for (int k = 0; k < 32; k++) s += part[(size_t)(g*32 + k)*256 + t];
  out[g*256 + t] = s / fmaxf((float)cnt, 1.f);
}

// ---------------- launch ----------------
extern "C" void kernel_launch(void* const* d_in, const int* in_sizes, int n_in,
                              void* d_out, int out_size, void* d_ws, size_t ws_size,
                              hipStream_t stream){
  const float* xg    = (const float*)d_in[0];
  const float* ac    = (const float*)d_in[1];
  const float* ti    = (const float*)d_in[2];
  const float* eattr = (const float*)d_in[3];
  const int*   ei    = (const int*)  d_in[4];
  const int*   batch = (const int*)  d_in[5];
  const float* W1    = (const float*)d_in[6];
  const float* as1w  = (const float*)d_in[7];
  const float* ad1w  = (const float*)d_in[8];
  const float* ae1w  = (const float*)d_in[9];
  const float* We1   = (const float*)d_in[10];
  const float* b1    = (const float*)d_in[11];
  const float* W2    = (const float*)d_in[12];
  const float* as2w  = (const float*)d_in[13];
  const float* ad2w  = (const float*)d_in[14];
  const float* ae2w  = (const float*)d_in[15];
  const float* We2   = (const float*)d_in[16];
  const float* b2    = (const float*)d_in[17];
  const float* Wout  = (const float*)d_in[18];
  const float* bout  = (const float*)d_in[19];
  float* out = (float*)d_out;
  float* ws  = (float*)d_ws;
  if (ws_size < WS_FLOATS * sizeof(float)) return;
  int* iws = (int*)(ws + OFF_I);

  unsigned short* z1hi = (unsigned short*)(ws + OFF_Z1HI);
  unsigned short* z1lo = (unsigned short*)(ws + OFF_Z1LO);
  unsigned short* wt1h = (unsigned short*)(ws + OFF_WT1H);
  unsigned short* wt1l = (unsigned short*)(ws + OFF_WT1L);
  unsigned short* x2hi = (unsigned short*)(ws + OFF_X2HI);
  unsigned short* x2lo = (unsigned short*)(ws + OFF_X2LO);
  unsigned short* whi  = (unsigned short*)(ws + OFF_X);
  unsigned short* wlo  = (unsigned short*)(ws + OFF_WLO);
  unsigned short* woh  = (unsigned short*)(ws + OFF_WOH);
  unsigned short* wol  = (unsigned short*)(ws + OFF_WOL);
  unsigned short* Hb   = (unsigned short*)(ws + OFF_H);
  unsigned short* x3   = (unsigned short*)(ws + OFF_X3);

  hipMemsetAsync(iws + I_DEG, 0, Nn * sizeof(int), stream);
  k_concat <<<8192, 256, 0, stream>>>(xg, ac, ti, ws + OFF_X);
  k_count  <<<128,  256, 0, stream>>>(ei, iws + I_DEG);
  k_scan   <<<1,   1024, 0, stream>>>(iws + I_DEG, iws + I_RP, iws + I_CUR);
  k_fill   <<<144,  256, 0, stream>>>(ei, iws + I_CUR, iws + I_EID);
  k_sort   <<<16,   256, 0, stream>>>(iws + I_RP, iws + I_EID);
  k_loopattr<<<256, 256, 0, stream>>>(eattr, iws + I_RP, iws + I_EID, ws + OFF_LP);

  k_proj   <<<512,  256, 0, stream>>>(W1, as1w, ad1w, ws + OFF_WS1, ws + OFF_WD1, 512, 512);
  k_proj   <<<2048, 256, 0, stream>>>(W2, as2w, ad2w, ws + OFF_WS2, ws + OFF_WD2, 2048, 2048);
  k_aeproj <<<16,   256, 0, stream>>>(We1, ae1w, ws + OFF_AE1, 512);
  k_aeproj <<<16,   256, 0, stream>>>(We2, ae2w, ws + OFF_AE2, 2048);
  k_wsplit <<<dim3(256, 8), 256, 0, stream>>>(Wout, 256, 0, 8192, woh, wol);   // wtout [256][8192]

  // ---- layer 1 ----
  k_asad      <<<4096, 256, 0, stream>>>(ws + OFF_X, ws + OFF_WS1, ws + OFF_WD1, ws + OFF_AS1, ws + OFF_AD1, 512);
  k_edge      <<<144,  256, 0, stream>>>(eattr, ws + OFF_LP, ei, ws + OFF_AS1, ws + OFF_AD1, ws + OFF_AE1, ws + OFF_EB);
  k_softmax   <<<16,   256, 0, stream>>>(iws + I_RP, iws + I_EID, ws + OFF_EB, ws + OFF_AL);
  k_agg1_split<<<4096, 256, 0, stream>>>(ws + OFF_X, ws + OFF_AL, iws + I_RP, iws + I_EID, ei, z1hi, z1lo);
  // X dead; wt1 overlays it
  k_wsplit <<<dim3(16, 64), 256, 0, stream>>>(W1, 2048, 0, 512, wt1h, wt1l);   // wt1 [2048][512]
  k_gemm2<512, false, true, false, true, true><<<dim3(4, 32, 4), 256, 0, stream>>>(
      z1hi, z1lo, 2048, 512,  wt1h, wt1l, 512, 512*512,
      ws + OFF_X2, 2048, 512,  b1, 512);

  // ---- layer 2 attention ----
  k_asad   <<<4096, 256, 0, stream>>>(ws + OFF_X2, ws + OFF_WS2, ws + OFF_WD2, ws + OFF_AS2, ws + OFF_AD2, 2048);
  k_edge   <<<144,  256, 0, stream>>>(eattr, ws + OFF_LP, ei, ws + OFF_AS2, ws + OFF_AD2, ws + OFF_AE2, ws + OFF_EB);
  k_softmax<<<16,   256, 0, stream>>>(iws + I_RP, iws + I_EID, ws + OFF_EB, ws + OFF_AL);

  // x2 fp32 -> hi/lo split (z1 regions dead); x2 fp32 dead afterwards
  k_splitx2<<<8192, 256, 0, stream>>>(ws + OFF_X2, x2hi, x2lo);

  // ---- layer 2 + fc, per head: H = x2@W2_h^T (dense MFMA), then sparse agg of bf16 H ----
  for (int h = 0; h < 4; ++h){
    k_wsplit  <<<dim3(64, 64), 256, 0, stream>>>(W2, 8192, h*2048, 2048, whi, wlo);
    k_gemm256 <<<dim3(8, 32), 512, 0, stream>>>(x2hi, x2lo, whi, wlo, Hb);
    k_agg2b   <<<4096, 256, 0, stream>>>(Hb, ws + OFF_AL, iws + I_RP, iws + I_EID, ei, x3, b2, h);
    if (h == 0)
      k_gemm2<512, true, true, false, false, false><<<dim3(2, 32, 4), 256, 0, stream>>>(
          x3, x3, 2048, 512,  woh + (size_t)h*2048, wol + (size_t)h*2048, 8192, 512,
          ws + OFF_YP, 256, (size_t)Nn*256,  nullptr, 0);
    else
      k_gemm2<512, true, true, true, false, false><<<dim3(2, 32, 4), 256, 0, stream>>>(
          x3, x3, 2048, 512,  woh + (size_t)h*2048, wol + (size_t)h*2048, 8192, 512,
          ws + OFF_YP, 256, (size_t)Nn*256,  nullptr, 0);
  }

  k_gsum<<<dim3(32, 8), 256, 0, stream>>>(ws + OFF_YP, bout, batch, ws + OFF_PART);
  k_gfin<<<8, 256, 0, stream>>>(ws + OFF_PART, batch, out);
}

// Round 7
// 905.430 us; speedup vs baseline: 3.2599x; 1.1111x over previous
//
#include <hip/hip_runtime.h>
#include <math.h>

constexpr int Nn  = 4096;
constexpr int Ne  = 32768;
constexpr int NEf = Ne + Nn;     // real edges + self loops

// ---------------- ws layout (float offsets) ----------------
// region reuse timeline:
//   R0 [0..2097152)          X fp32 (prep/L1) -> wt1 hi/lo bf16 (L1 gemm) -> whi fp16 [2048][2048] (L2 loop)
//   R1 [2097152..10485760)   z1 hi/lo bf16 (L1) -> x2hi/x2lo fp16 [4096][2048] (L2) -> part fp32 (final)
//   R2 [10485760..18874368)  X2 fp32 -> x3 fp16 [4096][2048] (L2 loop, after split)
//   R3 [18874368..23068672)  H fp16 [4096][2048] (L2 loop)
//   R4 [23068672..25165824)  (free)
//   R5 [25165824..27262976)  wtout hi/lo fp16 [256][8192]
//   R6 [27262976..31457280)  YP 4x [4096][256] fp32
constexpr size_t OFF_X    = 0;
constexpr size_t OFF_WT1H = 0;
constexpr size_t OFF_WT1L = 524288;
constexpr size_t OFF_Z1HI = 2097152;
constexpr size_t OFF_Z1LO = 6291456;
constexpr size_t OFF_X2HI = 2097152;
constexpr size_t OFF_X2LO = 6291456;
constexpr size_t OFF_PART = 2097152;     // 8*32*256 fp32 (final)
constexpr size_t OFF_X2   = 10485760;
constexpr size_t OFF_X3   = 10485760;    // ushort region (fp16), overlays dead X2
constexpr size_t OFF_H    = 18874368;    // ushort region (fp16) [4096][2048]
constexpr size_t OFF_WOH  = 25165824;    // ushort region [256][8192] fp16
constexpr size_t OFF_WOL  = 26214400;    // ushort region
constexpr size_t OFF_YP   = 27262976;
constexpr size_t OFF_LP  = 31457280;     // [N,16] self-loop edge attr
constexpr size_t OFF_WS1 = OFF_LP  + 65536;   // [512,4]
constexpr size_t OFF_WD1 = OFF_WS1 + 2048;    // [512,4]
constexpr size_t OFF_WS2 = OFF_WD1 + 2048;    // [2048,4]
constexpr size_t OFF_WD2 = OFF_WS2 + 8192;    // [2048,4]
constexpr size_t OFF_AE1 = OFF_WD2 + 8192;    // [16,4]
constexpr size_t OFF_AE2 = OFF_AE1 + 64;      // [16,4]
constexpr size_t OFF_AS1 = OFF_AE2 + 64;      // [N,4]
constexpr size_t OFF_AD1 = OFF_AS1 + 16384;
constexpr size_t OFF_AS2 = OFF_AD1 + 16384;
constexpr size_t OFF_AD2 = OFF_AS2 + 16384;
constexpr size_t OFF_EB  = OFF_AD2 + 16384;          // [Ef,4] logits
constexpr size_t OFF_AL  = OFF_EB  + (size_t)NEf*4;  // [Ef,4] alpha
constexpr size_t OFF_I   = OFF_AL  + (size_t)NEf*4;  // int region
constexpr size_t I_DEG = 0;       // [N]
constexpr size_t I_RP  = 4096;    // [N+1] (+pad)
constexpr size_t I_CUR = 8200;    // [N]
constexpr size_t I_EID = 12296;   // [Ef]
constexpr size_t WS_FLOATS = OFF_I + I_EID + (size_t)NEf + 64;

using bf16x8 = __bf16 __attribute__((ext_vector_type(8)));
using f16x8  = _Float16 __attribute__((ext_vector_type(8)));
using f32x4  = float __attribute__((ext_vector_type(4)));

__device__ __forceinline__ float wred64(float v){
#pragma unroll
  for (int o = 32; o > 0; o >>= 1) v += __shfl_down(v, o, 64);
  return v;
}
__device__ __forceinline__ float lrelu(float v, float s){ return v > 0.f ? v : s * v; }

__device__ __forceinline__ unsigned short f2bf(float x){  // RTNE
  unsigned int u = __float_as_uint(x);
  unsigned int r = (u + 0x7FFFu + ((u >> 16) & 1u)) >> 16;
  return (unsigned short)r;
}
__device__ __forceinline__ float bf2f(unsigned short h){
  return __uint_as_float((unsigned int)h << 16);
}
__device__ __forceinline__ void split2(float x, unsigned short& h, unsigned short& l){
  h = f2bf(x);
  l = f2bf(x - bf2f(h));
}
__device__ __forceinline__ unsigned short f2h(float x){
  _Float16 h = (_Float16)x;
  return __builtin_bit_cast(unsigned short, h);
}
__device__ __forceinline__ float h2f(unsigned short u){
  return (float)__builtin_bit_cast(_Float16, u);
}
__device__ __forceinline__ void split2h(float x, unsigned short& h, unsigned short& l){
  _Float16 hh = (_Float16)x;
  h = __builtin_bit_cast(unsigned short, hh);
  _Float16 ll = (_Float16)(x - (float)hh);
  l = __builtin_bit_cast(unsigned short, ll);
}
__device__ __forceinline__ void gload16(const void* g, void* l){
  __builtin_amdgcn_global_load_lds((const __attribute__((address_space(1))) void*)g,
                                   (__attribute__((address_space(3))) void*)l, 16, 0, 0);
}

// ---------------- small prep kernels ----------------
__global__ void k_concat(const float* __restrict__ xg, const float* __restrict__ ac,
                         const float* __restrict__ ti, float* __restrict__ x){
  int i = blockIdx.x * 256 + threadIdx.x;          // over N*512
  int n = i >> 9, c = i & 511;
  float v;
  if (c < 256)      v = xg[(size_t)n*256 + c];
  else if (c < 384) v = ac[(size_t)n*128 + (c-256)];
  else              v = ti[(size_t)n*128 + (c-384)];
  x[i] = v;
}

__global__ void k_count(const int* __restrict__ ei, int* __restrict__ deg){
  int e = blockIdx.x * 256 + threadIdx.x;
  if (e < Ne) atomicAdd(&deg[ei[Ne + e]], 1);
}

__global__ void k_scan(const int* __restrict__ deg, int* __restrict__ rowptr, int* __restrict__ cursor){
  __shared__ int sd[1024];
  int t = threadIdx.x;
  int v[4]; int s = 0;
#pragma unroll
  for (int i = 0; i < 4; i++){ v[i] = s; s += deg[t*4 + i] + 1; }   // +1 self loop
  sd[t] = s;
  __syncthreads();
  for (int off = 1; off < 1024; off <<= 1){
    int x = (t >= off) ? sd[t - off] : 0;
    __syncthreads();
    sd[t] += x;
    __syncthreads();
  }
  int base = (t == 0) ? 0 : sd[t - 1];
#pragma unroll
  for (int i = 0; i < 4; i++){ int rp = base + v[i]; rowptr[t*4 + i] = rp; cursor[t*4 + i] = rp; }
  if (t == 1023) rowptr[4096] = sd[1023];
}

__global__ void k_fill(const int* __restrict__ ei, int* __restrict__ cursor, int* __restrict__ eids){
  int e = blockIdx.x * 256 + threadIdx.x;
  if (e >= NEf) return;
  int d = (e < Ne) ? ei[Ne + e] : (e - Ne);
  int p = atomicAdd(&cursor[d], 1);
  eids[p] = e;
}

__global__ void k_sort(const int* __restrict__ rowptr, int* __restrict__ eids){
  int n = blockIdx.x * 256 + threadIdx.x;
  if (n >= Nn) return;
  int b = rowptr[n], e = rowptr[n + 1];
  for (int i = b + 1; i < e; i++){
    int key = eids[i]; int j = i - 1;
    while (j >= b && eids[j] > key){ eids[j+1] = eids[j]; j--; }
    eids[j+1] = key;
  }
}

__global__ void k_loopattr(const float* __restrict__ eattr, const int* __restrict__ rowptr,
                           const int* __restrict__ eids, float* __restrict__ lp){
  int idx = blockIdx.x * 256 + threadIdx.x;        // N*16
  int n = idx >> 4, a = idx & 15;
  if (n >= Nn) return;
  int b = rowptr[n], e = rowptr[n + 1];
  float s = 0.f; int cnt = 0;
  for (int j = b; j < e; ++j){
    int id = eids[j];
    if (id < Ne){ s += eattr[(size_t)id*16 + a]; cnt++; }
  }
  lp[(size_t)n*16 + a] = s / fmaxf((float)cnt, 1.f);
}

// Ws[k,h] = sum_c W[k, h*C+c]*a_s[h,c] ; Wd likewise.
__global__ void k_proj(const float* __restrict__ W, const float* __restrict__ a_s,
                       const float* __restrict__ a_d, float* __restrict__ Ws,
                       float* __restrict__ Wd, int K, int C){
  int gid = blockIdx.x * 256 + threadIdx.x;
  int wave = gid >> 6, lane = gid & 63;
  int h = wave & 3, k = wave >> 2;
  if (k >= K) return;
  const float* wrow = W + (size_t)k * (4*C) + (size_t)h * C;
  const float* ar = a_s + (size_t)h * C;
  const float* dr = a_d + (size_t)h * C;
  float ps = 0.f, pd = 0.f;
  for (int c = lane; c < C; c += 64){ float w = wrow[c]; ps += w * ar[c]; pd += w * dr[c]; }
  ps = wred64(ps); pd = wred64(pd);
  if (lane == 0){ Ws[k*4 + h] = ps; Wd[k*4 + h] = pd; }
}

// one wave per (k,h): outp[k*4+h] = dot(We[k, h*C:(h+1)*C], ae[h,:])
__global__ void k_aeproj(const float* __restrict__ We, const float* __restrict__ ae,
                         float* __restrict__ outp, int C){
  int gid = blockIdx.x * 256 + threadIdx.x;
  int wave = gid >> 6, lane = gid & 63;
  int h = wave & 3, k = wave >> 2;
  if (k >= 16) return;
  const float* wrow = We + (size_t)k * (4*C) + (size_t)h * C;
  const float* ar = ae + (size_t)h * C;
  float s = 0.f;
  for (int c = lane; c < C; c += 64) s += wrow[c] * ar[c];
  s = wred64(s);
  if (lane == 0) outp[k*4 + h] = s;
}

// as[n,h], ad[n,h] = x[n,:] @ Ws/Wd. Block per node.
__global__ __launch_bounds__(256) void k_asad(const float* __restrict__ x, const float* __restrict__ Ws,
                      const float* __restrict__ Wd, float* __restrict__ as_,
                      float* __restrict__ ad_, int D){
  int n = blockIdx.x, t = threadIdx.x;
  const float* row = x + (size_t)n * D;
  float p[8] = {0,0,0,0,0,0,0,0};
  for (int c = t; c < D; c += 256){
    float xv = row[c];
    float4 ws4 = *(const float4*)&Ws[c*4];
    float4 wd4 = *(const float4*)&Wd[c*4];
    p[0] += xv * ws4.x; p[1] += xv * ws4.y; p[2] += xv * ws4.z; p[3] += xv * ws4.w;
    p[4] += xv * wd4.x; p[5] += xv * wd4.y; p[6] += xv * wd4.z; p[7] += xv * wd4.w;
  }
  __shared__ float sm[4][8];
  int lane = t & 63, wid = t >> 6;
#pragma unroll
  for (int q = 0; q < 8; q++){
    float v = wred64(p[q]);
    if (lane == 0) sm[wid][q] = v;
  }
  __syncthreads();
  if (t < 8){
    float s = sm[0][t] + sm[1][t] + sm[2][t] + sm[3][t];
    if (t < 4) as_[(size_t)n*4 + t] = s;
    else       ad_[(size_t)n*4 + (t-4)] = s;
  }
}

__global__ void k_edge(const float* __restrict__ eattr, const float* __restrict__ lp,
                       const int* __restrict__ ei, const float* __restrict__ as_,
                       const float* __restrict__ ad_, const float* __restrict__ aep,
                       float* __restrict__ ebuf){
  int e = blockIdx.x * 256 + threadIdx.x;
  if (e >= NEf) return;
  int s, d; const float* ea;
  if (e < Ne){ s = ei[e]; d = ei[Ne + e]; ea = eattr + (size_t)e * 16; }
  else { s = e - Ne; d = e - Ne; ea = lp + (size_t)(e - Ne) * 16; }
  float eav[16];
#pragma unroll
  for (int k = 0; k < 16; k++) eav[k] = ea[k];
#pragma unroll
  for (int h = 0; h < 4; h++){
    float v = as_[(size_t)s*4 + h] + ad_[(size_t)d*4 + h];
#pragma unroll
    for (int k = 0; k < 16; k++) v += eav[k] * aep[k*4 + h];
    ebuf[(size_t)e*4 + h] = lrelu(v, 0.2f);
  }
}

__global__ void k_softmax(const int* __restrict__ rowptr, const int* __restrict__ eids,
                          const float* __restrict__ ebuf, float* __restrict__ alpha){
  int n = blockIdx.x * 256 + threadIdx.x;
  if (n >= Nn) return;
  int b = rowptr[n], e = rowptr[n + 1];
#pragma unroll
  for (int h = 0; h < 4; h++){
    float m = -1e30f;
    for (int j = b; j < e; ++j) m = fmaxf(m, ebuf[(size_t)eids[j]*4 + h]);
    float ss = 0.f;
    for (int j = b; j < e; ++j){
      float ex = expf(ebuf[(size_t)eids[j]*4 + h] - m);
      alpha[(size_t)eids[j]*4 + h] = ex; ss += ex;
    }
    for (int j = b; j < e; ++j) alpha[(size_t)eids[j]*4 + h] /= ss;
  }
}

// z1[n, h*512+c] = sum_e alpha[e,h] * x[src(e),c], written bf16 hi/lo split
__global__ __launch_bounds__(256) void k_agg1_split(const float* __restrict__ x, const float* __restrict__ alpha,
                      const int* __restrict__ rowptr, const int* __restrict__ eids,
                      const int* __restrict__ ei, unsigned short* __restrict__ z1hi,
                      unsigned short* __restrict__ z1lo){
  int n = blockIdx.x, t = threadIdx.x;
  float2 a0 = {0,0}, a1 = {0,0}, a2 = {0,0}, a3 = {0,0};
  int b = rowptr[n], e = rowptr[n + 1];
  for (int j = b; j < e; ++j){
    int eid = eids[j];
    int s = (eid < Ne) ? ei[eid] : (eid - Ne);
    float4 av = *(const float4*)&alpha[(size_t)eid*4];
    float2 xv = *(const float2*)&x[(size_t)s*512 + t*2];
    a0.x += av.x*xv.x; a0.y += av.x*xv.y;
    a1.x += av.y*xv.x; a1.y += av.y*xv.y;
    a2.x += av.z*xv.x; a2.y += av.z*xv.y;
    a3.x += av.w*xv.x; a3.y += av.w*xv.y;
  }
  size_t base = (size_t)n*2048 + t*2;
  float2 av[4] = {a0, a1, a2, a3};
#pragma unroll
  for (int h = 0; h < 4; h++){
    ushort2 hh, ll;
    split2(av[h].x, hh.x, ll.x);
    split2(av[h].y, hh.y, ll.y);
    *(ushort2*)&z1hi[base + h*512] = hh;
    *(ushort2*)&z1lo[base + h*512] = ll;
  }
}

// x2 fp32 -> fp16 hi/lo split (one pass)
__global__ void k_splitx2(const float* __restrict__ x2, unsigned short* __restrict__ xh,
                          unsigned short* __restrict__ xl){
  int i = blockIdx.x * 256 + threadIdx.x;   // over (4096*2048)/4 float4s
  float4 v = ((const float4*)x2)[i];
  ushort4 h, l;
  split2h(v.x, h.x, l.x); split2h(v.y, h.y, l.y);
  split2h(v.z, h.z, l.z); split2h(v.w, h.w, l.w);
  ((ushort4*)xh)[i] = h;
  ((ushort4*)xl)[i] = l;
}

// x3[n,:] = lrelu( sum_e alpha[e,h]*H[src,:] + b2_h, 0.01 ), fp16 in/out. Block per dst node.
__global__ __launch_bounds__(256) void k_agg2b(const unsigned short* __restrict__ H,
                      const float* __restrict__ alpha,
                      const int* __restrict__ rowptr, const int* __restrict__ eids,
                      const int* __restrict__ ei, unsigned short* __restrict__ x3,
                      const float* __restrict__ b2, int h){
  int n = blockIdx.x, t = threadIdx.x;
  float acc[8] = {0,0,0,0,0,0,0,0};
  int b = rowptr[n], e = rowptr[n + 1];
  for (int j = b; j < e; ++j){
    int eid = eids[j];
    int s = (eid < Ne) ? ei[eid] : (eid - Ne);
    float a = alpha[(size_t)eid*4 + h];
    f16x8 hv = *(const f16x8*)&H[(size_t)s*2048 + t*8];
#pragma unroll
    for (int q = 0; q < 8; q++) acc[q] += a * (float)hv[q];
  }
  const float* bb = b2 + (size_t)h*2048 + t*8;
  ushort4 o0, o1;
  float4 b0 = *(const float4*)bb;
  float4 b1 = *(const float4*)(bb + 4);
  o0.x = f2h(lrelu(acc[0] + b0.x, 0.01f)); o0.y = f2h(lrelu(acc[1] + b0.y, 0.01f));
  o0.z = f2h(lrelu(acc[2] + b0.z, 0.01f)); o0.w = f2h(lrelu(acc[3] + b0.w, 0.01f));
  o1.x = f2h(lrelu(acc[4] + b1.x, 0.01f)); o1.y = f2h(lrelu(acc[5] + b1.y, 0.01f));
  o1.z = f2h(lrelu(acc[6] + b1.z, 0.01f)); o1.w = f2h(lrelu(acc[7] + b1.w, 0.01f));
  size_t base = (size_t)n*2048 + t*8;
  *(ushort4*)&x3[base]     = o0;
  *(ushort4*)&x3[base + 4] = o1;
}

// transpose + split: out[col][k] = split(W[k][coloff+col]); out stride K.
// HALF: fp16 split; STORELO: write lo array.
template<bool HALF, bool STORELO>
__global__ __launch_bounds__(256) void k_wsplit(const float* __restrict__ W, int ldw, int coloff, int K,
                       unsigned short* __restrict__ whi, unsigned short* __restrict__ wlo){
  __shared__ float tile[32][33];
  int bk = blockIdx.x * 32, bn = blockIdx.y * 32;
  int tx = threadIdx.x & 31, ty = threadIdx.x >> 5;
#pragma unroll
  for (int i = 0; i < 4; i++){
    int k = bk + ty + i*8;
    tile[ty + i*8][tx] = W[(size_t)k*ldw + coloff + bn + tx];
  }
  __syncthreads();
#pragma unroll
  for (int i = 0; i < 4; i++){
    int n = bn + ty + i*8;
    float v = tile[tx][ty + i*8];
    unsigned short hh, ll;
    if (HALF) split2h(v, hh, ll); else split2(v, hh, ll);
    whi[(size_t)n*K + bk + tx] = hh;
    if (STORELO) wlo[(size_t)n*K + bk + tx] = ll;
  }
}

// ---------------- L2 dense GEMM: H[4096][2048] = x2[4096][2048k] x W2h^T[2048n][2048k]
// fp16 2-term: C = Ah*Bh + Al*Bh (A = x2 hi+lo fp16 near-exact; B = W2 fp16 hi only).
// BM=128, BN=256, 8 waves, 2 phases x 16 MFMA per K-step(32), 3-buffer LDS (96KB),
// counted vmcnt(4), 2-deep prefetch. fp16 out.
__global__ __launch_bounds__(512) void k_gemm256(
    const unsigned short* __restrict__ Ah, const unsigned short* __restrict__ Al,
    const unsigned short* __restrict__ Bh, unsigned short* __restrict__ Cout)
{
  __shared__ __align__(16) unsigned short lds[49152];   // 3 x (A 8192 + B 8192) ushorts
  const int t = threadIdx.x;
  const int brow = blockIdx.y * 128, bcol = blockIdx.x * 256;
  const int w = t >> 6, lane = t & 63;
  const int wm = (w >> 2) * 64, wn = (w & 3) * 64;
  constexpr int BUF = 16384, BOFF = 8192;   // ushorts

  // A staging: slot = i*512+t -> row = i*64+(t>>3), phys chunk t&7, logical = phys^(row&7)
  const int asr = t >> 3;
  const int ascc = (t & 7) ^ (asr & 7);
  const unsigned short* asrc = (ascc < 4 ? Ah : Al) + (size_t)(brow + asr)*2048 + (size_t)(ascc & 3)*8;
  // B staging: slot = i*512+t -> row = i*128+(t>>2), phys chunk t&3, logical = phys^(row&3)
  const int bsr = t >> 2;
  const int bscc = (t & 3) ^ (bsr & 3);
  const unsigned short* bsrc = Bh + (size_t)(bcol + bsr)*2048 + (size_t)bscc*8;
  const int adst = w * 512;           // + buf*BUF + i*4096 (+ lane*16B implicit)
  const int bdst = BOFF + w * 512;

  // fragment read offsets (ushort units, within buffer)
  const int fr = lane & 15, kc = lane >> 4;
  const int aswz = (kc ^ (lane & 7)) * 8;
  const int bswz = (kc ^ (lane & 3)) * 8;
  int aoff[4], boff[4];
#pragma unroll
  for (int m = 0; m < 4; m++) aoff[m] = (wm + m*16 + fr)*64 + aswz;
#pragma unroll
  for (int n = 0; n < 4; n++) boff[n] = BOFF + (wn + n*16 + fr)*32 + bswz;

  f32x4 acc[4][4];
#pragma unroll
  for (int m = 0; m < 4; m++)
#pragma unroll
    for (int n = 0; n < 4; n++) acc[m][n] = f32x4{0.f, 0.f, 0.f, 0.f};

  // prologue: stage tile 0 (buf0) FULLY FIRST, then tile 1 (buf1).
  // vmcnt counts oldest-first: vmcnt(4) => the 4 oldest (ALL of tile 0) complete,
  // tile 1's 4 loads still in flight. (Round-6 bug: interleaved order left half of
  // tile 0 in flight at vmcnt(4) -> first K-step read uninitialized LDS -> NaN.)
  gload16(asrc,                        &lds[adst]);
  gload16(asrc + (size_t)64*2048,      &lds[4096 + adst]);
  gload16(bsrc,                        &lds[bdst]);
  gload16(bsrc + (size_t)128*2048,     &lds[4096 + bdst]);
  gload16(asrc + 32,                   &lds[BUF + adst]);
  gload16(asrc + (size_t)64*2048 + 32, &lds[BUF + 4096 + adst]);
  gload16(bsrc + 32,                   &lds[BUF + bdst]);
  gload16(bsrc + (size_t)128*2048 + 32,&lds[BUF + 4096 + bdst]);
  asm volatile("s_waitcnt vmcnt(4)" ::: "memory");   // tile 0 landed; tile 1 in flight
  __builtin_amdgcn_s_barrier();

  for (int kt = 0; kt < 64; ++kt){
    const int bufo = (kt % 3) * BUF;
    const int nbo  = ((kt + 2) % 3) * BUF;
    const size_t nko = (size_t)(kt + 2) * 32;
    const bool pf = (kt + 2) < 64;

    f16x8 ah[4], al[4];
    // ---- phase 0: A frags + B0,B1; prefetch A of tile kt+2
#pragma unroll
    for (int m = 0; m < 4; m++){
      ah[m] = *(const f16x8*)&lds[bufo + aoff[m]];
      al[m] = *(const f16x8*)&lds[bufo + (aoff[m] ^ 32)];
    }
    {
      f16x8 b0 = *(const f16x8*)&lds[bufo + boff[0]];
      f16x8 b1 = *(const f16x8*)&lds[bufo + boff[1]];
      if (pf){
        gload16(asrc + nko,                   &lds[nbo + adst]);
        gload16(asrc + (size_t)64*2048 + nko, &lds[nbo + 4096 + adst]);
      }
      __builtin_amdgcn_s_barrier();
      asm volatile("s_waitcnt lgkmcnt(0)");
      __builtin_amdgcn_s_setprio(1);
#pragma unroll
      for (int m = 0; m < 4; m++) acc[m][0] = __builtin_amdgcn_mfma_f32_16x16x32_f16(ah[m], b0, acc[m][0], 0, 0, 0);
#pragma unroll
      for (int m = 0; m < 4; m++) acc[m][0] = __builtin_amdgcn_mfma_f32_16x16x32_f16(al[m], b0, acc[m][0], 0, 0, 0);
#pragma unroll
      for (int m = 0; m < 4; m++) acc[m][1] = __builtin_amdgcn_mfma_f32_16x16x32_f16(ah[m], b1, acc[m][1], 0, 0, 0);
#pragma unroll
      for (int m = 0; m < 4; m++) acc[m][1] = __builtin_amdgcn_mfma_f32_16x16x32_f16(al[m], b1, acc[m][1], 0, 0, 0);
      __builtin_amdgcn_s_setprio(0);
      __builtin_amdgcn_s_barrier();
    }
    // ---- phase 1: B2,B3; prefetch B of tile kt+2
    {
      f16x8 b2 = *(const f16x8*)&lds[bufo + boff[2]];
      f16x8 b3 = *(const f16x8*)&lds[bufo + boff[3]];
      if (pf){
        gload16(bsrc + nko,                    &lds[nbo + bdst]);
        gload16(bsrc + (size_t)128*2048 + nko, &lds[nbo + 4096 + bdst]);
      }
      __builtin_amdgcn_s_barrier();
      asm volatile("s_waitcnt lgkmcnt(0)");
      __builtin_amdgcn_s_setprio(1);
#pragma unroll
      for (int m = 0; m < 4; m++) acc[m][2] = __builtin_amdgcn_mfma_f32_16x16x32_f16(ah[m], b2, acc[m][2], 0, 0, 0);
#pragma unroll
      for (int m = 0; m < 4; m++) acc[m][2] = __builtin_amdgcn_mfma_f32_16x16x32_f16(al[m], b2, acc[m][2], 0, 0, 0);
#pragma unroll
      for (int m = 0; m < 4; m++) acc[m][3] = __builtin_amdgcn_mfma_f32_16x16x32_f16(ah[m], b3, acc[m][3], 0, 0, 0);
#pragma unroll
      for (int m = 0; m < 4; m++) acc[m][3] = __builtin_amdgcn_mfma_f32_16x16x32_f16(al[m], b3, acc[m][3], 0, 0, 0);
      __builtin_amdgcn_s_setprio(0);
      __builtin_amdgcn_s_barrier();
    }
    // ---- end of K-step: tile kt+1 must be complete; keep tile kt+2's 4 loads in flight
    if (pf) asm volatile("s_waitcnt vmcnt(4)" ::: "memory");
    else    asm volatile("s_waitcnt vmcnt(0)" ::: "memory");
    __builtin_amdgcn_s_barrier();
  }

  // ---- epilogue: fp16 store. C/D frag: col=lane&15, row=(lane>>4)*4+reg
#pragma unroll
  for (int m = 0; m < 4; m++){
    const int row0 = brow + wm + m*16 + kc*4;
#pragma unroll
    for (int n = 0; n < 4; n++){
      const int col = bcol + wn + n*16 + fr;
#pragma unroll
      for (int r = 0; r < 4; r++)
        Cout[(size_t)(row0 + r)*2048 + col] = f2h(acc[m][n][r]);
    }
  }
}

// ---------------- MFMA GEMM (128x128): bf16 3-term, or fp16 exact-A 2-term ----------------
template<int KLEN, bool EXACTA, bool HALF, bool OUTF32, bool BETA1, bool ACT, bool HASBIAS>
__global__ __launch_bounds__(256) void k_gemm2(
    const unsigned short* __restrict__ Ah, const unsigned short* __restrict__ Al, int lda, size_t az,
    const unsigned short* __restrict__ Bh, const unsigned short* __restrict__ Bl, int ldb, size_t bz,
    void* __restrict__ Cout, int ldc, size_t cz,
    const float* __restrict__ bias, size_t biasz)
{
  __shared__ unsigned short lds[16384];   // A: [0,8192) ushorts, B: [8192,16384)
  const int t = threadIdx.x;
  const int z = blockIdx.z;
  const int brow = blockIdx.y * 128, bcol = blockIdx.x * 128;
  const int wid = t >> 6, lane = t & 63;
  const int wm = (wid >> 1) * 64, wn = (wid & 1) * 64;

  const int sr = t >> 3, sc = t & 7;
  const int scc = sc ^ (sr & 7);
  const unsigned short* asrc = (scc < 4 ? Ah : Al) + (size_t)(brow + sr)*lda + (size_t)z*az + (size_t)(scc & 3)*8;
  const unsigned short* bsrc = (scc < 4 ? Bh : Bl) + (size_t)(bcol + sr)*ldb + (size_t)z*bz + (size_t)(scc & 3)*8;
  unsigned short* adst = &lds[(size_t)wid * 512];
  unsigned short* bdst = &lds[8192 + (size_t)wid * 512];

  const int fr = lane & 15, kc = lane >> 4;
  const int swz = ((kc ^ (lane & 7)) << 3);
  int aoff[4], boff[4];
#pragma unroll
  for (int m = 0; m < 4; m++) aoff[m] = (wm + m*16 + fr)*64 + swz;
#pragma unroll
  for (int n = 0; n < 4; n++) boff[n] = 8192 + (wn + n*16 + fr)*64 + swz;

  f32x4 acc[4][4];
#pragma unroll
  for (int m = 0; m < 4; m++)
#pragma unroll
    for (int n = 0; n < 4; n++) acc[m][n] = f32x4{0.f, 0.f, 0.f, 0.f};

  for (int kt = 0; kt < KLEN/32; ++kt){
    const size_t ko = (size_t)kt * 32;
#pragma unroll
    for (int i = 0; i < 4; i++){
      gload16(asrc + (size_t)i*32*lda + ko, adst + i*2048);
      gload16(bsrc + (size_t)i*32*ldb + ko, bdst + i*2048);
    }
    __syncthreads();

    if (HALF){
      f16x8 ah[4], bh[4], bl[4];
#pragma unroll
      for (int m = 0; m < 4; m++) ah[m] = *(const f16x8*)&lds[aoff[m]];
#pragma unroll
      for (int n = 0; n < 4; n++){
        bh[n] = *(const f16x8*)&lds[boff[n]];
        bl[n] = *(const f16x8*)&lds[boff[n] ^ 32];
      }
#pragma unroll
      for (int m = 0; m < 4; m++)
#pragma unroll
        for (int n = 0; n < 4; n++){
          acc[m][n] = __builtin_amdgcn_mfma_f32_16x16x32_f16(ah[m], bh[n], acc[m][n], 0, 0, 0);
          acc[m][n] = __builtin_amdgcn_mfma_f32_16x16x32_f16(ah[m], bl[n], acc[m][n], 0, 0, 0);
        }
    } else {
      bf16x8 ah[4], al[4], bh[4], bl[4];
#pragma unroll
      for (int m = 0; m < 4; m++){
        ah[m] = *(const bf16x8*)&lds[aoff[m]];
        if (!EXACTA) al[m] = *(const bf16x8*)&lds[aoff[m] ^ 32];
      }
#pragma unroll
      for (int n = 0; n < 4; n++){
        bh[n] = *(const bf16x8*)&lds[boff[n]];
        bl[n] = *(const bf16x8*)&lds[boff[n] ^ 32];
      }
#pragma unroll
      for (int m = 0; m < 4; m++)
#pragma unroll
        for (int n = 0; n < 4; n++){
          acc[m][n] = __builtin_amdgcn_mfma_f32_16x16x32_bf16(ah[m], bh[n], acc[m][n], 0, 0, 0);
          acc[m][n] = __builtin_amdgcn_mfma_f32_16x16x32_bf16(ah[m], bl[n], acc[m][n], 0, 0, 0);
          if (!EXACTA)
            acc[m][n] = __builtin_amdgcn_mfma_f32_16x16x32_bf16(al[m], bh[n], acc[m][n], 0, 0, 0);
        }
    }
    __syncthreads();
  }

  float bv[4] = {0.f, 0.f, 0.f, 0.f};
  if (HASBIAS){
#pragma unroll
    for (int n = 0; n < 4; n++) bv[n] = bias[(size_t)z*biasz + bcol + wn + n*16 + fr];
  }
  float* Cf = (float*)Cout + (size_t)z*cz;
  unsigned short* Cb = (unsigned short*)Cout + (size_t)z*cz;
#pragma unroll
  for (int m = 0; m < 4; m++){
    const int row0 = brow + wm + m*16 + kc*4;
#pragma unroll
    for (int n = 0; n < 4; n++){
      const int col = bcol + wn + n*16 + fr;
#pragma unroll
      for (int r = 0; r < 4; r++){
        float v = acc[m][n][r] + bv[n];
        if (ACT) v = lrelu(v, 0.01f);
        if (OUTF32){
          float* cp = &Cf[(size_t)(row0 + r)*ldc + col];
          if (BETA1) v += *cp;
          *cp = v;
        } else {
          Cb[(size_t)(row0 + r)*ldc + col] = f2bf(v);
        }
      }
    }
  }
}

// stage 1: per (slice, graph) partial sums over stride-32 node slices
__global__ void k_gsum(const float* __restrict__ yp, const float* __restrict__ bout,
                       const int* __restrict__ batch, float* __restrict__ part){
  const int s = blockIdx.x, g = blockIdx.y, t = threadIdx.x;
  __shared__ int sb[2];
  if (t < 2){
    int key = g + t, lo = 0, hi = Nn;
    while (lo < hi){ int mid = (lo + hi) >> 1; if (batch[mid] < key) lo = mid + 1; else hi = mid; }
    sb[t] = lo;
  }
  __syncthreads();
  const int b = sb[0], e = sb[1];
  const size_t P = (size_t)Nn * 256;
  float acc = 0.f;
  float bt = bout[t];
  for (int n = b + s; n < e; n += 32){
    size_t i = (size_t)n*256 + t;
    float v = yp[i] + yp[P + i] + yp[2*P + i] + yp[3*P + i] + bt;
    acc += lrelu(v, 0.01f);
  }
  part[(size_t)(g*32 + s)*256 + t] = acc;
}

// stage 2: sum 32 slices, divide by count
__global__ void k_gfin(const float* __restrict__ part, const int* __restrict__ batch,
                       float* __restrict__ out){
  const int g = blockIdx.x, t = threadIdx.x;
  __shared__ int sb[2];
  if (t < 2){
    int key = g + t, lo = 0, hi = Nn;
    while (lo < hi){ int mid = (lo + hi) >> 1; if (batch[mid] < key) lo = mid + 1; else hi = mid; }
    sb[t] = lo;
  }
  __syncthreads();
  const int cnt = sb[1] - sb[0];
  float s = 0.f;
#pragma unroll
  for (int k = 0; k < 32; k++) s += part[(size_t)(g*32 + k)*256 + t];
  out[g*256 + t] = s / fmaxf((float)cnt, 1.f);
}

// ---------------- launch ----------------
extern "C" void kernel_launch(void* const* d_in, const int* in_sizes, int n_in,
                              void* d_out, int out_size, void* d_ws, size_t ws_size,
                              hipStream_t stream){
  const float* xg    = (const float*)d_in[0];
  const float* ac    = (const float*)d_in[1];
  const float* ti    = (const float*)d_in[2];
  const float* eattr = (const float*)d_in[3];
  const int*   ei    = (const int*)  d_in[4];
  const int*   batch = (const int*)  d_in[5];
  const float* W1    = (const float*)d_in[6];
  const float* as1w  = (const float*)d_in[7];
  const float* ad1w  = (const float*)d_in[8];
  const float* ae1w  = (const float*)d_in[9];
  const float* We1   = (const float*)d_in[10];
  const float* b1    = (const float*)d_in[11];
  const float* W2    = (const float*)d_in[12];
  const float* as2w  = (const float*)d_in[13];
  const float* ad2w  = (const float*)d_in[14];
  const float* ae2w  = (const float*)d_in[15];
  const float* We2   = (const float*)d_in[16];
  const float* b2    = (const float*)d_in[17];
  const float* Wout  = (const float*)d_in[18];
  const float* bout  = (const float*)d_in[19];
  float* out = (float*)d_out;
  float* ws  = (float*)d_ws;
  if (ws_size < WS_FLOATS * sizeof(float)) return;
  int* iws = (int*)(ws + OFF_I);

  unsigned short* z1hi = (unsigned short*)(ws + OFF_Z1HI);
  unsigned short* z1lo = (unsigned short*)(ws + OFF_Z1LO);
  unsigned short* wt1h = (unsigned short*)(ws + OFF_WT1H);
  unsigned short* wt1l = (unsigned short*)(ws + OFF_WT1L);
  unsigned short* x2hi = (unsigned short*)(ws + OFF_X2HI);
  unsigned short* x2lo = (unsigned short*)(ws + OFF_X2LO);
  unsigned short* whi  = (unsigned short*)(ws + OFF_X);
  unsigned short* woh  = (unsigned short*)(ws + OFF_WOH);
  unsigned short* wol  = (unsigned short*)(ws + OFF_WOL);
  unsigned short* Hb   = (unsigned short*)(ws + OFF_H);
  unsigned short* x3   = (unsigned short*)(ws + OFF_X3);

  hipMemsetAsync(iws + I_DEG, 0, Nn * sizeof(int), stream);
  k_concat <<<8192, 256, 0, stream>>>(xg, ac, ti, ws + OFF_X);
  k_count  <<<128,  256, 0, stream>>>(ei, iws + I_DEG);
  k_scan   <<<1,   1024, 0, stream>>>(iws + I_DEG, iws + I_RP, iws + I_CUR);
  k_fill   <<<144,  256, 0, stream>>>(ei, iws + I_CUR, iws + I_EID);
  k_sort   <<<16,   256, 0, stream>>>(iws + I_RP, iws + I_EID);
  k_loopattr<<<256, 256, 0, stream>>>(eattr, iws + I_RP, iws + I_EID, ws + OFF_LP);

  k_proj   <<<512,  256, 0, stream>>>(W1, as1w, ad1w, ws + OFF_WS1, ws + OFF_WD1, 512, 512);
  k_proj   <<<2048, 256, 0, stream>>>(W2, as2w, ad2w, ws + OFF_WS2, ws + OFF_WD2, 2048, 2048);
  k_aeproj <<<16,   256, 0, stream>>>(We1, ae1w, ws + OFF_AE1, 512);
  k_aeproj <<<16,   256, 0, stream>>>(We2, ae2w, ws + OFF_AE2, 2048);
  k_wsplit<true, true><<<dim3(256, 8), 256, 0, stream>>>(Wout, 256, 0, 8192, woh, wol);   // fp16 [256][8192]

  // ---- layer 1 (bf16 3-term, unchanged) ----
  k_asad      <<<4096, 256, 0, stream>>>(ws + OFF_X, ws + OFF_WS1, ws + OFF_WD1, ws + OFF_AS1, ws + OFF_AD1, 512);
  k_edge      <<<144,  256, 0, stream>>>(eattr, ws + OFF_LP, ei, ws + OFF_AS1, ws + OFF_AD1, ws + OFF_AE1, ws + OFF_EB);
  k_softmax   <<<16,   256, 0, stream>>>(iws + I_RP, iws + I_EID, ws + OFF_EB, ws + OFF_AL);
  k_agg1_split<<<4096, 256, 0, stream>>>(ws + OFF_X, ws + OFF_AL, iws + I_RP, iws + I_EID, ei, z1hi, z1lo);
  // X dead; wt1 overlays it
  k_wsplit<false, true><<<dim3(16, 64), 256, 0, stream>>>(W1, 2048, 0, 512, wt1h, wt1l);  // bf16 [2048][512]
  k_gemm2<512, false, false, true, false, true, true><<<dim3(4, 32, 4), 256, 0, stream>>>(
      z1hi, z1lo, 2048, 512,  wt1h, wt1l, 512, 512*512,
      ws + OFF_X2, 2048, 512,  b1, 512);

  // ---- layer 2 attention ----
  k_asad   <<<4096, 256, 0, stream>>>(ws + OFF_X2, ws + OFF_WS2, ws + OFF_WD2, ws + OFF_AS2, ws + OFF_AD2, 2048);
  k_edge   <<<144,  256, 0, stream>>>(eattr, ws + OFF_LP, ei, ws + OFF_AS2, ws + OFF_AD2, ws + OFF_AE2, ws + OFF_EB);
  k_softmax<<<16,   256, 0, stream>>>(iws + I_RP, iws + I_EID, ws + OFF_EB, ws + OFF_AL);

  // x2 fp32 -> fp16 hi/lo split (z1 regions dead); x2 fp32 dead afterwards
  k_splitx2<<<8192, 256, 0, stream>>>(ws + OFF_X2, x2hi, x2lo);

  // ---- layer 2 + fc, per head: H = x2@W2_h^T (fp16 MFMA), sparse agg of fp16 H, fp16 FC ----
  for (int h = 0; h < 4; ++h){
    k_wsplit<true, false><<<dim3(64, 64), 256, 0, stream>>>(W2, 8192, h*2048, 2048, whi, nullptr);
    k_gemm256 <<<dim3(8, 32), 512, 0, stream>>>(x2hi, x2lo, whi, Hb);
    k_agg2b   <<<4096, 256, 0, stream>>>(Hb, ws + OFF_AL, iws + I_RP, iws + I_EID, ei, x3, b2, h);
    if (h == 0)
      k_gemm2<512, true, true, true, false, false, false><<<dim3(2, 32, 4), 256, 0, stream>>>(
          x3, x3, 2048, 512,  woh + (size_t)h*2048, wol + (size_t)h*2048, 8192, 512,
          ws + OFF_YP, 256, (size_t)Nn*256,  nullptr, 0);
    else
      k_gemm2<512, true, true, true, true, false, false><<<dim3(2, 32, 4), 256, 0, stream>>>(
          x3, x3, 2048, 512,  woh + (size_t)h*2048, wol + (size_t)h*2048, 8192, 512,
          ws + OFF_YP, 256, (size_t)Nn*256,  nullptr, 0);
  }

  k_gsum<<<dim3(32, 8), 256, 0, stream>>>(ws + OFF_YP, bout, batch, ws + OFF_PART);
  k_gfin<<<8, 256, 0, stream>>>(ws + OFF_PART, batch, out);
}

// Round 8
// 746.168 us; speedup vs baseline: 3.9557x; 1.2134x over previous
//
#include <hip/hip_runtime.h>
#include <math.h>

constexpr int Nn  = 4096;
constexpr int Ne  = 32768;
constexpr int NEf = Ne + Nn;     // real edges + self loops

// ---------------- ws layout (float offsets) ----------------
// region reuse timeline:
//   R0 [0..2097152)          X fp32 (prep/L1) -> wt1 hi/lo bf16 (L1 gemm) -> whi fp16 [2048][2048] (L2 loop)
//   R1 [2097152..10485760)   z1 hi/lo bf16 (L1) -> x2hi/x2lo fp16 [4096][2048] (L2) -> part fp32 (final)
//   R2 [10485760..18874368)  X2 fp32 -> x3 fp16 [4096][2048] (L2 loop, after split)
//   R3 [18874368..23068672)  H fp16 [4096][2048] (L2 loop)
//   R4 [23068672..25165824)  (free)
//   R5 [25165824..27262976)  wtout hi/lo fp16 [256][8192]
//   R6 [27262976..31457280)  YP 4x [4096][256] fp32
constexpr size_t OFF_X    = 0;
constexpr size_t OFF_WT1H = 0;
constexpr size_t OFF_WT1L = 524288;
constexpr size_t OFF_Z1HI = 2097152;
constexpr size_t OFF_Z1LO = 6291456;
constexpr size_t OFF_X2HI = 2097152;
constexpr size_t OFF_X2LO = 6291456;
constexpr size_t OFF_PART = 2097152;     // 8*32*256 fp32 (final)
constexpr size_t OFF_X2   = 10485760;
constexpr size_t OFF_X3   = 10485760;    // ushort region (fp16), overlays dead X2
constexpr size_t OFF_H    = 18874368;    // ushort region (fp16) [4096][2048]
constexpr size_t OFF_WOH  = 25165824;    // ushort region [256][8192] fp16
constexpr size_t OFF_WOL  = 26214400;    // ushort region
constexpr size_t OFF_YP   = 27262976;
constexpr size_t OFF_LP  = 31457280;     // [N,16] self-loop edge attr
constexpr size_t OFF_WS1 = OFF_LP  + 65536;   // [512,4]
constexpr size_t OFF_WD1 = OFF_WS1 + 2048;    // [512,4]
constexpr size_t OFF_WS2 = OFF_WD1 + 2048;    // [2048,4]
constexpr size_t OFF_WD2 = OFF_WS2 + 8192;    // [2048,4]
constexpr size_t OFF_AE1 = OFF_WD2 + 8192;    // [16,4]
constexpr size_t OFF_AE2 = OFF_AE1 + 64;      // [16,4]
constexpr size_t OFF_AS1 = OFF_AE2 + 64;      // [N,4]
constexpr size_t OFF_AD1 = OFF_AS1 + 16384;
constexpr size_t OFF_AS2 = OFF_AD1 + 16384;
constexpr size_t OFF_AD2 = OFF_AS2 + 16384;
constexpr size_t OFF_EB  = OFF_AD2 + 16384;          // [Ef,4] logits
constexpr size_t OFF_AL  = OFF_EB  + (size_t)NEf*4;  // [Ef,4] alpha
constexpr size_t OFF_I   = OFF_AL  + (size_t)NEf*4;  // int region
constexpr size_t I_DEG = 0;       // [N]
constexpr size_t I_RP  = 4096;    // [N+1] (+pad)
constexpr size_t I_CUR = 8200;    // [N]
constexpr size_t I_EID = 12296;   // [Ef]
constexpr size_t WS_FLOATS = OFF_I + I_EID + (size_t)NEf + 64;

using bf16x8 = __bf16 __attribute__((ext_vector_type(8)));
using f16x8  = _Float16 __attribute__((ext_vector_type(8)));
using f32x4  = float __attribute__((ext_vector_type(4)));

__device__ __forceinline__ float wred64(float v){
#pragma unroll
  for (int o = 32; o > 0; o >>= 1) v += __shfl_down(v, o, 64);
  return v;
}
__device__ __forceinline__ float lrelu(float v, float s){ return v > 0.f ? v : s * v; }

__device__ __forceinline__ unsigned short f2bf(float x){  // RTNE
  unsigned int u = __float_as_uint(x);
  unsigned int r = (u + 0x7FFFu + ((u >> 16) & 1u)) >> 16;
  return (unsigned short)r;
}
__device__ __forceinline__ float bf2f(unsigned short h){
  return __uint_as_float((unsigned int)h << 16);
}
__device__ __forceinline__ void split2(float x, unsigned short& h, unsigned short& l){
  h = f2bf(x);
  l = f2bf(x - bf2f(h));
}
__device__ __forceinline__ unsigned short f2h(float x){
  _Float16 h = (_Float16)x;
  return __builtin_bit_cast(unsigned short, h);
}
__device__ __forceinline__ float h2f(unsigned short u){
  return (float)__builtin_bit_cast(_Float16, u);
}
__device__ __forceinline__ void split2h(float x, unsigned short& h, unsigned short& l){
  _Float16 hh = (_Float16)x;
  h = __builtin_bit_cast(unsigned short, hh);
  _Float16 ll = (_Float16)(x - (float)hh);
  l = __builtin_bit_cast(unsigned short, ll);
}
__device__ __forceinline__ void gload16(const void* g, void* l){
  __builtin_amdgcn_global_load_lds((const __attribute__((address_space(1))) void*)g,
                                   (__attribute__((address_space(3))) void*)l, 16, 0, 0);
}

// ---------------- small prep kernels ----------------
__global__ void k_concat(const float* __restrict__ xg, const float* __restrict__ ac,
                         const float* __restrict__ ti, float* __restrict__ x){
  int i = blockIdx.x * 256 + threadIdx.x;          // over N*512
  int n = i >> 9, c = i & 511;
  float v;
  if (c < 256)      v = xg[(size_t)n*256 + c];
  else if (c < 384) v = ac[(size_t)n*128 + (c-256)];
  else              v = ti[(size_t)n*128 + (c-384)];
  x[i] = v;
}

__global__ void k_count(const int* __restrict__ ei, int* __restrict__ deg){
  int e = blockIdx.x * 256 + threadIdx.x;
  if (e < Ne) atomicAdd(&deg[ei[Ne + e]], 1);
}

__global__ void k_scan(const int* __restrict__ deg, int* __restrict__ rowptr, int* __restrict__ cursor){
  __shared__ int sd[1024];
  int t = threadIdx.x;
  int v[4]; int s = 0;
#pragma unroll
  for (int i = 0; i < 4; i++){ v[i] = s; s += deg[t*4 + i] + 1; }   // +1 self loop
  sd[t] = s;
  __syncthreads();
  for (int off = 1; off < 1024; off <<= 1){
    int x = (t >= off) ? sd[t - off] : 0;
    __syncthreads();
    sd[t] += x;
    __syncthreads();
  }
  int base = (t == 0) ? 0 : sd[t - 1];
#pragma unroll
  for (int i = 0; i < 4; i++){ int rp = base + v[i]; rowptr[t*4 + i] = rp; cursor[t*4 + i] = rp; }
  if (t == 1023) rowptr[4096] = sd[1023];
}

__global__ void k_fill(const int* __restrict__ ei, int* __restrict__ cursor, int* __restrict__ eids){
  int e = blockIdx.x * 256 + threadIdx.x;
  if (e >= NEf) return;
  int d = (e < Ne) ? ei[Ne + e] : (e - Ne);
  int p = atomicAdd(&cursor[d], 1);
  eids[p] = e;
}

__global__ void k_sort(const int* __restrict__ rowptr, int* __restrict__ eids){
  int n = blockIdx.x * 256 + threadIdx.x;
  if (n >= Nn) return;
  int b = rowptr[n], e = rowptr[n + 1];
  for (int i = b + 1; i < e; i++){
    int key = eids[i]; int j = i - 1;
    while (j >= b && eids[j] > key){ eids[j+1] = eids[j]; j--; }
    eids[j+1] = key;
  }
}

__global__ void k_loopattr(const float* __restrict__ eattr, const int* __restrict__ rowptr,
                           const int* __restrict__ eids, float* __restrict__ lp){
  int idx = blockIdx.x * 256 + threadIdx.x;        // N*16
  int n = idx >> 4, a = idx & 15;
  if (n >= Nn) return;
  int b = rowptr[n], e = rowptr[n + 1];
  float s = 0.f; int cnt = 0;
  for (int j = b; j < e; ++j){
    int id = eids[j];
    if (id < Ne){ s += eattr[(size_t)id*16 + a]; cnt++; }
  }
  lp[(size_t)n*16 + a] = s / fmaxf((float)cnt, 1.f);
}

// Ws[k,h] = sum_c W[k, h*C+c]*a_s[h,c] ; Wd likewise.
__global__ void k_proj(const float* __restrict__ W, const float* __restrict__ a_s,
                       const float* __restrict__ a_d, float* __restrict__ Ws,
                       float* __restrict__ Wd, int K, int C){
  int gid = blockIdx.x * 256 + threadIdx.x;
  int wave = gid >> 6, lane = gid & 63;
  int h = wave & 3, k = wave >> 2;
  if (k >= K) return;
  const float* wrow = W + (size_t)k * (4*C) + (size_t)h * C;
  const float* ar = a_s + (size_t)h * C;
  const float* dr = a_d + (size_t)h * C;
  float ps = 0.f, pd = 0.f;
  for (int c = lane; c < C; c += 64){ float w = wrow[c]; ps += w * ar[c]; pd += w * dr[c]; }
  ps = wred64(ps); pd = wred64(pd);
  if (lane == 0){ Ws[k*4 + h] = ps; Wd[k*4 + h] = pd; }
}

// one wave per (k,h): outp[k*4+h] = dot(We[k, h*C:(h+1)*C], ae[h,:])
__global__ void k_aeproj(const float* __restrict__ We, const float* __restrict__ ae,
                         float* __restrict__ outp, int C){
  int gid = blockIdx.x * 256 + threadIdx.x;
  int wave = gid >> 6, lane = gid & 63;
  int h = wave & 3, k = wave >> 2;
  if (k >= 16) return;
  const float* wrow = We + (size_t)k * (4*C) + (size_t)h * C;
  const float* ar = ae + (size_t)h * C;
  float s = 0.f;
  for (int c = lane; c < C; c += 64) s += wrow[c] * ar[c];
  s = wred64(s);
  if (lane == 0) outp[k*4 + h] = s;
}

// as[n,h], ad[n,h] = x[n,:] @ Ws/Wd. Block per node.
__global__ __launch_bounds__(256) void k_asad(const float* __restrict__ x, const float* __restrict__ Ws,
                      const float* __restrict__ Wd, float* __restrict__ as_,
                      float* __restrict__ ad_, int D){
  int n = blockIdx.x, t = threadIdx.x;
  const float* row = x + (size_t)n * D;
  float p[8] = {0,0,0,0,0,0,0,0};
  for (int c = t; c < D; c += 256){
    float xv = row[c];
    float4 ws4 = *(const float4*)&Ws[c*4];
    float4 wd4 = *(const float4*)&Wd[c*4];
    p[0] += xv * ws4.x; p[1] += xv * ws4.y; p[2] += xv * ws4.z; p[3] += xv * ws4.w;
    p[4] += xv * wd4.x; p[5] += xv * wd4.y; p[6] += xv * wd4.z; p[7] += xv * wd4.w;
  }
  __shared__ float sm[4][8];
  int lane = t & 63, wid = t >> 6;
#pragma unroll
  for (int q = 0; q < 8; q++){
    float v = wred64(p[q]);
    if (lane == 0) sm[wid][q] = v;
  }
  __syncthreads();
  if (t < 8){
    float s = sm[0][t] + sm[1][t] + sm[2][t] + sm[3][t];
    if (t < 4) as_[(size_t)n*4 + t] = s;
    else       ad_[(size_t)n*4 + (t-4)] = s;
  }
}

__global__ void k_edge(const float* __restrict__ eattr, const float* __restrict__ lp,
                       const int* __restrict__ ei, const float* __restrict__ as_,
                       const float* __restrict__ ad_, const float* __restrict__ aep,
                       float* __restrict__ ebuf){
  int e = blockIdx.x * 256 + threadIdx.x;
  if (e >= NEf) return;
  int s, d; const float* ea;
  if (e < Ne){ s = ei[e]; d = ei[Ne + e]; ea = eattr + (size_t)e * 16; }
  else { s = e - Ne; d = e - Ne; ea = lp + (size_t)(e - Ne) * 16; }
  float eav[16];
#pragma unroll
  for (int k = 0; k < 16; k++) eav[k] = ea[k];
#pragma unroll
  for (int h = 0; h < 4; h++){
    float v = as_[(size_t)s*4 + h] + ad_[(size_t)d*4 + h];
#pragma unroll
    for (int k = 0; k < 16; k++) v += eav[k] * aep[k*4 + h];
    ebuf[(size_t)e*4 + h] = lrelu(v, 0.2f);
  }
}

// wave-per-node softmax: 4 waves/block, 1024 blocks. Lanes cover edges in parallel;
// all 4 heads per edge as float4; wave-wide max/sum via xor-butterfly (deterministic).
__global__ __launch_bounds__(256) void k_softmax(const int* __restrict__ rowptr, const int* __restrict__ eids,
                          const float* __restrict__ ebuf, float* __restrict__ alpha){
  const int wid = threadIdx.x >> 6, lane = threadIdx.x & 63;
  const int n = blockIdx.x * 4 + wid;
  const int b = rowptr[n], e = rowptr[n + 1];
  float4 m = {-1e30f, -1e30f, -1e30f, -1e30f};
  for (int j = b + lane; j < e; j += 64){
    float4 ev = *(const float4*)&ebuf[(size_t)eids[j]*4];
    m.x = fmaxf(m.x, ev.x); m.y = fmaxf(m.y, ev.y);
    m.z = fmaxf(m.z, ev.z); m.w = fmaxf(m.w, ev.w);
  }
#pragma unroll
  for (int o = 32; o > 0; o >>= 1){
    m.x = fmaxf(m.x, __shfl_xor(m.x, o, 64));
    m.y = fmaxf(m.y, __shfl_xor(m.y, o, 64));
    m.z = fmaxf(m.z, __shfl_xor(m.z, o, 64));
    m.w = fmaxf(m.w, __shfl_xor(m.w, o, 64));
  }
  float4 s = {0.f, 0.f, 0.f, 0.f};
  for (int j = b + lane; j < e; j += 64){
    int eid = eids[j];
    float4 ev = *(const float4*)&ebuf[(size_t)eid*4];
    float4 ex = { expf(ev.x - m.x), expf(ev.y - m.y), expf(ev.z - m.z), expf(ev.w - m.w) };
    *(float4*)&alpha[(size_t)eid*4] = ex;
    s.x += ex.x; s.y += ex.y; s.z += ex.z; s.w += ex.w;
  }
#pragma unroll
  for (int o = 32; o > 0; o >>= 1){
    s.x += __shfl_xor(s.x, o, 64);
    s.y += __shfl_xor(s.y, o, 64);
    s.z += __shfl_xor(s.z, o, 64);
    s.w += __shfl_xor(s.w, o, 64);
  }
  float4 r = { 1.f/s.x, 1.f/s.y, 1.f/s.z, 1.f/s.w };
  for (int j = b + lane; j < e; j += 64){
    int eid = eids[j];
    float4 av = *(const float4*)&alpha[(size_t)eid*4];
    av.x *= r.x; av.y *= r.y; av.z *= r.z; av.w *= r.w;
    *(float4*)&alpha[(size_t)eid*4] = av;
  }
}

// z1[n, h*512+c] = sum_e alpha[e,h] * x[src(e),c], written bf16 hi/lo split
__global__ __launch_bounds__(256) void k_agg1_split(const float* __restrict__ x, const float* __restrict__ alpha,
                      const int* __restrict__ rowptr, const int* __restrict__ eids,
                      const int* __restrict__ ei, unsigned short* __restrict__ z1hi,
                      unsigned short* __restrict__ z1lo){
  int n = blockIdx.x, t = threadIdx.x;
  float2 a0 = {0,0}, a1 = {0,0}, a2 = {0,0}, a3 = {0,0};
  int b = rowptr[n], e = rowptr[n + 1];
  for (int j = b; j < e; ++j){
    int eid = eids[j];
    int s = (eid < Ne) ? ei[eid] : (eid - Ne);
    float4 av = *(const float4*)&alpha[(size_t)eid*4];
    float2 xv = *(const float2*)&x[(size_t)s*512 + t*2];
    a0.x += av.x*xv.x; a0.y += av.x*xv.y;
    a1.x += av.y*xv.x; a1.y += av.y*xv.y;
    a2.x += av.z*xv.x; a2.y += av.z*xv.y;
    a3.x += av.w*xv.x; a3.y += av.w*xv.y;
  }
  size_t base = (size_t)n*2048 + t*2;
  float2 av[4] = {a0, a1, a2, a3};
#pragma unroll
  for (int h = 0; h < 4; h++){
    ushort2 hh, ll;
    split2(av[h].x, hh.x, ll.x);
    split2(av[h].y, hh.y, ll.y);
    *(ushort2*)&z1hi[base + h*512] = hh;
    *(ushort2*)&z1lo[base + h*512] = ll;
  }
}

// x2 fp32 -> fp16 hi/lo split (one pass)
__global__ void k_splitx2(const float* __restrict__ x2, unsigned short* __restrict__ xh,
                          unsigned short* __restrict__ xl){
  int i = blockIdx.x * 256 + threadIdx.x;   // over (4096*2048)/4 float4s
  float4 v = ((const float4*)x2)[i];
  ushort4 h, l;
  split2h(v.x, h.x, l.x); split2h(v.y, h.y, l.y);
  split2h(v.z, h.z, l.z); split2h(v.w, h.w, l.w);
  ((ushort4*)xh)[i] = h;
  ((ushort4*)xl)[i] = l;
}

// x3[n,:] = lrelu( sum_e alpha[e,h]*H[src,:] + b2_h, 0.01 ), fp16 in/out. Block per dst node.
__global__ __launch_bounds__(256) void k_agg2b(const unsigned short* __restrict__ H,
                      const float* __restrict__ alpha,
                      const int* __restrict__ rowptr, const int* __restrict__ eids,
                      const int* __restrict__ ei, unsigned short* __restrict__ x3,
                      const float* __restrict__ b2, int h){
  int n = blockIdx.x, t = threadIdx.x;
  float acc[8] = {0,0,0,0,0,0,0,0};
  int b = rowptr[n], e = rowptr[n + 1];
  for (int j = b; j < e; ++j){
    int eid = eids[j];
    int s = (eid < Ne) ? ei[eid] : (eid - Ne);
    float a = alpha[(size_t)eid*4 + h];
    f16x8 hv = *(const f16x8*)&H[(size_t)s*2048 + t*8];
#pragma unroll
    for (int q = 0; q < 8; q++) acc[q] += a * (float)hv[q];
  }
  const float* bb = b2 + (size_t)h*2048 + t*8;
  ushort4 o0, o1;
  float4 b0 = *(const float4*)bb;
  float4 b1 = *(const float4*)(bb + 4);
  o0.x = f2h(lrelu(acc[0] + b0.x, 0.01f)); o0.y = f2h(lrelu(acc[1] + b0.y, 0.01f));
  o0.z = f2h(lrelu(acc[2] + b0.z, 0.01f)); o0.w = f2h(lrelu(acc[3] + b0.w, 0.01f));
  o1.x = f2h(lrelu(acc[4] + b1.x, 0.01f)); o1.y = f2h(lrelu(acc[5] + b1.y, 0.01f));
  o1.z = f2h(lrelu(acc[6] + b1.z, 0.01f)); o1.w = f2h(lrelu(acc[7] + b1.w, 0.01f));
  size_t base = (size_t)n*2048 + t*8;
  *(ushort4*)&x3[base]     = o0;
  *(ushort4*)&x3[base + 4] = o1;
}

// transpose + split: out[col][k] = split(W[k][coloff+col]); out stride K.
// HALF: fp16 split; STORELO: write lo array.
template<bool HALF, bool STORELO>
__global__ __launch_bounds__(256) void k_wsplit(const float* __restrict__ W, int ldw, int coloff, int K,
                       unsigned short* __restrict__ whi, unsigned short* __restrict__ wlo){
  __shared__ float tile[32][33];
  int bk = blockIdx.x * 32, bn = blockIdx.y * 32;
  int tx = threadIdx.x & 31, ty = threadIdx.x >> 5;
#pragma unroll
  for (int i = 0; i < 4; i++){
    int k = bk + ty + i*8;
    tile[ty + i*8][tx] = W[(size_t)k*ldw + coloff + bn + tx];
  }
  __syncthreads();
#pragma unroll
  for (int i = 0; i < 4; i++){
    int n = bn + ty + i*8;
    float v = tile[tx][ty + i*8];
    unsigned short hh, ll;
    if (HALF) split2h(v, hh, ll); else split2(v, hh, ll);
    whi[(size_t)n*K + bk + tx] = hh;
    if (STORELO) wlo[(size_t)n*K + bk + tx] = ll;
  }
}

// ---------------- L2 dense GEMM: H[4096][2048] = x2[4096][2048k] x W2h^T[2048n][2048k]
// fp16 2-term: C = Ah*Bh + Al*Bh (A = x2 hi+lo fp16 near-exact; B = W2 fp16 hi only).
// BM=128, BN=256, 8 waves, 2 phases x 16 MFMA per K-step(32), 3-buffer LDS (96KB),
// counted vmcnt(4), 2-deep prefetch. fp16 out.
__global__ __launch_bounds__(512) void k_gemm256(
    const unsigned short* __restrict__ Ah, const unsigned short* __restrict__ Al,
    const unsigned short* __restrict__ Bh, unsigned short* __restrict__ Cout)
{
  __shared__ __align__(16) unsigned short lds[49152];   // 3 x (A 8192 + B 8192) ushorts
  const int t = threadIdx.x;
  const int brow = blockIdx.y * 128, bcol = blockIdx.x * 256;
  const int w = t >> 6, lane = t & 63;
  const int wm = (w >> 2) * 64, wn = (w & 3) * 64;
  constexpr int BUF = 16384, BOFF = 8192;   // ushorts

  // A staging: slot = i*512+t -> row = i*64+(t>>3), phys chunk t&7, logical = phys^(row&7)
  const int asr = t >> 3;
  const int ascc = (t & 7) ^ (asr & 7);
  const unsigned short* asrc = (ascc < 4 ? Ah : Al) + (size_t)(brow + asr)*2048 + (size_t)(ascc & 3)*8;
  // B staging: slot = i*512+t -> row = i*128+(t>>2), phys chunk t&3, logical = phys^(row&3)
  const int bsr = t >> 2;
  const int bscc = (t & 3) ^ (bsr & 3);
  const unsigned short* bsrc = Bh + (size_t)(bcol + bsr)*2048 + (size_t)bscc*8;
  const int adst = w * 512;           // + buf*BUF + i*4096 (+ lane*16B implicit)
  const int bdst = BOFF + w * 512;

  // fragment read offsets (ushort units, within buffer)
  const int fr = lane & 15, kc = lane >> 4;
  const int aswz = (kc ^ (lane & 7)) * 8;
  const int bswz = (kc ^ (lane & 3)) * 8;
  int aoff[4], boff[4];
#pragma unroll
  for (int m = 0; m < 4; m++) aoff[m] = (wm + m*16 + fr)*64 + aswz;
#pragma unroll
  for (int n = 0; n < 4; n++) boff[n] = BOFF + (wn + n*16 + fr)*32 + bswz;

  f32x4 acc[4][4];
#pragma unroll
  for (int m = 0; m < 4; m++)
#pragma unroll
    for (int n = 0; n < 4; n++) acc[m][n] = f32x4{0.f, 0.f, 0.f, 0.f};

  // prologue: stage tile 0 (buf0) FULLY FIRST, then tile 1 (buf1).
  // vmcnt counts oldest-first: vmcnt(4) => the 4 oldest (ALL of tile 0) complete.
  gload16(asrc,                        &lds[adst]);
  gload16(asrc + (size_t)64*2048,      &lds[4096 + adst]);
  gload16(bsrc,                        &lds[bdst]);
  gload16(bsrc + (size_t)128*2048,     &lds[4096 + bdst]);
  gload16(asrc + 32,                   &lds[BUF + adst]);
  gload16(asrc + (size_t)64*2048 + 32, &lds[BUF + 4096 + adst]);
  gload16(bsrc + 32,                   &lds[BUF + bdst]);
  gload16(bsrc + (size_t)128*2048 + 32,&lds[BUF + 4096 + bdst]);
  asm volatile("s_waitcnt vmcnt(4)" ::: "memory");   // tile 0 landed; tile 1 in flight
  __builtin_amdgcn_s_barrier();

  for (int kt = 0; kt < 64; ++kt){
    const int bufo = (kt % 3) * BUF;
    const int nbo  = ((kt + 2) % 3) * BUF;
    const size_t nko = (size_t)(kt + 2) * 32;
    const bool pf = (kt + 2) < 64;

    f16x8 ah[4], al[4];
    // ---- phase 0: A frags + B0,B1; prefetch A of tile kt+2
#pragma unroll
    for (int m = 0; m < 4; m++){
      ah[m] = *(const f16x8*)&lds[bufo + aoff[m]];
      al[m] = *(const f16x8*)&lds[bufo + (aoff[m] ^ 32)];
    }
    {
      f16x8 b0 = *(const f16x8*)&lds[bufo + boff[0]];
      f16x8 b1 = *(const f16x8*)&lds[bufo + boff[1]];
      if (pf){
        gload16(asrc + nko,                   &lds[nbo + adst]);
        gload16(asrc + (size_t)64*2048 + nko, &lds[nbo + 4096 + adst]);
      }
      __builtin_amdgcn_s_barrier();
      asm volatile("s_waitcnt lgkmcnt(0)");
      __builtin_amdgcn_s_setprio(1);
#pragma unroll
      for (int m = 0; m < 4; m++) acc[m][0] = __builtin_amdgcn_mfma_f32_16x16x32_f16(ah[m], b0, acc[m][0], 0, 0, 0);
#pragma unroll
      for (int m = 0; m < 4; m++) acc[m][0] = __builtin_amdgcn_mfma_f32_16x16x32_f16(al[m], b0, acc[m][0], 0, 0, 0);
#pragma unroll
      for (int m = 0; m < 4; m++) acc[m][1] = __builtin_amdgcn_mfma_f32_16x16x32_f16(ah[m], b1, acc[m][1], 0, 0, 0);
#pragma unroll
      for (int m = 0; m < 4; m++) acc[m][1] = __builtin_amdgcn_mfma_f32_16x16x32_f16(al[m], b1, acc[m][1], 0, 0, 0);
      __builtin_amdgcn_s_setprio(0);
      __builtin_amdgcn_s_barrier();
    }
    // ---- phase 1: B2,B3; prefetch B of tile kt+2
    {
      f16x8 b2 = *(const f16x8*)&lds[bufo + boff[2]];
      f16x8 b3 = *(const f16x8*)&lds[bufo + boff[3]];
      if (pf){
        gload16(bsrc + nko,                    &lds[nbo + bdst]);
        gload16(bsrc + (size_t)128*2048 + nko, &lds[nbo + 4096 + bdst]);
      }
      __builtin_amdgcn_s_barrier();
      asm volatile("s_waitcnt lgkmcnt(0)");
      __builtin_amdgcn_s_setprio(1);
#pragma unroll
      for (int m = 0; m < 4; m++) acc[m][2] = __builtin_amdgcn_mfma_f32_16x16x32_f16(ah[m], b2, acc[m][2], 0, 0, 0);
#pragma unroll
      for (int m = 0; m < 4; m++) acc[m][2] = __builtin_amdgcn_mfma_f32_16x16x32_f16(al[m], b2, acc[m][2], 0, 0, 0);
#pragma unroll
      for (int m = 0; m < 4; m++) acc[m][3] = __builtin_amdgcn_mfma_f32_16x16x32_f16(ah[m], b3, acc[m][3], 0, 0, 0);
#pragma unroll
      for (int m = 0; m < 4; m++) acc[m][3] = __builtin_amdgcn_mfma_f32_16x16x32_f16(al[m], b3, acc[m][3], 0, 0, 0);
      __builtin_amdgcn_s_setprio(0);
      __builtin_amdgcn_s_barrier();
    }
    // ---- end of K-step: tile kt+1 must be complete; keep tile kt+2's 4 loads in flight
    if (pf) asm volatile("s_waitcnt vmcnt(4)" ::: "memory");
    else    asm volatile("s_waitcnt vmcnt(0)" ::: "memory");
    __builtin_amdgcn_s_barrier();
  }

  // ---- epilogue: fp16 store. C/D frag: col=lane&15, row=(lane>>4)*4+reg
#pragma unroll
  for (int m = 0; m < 4; m++){
    const int row0 = brow + wm + m*16 + kc*4;
#pragma unroll
    for (int n = 0; n < 4; n++){
      const int col = bcol + wn + n*16 + fr;
#pragma unroll
      for (int r = 0; r < 4; r++)
        Cout[(size_t)(row0 + r)*2048 + col] = f2h(acc[m][n][r]);
    }
  }
}

// ---------------- MFMA GEMM (128x128): bf16 3-term, or fp16 exact-A 2-term ----------------
template<int KLEN, bool EXACTA, bool HALF, bool OUTF32, bool BETA1, bool ACT, bool HASBIAS>
__global__ __launch_bounds__(256) void k_gemm2(
    const unsigned short* __restrict__ Ah, const unsigned short* __restrict__ Al, int lda, size_t az,
    const unsigned short* __restrict__ Bh, const unsigned short* __restrict__ Bl, int ldb, size_t bz,
    void* __restrict__ Cout, int ldc, size_t cz,
    const float* __restrict__ bias, size_t biasz)
{
  __shared__ unsigned short lds[16384];   // A: [0,8192) ushorts, B: [8192,16384)
  const int t = threadIdx.x;
  const int z = blockIdx.z;
  const int brow = blockIdx.y * 128, bcol = blockIdx.x * 128;
  const int wid = t >> 6, lane = t & 63;
  const int wm = (wid >> 1) * 64, wn = (wid & 1) * 64;

  const int sr = t >> 3, sc = t & 7;
  const int scc = sc ^ (sr & 7);
  const unsigned short* asrc = (scc < 4 ? Ah : Al) + (size_t)(brow + sr)*lda + (size_t)z*az + (size_t)(scc & 3)*8;
  const unsigned short* bsrc = (scc < 4 ? Bh : Bl) + (size_t)(bcol + sr)*ldb + (size_t)z*bz + (size_t)(scc & 3)*8;
  unsigned short* adst = &lds[(size_t)wid * 512];
  unsigned short* bdst = &lds[8192 + (size_t)wid * 512];

  const int fr = lane & 15, kc = lane >> 4;
  const int swz = ((kc ^ (lane & 7)) << 3);
  int aoff[4], boff[4];
#pragma unroll
  for (int m = 0; m < 4; m++) aoff[m] = (wm + m*16 + fr)*64 + swz;
#pragma unroll
  for (int n = 0; n < 4; n++) boff[n] = 8192 + (wn + n*16 + fr)*64 + swz;

  f32x4 acc[4][4];
#pragma unroll
  for (int m = 0; m < 4; m++)
#pragma unroll
    for (int n = 0; n < 4; n++) acc[m][n] = f32x4{0.f, 0.f, 0.f, 0.f};

  for (int kt = 0; kt < KLEN/32; ++kt){
    const size_t ko = (size_t)kt * 32;
#pragma unroll
    for (int i = 0; i < 4; i++){
      gload16(asrc + (size_t)i*32*lda + ko, adst + i*2048);
      gload16(bsrc + (size_t)i*32*ldb + ko, bdst + i*2048);
    }
    __syncthreads();

    if (HALF){
      f16x8 ah[4], bh[4], bl[4];
#pragma unroll
      for (int m = 0; m < 4; m++) ah[m] = *(const f16x8*)&lds[aoff[m]];
#pragma unroll
      for (int n = 0; n < 4; n++){
        bh[n] = *(const f16x8*)&lds[boff[n]];
        bl[n] = *(const f16x8*)&lds[boff[n] ^ 32];
      }
#pragma unroll
      for (int m = 0; m < 4; m++)
#pragma unroll
        for (int n = 0; n < 4; n++){
          acc[m][n] = __builtin_amdgcn_mfma_f32_16x16x32_f16(ah[m], bh[n], acc[m][n], 0, 0, 0);
          acc[m][n] = __builtin_amdgcn_mfma_f32_16x16x32_f16(ah[m], bl[n], acc[m][n], 0, 0, 0);
        }
    } else {
      bf16x8 ah[4], al[4], bh[4], bl[4];
#pragma unroll
      for (int m = 0; m < 4; m++){
        ah[m] = *(const bf16x8*)&lds[aoff[m]];
        if (!EXACTA) al[m] = *(const bf16x8*)&lds[aoff[m] ^ 32];
      }
#pragma unroll
      for (int n = 0; n < 4; n++){
        bh[n] = *(const bf16x8*)&lds[boff[n]];
        bl[n] = *(const bf16x8*)&lds[boff[n] ^ 32];
      }
#pragma unroll
      for (int m = 0; m < 4; m++)
#pragma unroll
        for (int n = 0; n < 4; n++){
          acc[m][n] = __builtin_amdgcn_mfma_f32_16x16x32_bf16(ah[m], bh[n], acc[m][n], 0, 0, 0);
          acc[m][n] = __builtin_amdgcn_mfma_f32_16x16x32_bf16(ah[m], bl[n], acc[m][n], 0, 0, 0);
          if (!EXACTA)
            acc[m][n] = __builtin_amdgcn_mfma_f32_16x16x32_bf16(al[m], bh[n], acc[m][n], 0, 0, 0);
        }
    }
    __syncthreads();
  }

  float bv[4] = {0.f, 0.f, 0.f, 0.f};
  if (HASBIAS){
#pragma unroll
    for (int n = 0; n < 4; n++) bv[n] = bias[(size_t)z*biasz + bcol + wn + n*16 + fr];
  }
  float* Cf = (float*)Cout + (size_t)z*cz;
  unsigned short* Cb = (unsigned short*)Cout + (size_t)z*cz;
#pragma unroll
  for (int m = 0; m < 4; m++){
    const int row0 = brow + wm + m*16 + kc*4;
#pragma unroll
    for (int n = 0; n < 4; n++){
      const int col = bcol + wn + n*16 + fr;
#pragma unroll
      for (int r = 0; r < 4; r++){
        float v = acc[m][n][r] + bv[n];
        if (ACT) v = lrelu(v, 0.01f);
        if (OUTF32){
          float* cp = &Cf[(size_t)(row0 + r)*ldc + col];
          if (BETA1) v += *cp;
          *cp = v;
        } else {
          Cb[(size_t)(row0 + r)*ldc + col] = f2bf(v);
        }
      }
    }
  }
}

// stage 1: per (slice, graph) partial sums over stride-32 node slices
__global__ void k_gsum(const float* __restrict__ yp, const float* __restrict__ bout,
                       const int* __restrict__ batch, float* __restrict__ part){
  const int s = blockIdx.x, g = blockIdx.y, t = threadIdx.x;
  __shared__ int sb[2];
  if (t < 2){
    int key = g + t, lo = 0, hi = Nn;
    while (lo < hi){ int mid = (lo + hi) >> 1; if (batch[mid] < key) lo = mid + 1; else hi = mid; }
    sb[t] = lo;
  }
  __syncthreads();
  const int b = sb[0], e = sb[1];
  const size_t P = (size_t)Nn * 256;
  float acc = 0.f;
  float bt = bout[t];
  for (int n = b + s; n < e; n += 32){
    size_t i = (size_t)n*256 + t;
    float v = yp[i] + yp[P + i] + yp[2*P + i] + yp[3*P + i] + bt;
    acc += lrelu(v, 0.01f);
  }
  part[(size_t)(g*32 + s)*256 + t] = acc;
}

// stage 2: sum 32 slices, divide by count
__global__ void k_gfin(const float* __restrict__ part, const int* __restrict__ batch,
                       float* __restrict__ out){
  const int g = blockIdx.x, t = threadIdx.x;
  __shared__ int sb[2];
  if (t < 2){
    int key = g + t, lo = 0, hi = Nn;
    while (lo < hi){ int mid = (lo + hi) >> 1; if (batch[mid] < key) lo = mid + 1; else hi = mid; }
    sb[t] = lo;
  }
  __syncthreads();
  const int cnt = sb[1] - sb[0];
  float s = 0.f;
#pragma unroll
  for (int k = 0; k < 32; k++) s += part[(size_t)(g*32 + k)*256 + t];
  out[g*256 + t] = s / fmaxf((float)cnt, 1.f);
}

// ---------------- launch ----------------
extern "C" void kernel_launch(void* const* d_in, const int* in_sizes, int n_in,
                              void* d_out, int out_size, void* d_ws, size_t ws_size,
                              hipStream_t stream){
  const float* xg    = (const float*)d_in[0];
  const float* ac    = (const float*)d_in[1];
  const float* ti    = (const float*)d_in[2];
  const float* eattr = (const float*)d_in[3];
  const int*   ei    = (const int*)  d_in[4];
  const int*   batch = (const int*)  d_in[5];
  const float* W1    = (const float*)d_in[6];
  const float* as1w  = (const float*)d_in[7];
  const float* ad1w  = (const float*)d_in[8];
  const float* ae1w  = (const float*)d_in[9];
  const float* We1   = (const float*)d_in[10];
  const float* b1    = (const float*)d_in[11];
  const float* W2    = (const float*)d_in[12];
  const float* as2w  = (const float*)d_in[13];
  const float* ad2w  = (const float*)d_in[14];
  const float* ae2w  = (const float*)d_in[15];
  const float* We2   = (const float*)d_in[16];
  const float* b2    = (const float*)d_in[17];
  const float* Wout  = (const float*)d_in[18];
  const float* bout  = (const float*)d_in[19];
  float* out = (float*)d_out;
  float* ws  = (float*)d_ws;
  if (ws_size < WS_FLOATS * sizeof(float)) return;
  int* iws = (int*)(ws + OFF_I);

  unsigned short* z1hi = (unsigned short*)(ws + OFF_Z1HI);
  unsigned short* z1lo = (unsigned short*)(ws + OFF_Z1LO);
  unsigned short* wt1h = (unsigned short*)(ws + OFF_WT1H);
  unsigned short* wt1l = (unsigned short*)(ws + OFF_WT1L);
  unsigned short* x2hi = (unsigned short*)(ws + OFF_X2HI);
  unsigned short* x2lo = (unsigned short*)(ws + OFF_X2LO);
  unsigned short* whi  = (unsigned short*)(ws + OFF_X);
  unsigned short* woh  = (unsigned short*)(ws + OFF_WOH);
  unsigned short* wol  = (unsigned short*)(ws + OFF_WOL);
  unsigned short* Hb   = (unsigned short*)(ws + OFF_H);
  unsigned short* x3   = (unsigned short*)(ws + OFF_X3);

  hipMemsetAsync(iws + I_DEG, 0, Nn * sizeof(int), stream);
  k_concat <<<8192, 256, 0, stream>>>(xg, ac, ti, ws + OFF_X);
  k_count  <<<128,  256, 0, stream>>>(ei, iws + I_DEG);
  k_scan   <<<1,   1024, 0, stream>>>(iws + I_DEG, iws + I_RP, iws + I_CUR);
  k_fill   <<<144,  256, 0, stream>>>(ei, iws + I_CUR, iws + I_EID);
  k_sort   <<<16,   256, 0, stream>>>(iws + I_RP, iws + I_EID);
  k_loopattr<<<256, 256, 0, stream>>>(eattr, iws + I_RP, iws + I_EID, ws + OFF_LP);

  k_proj   <<<512,  256, 0, stream>>>(W1, as1w, ad1w, ws + OFF_WS1, ws + OFF_WD1, 512, 512);
  k_proj   <<<2048, 256, 0, stream>>>(W2, as2w, ad2w, ws + OFF_WS2, ws + OFF_WD2, 2048, 2048);
  k_aeproj <<<16,   256, 0, stream>>>(We1, ae1w, ws + OFF_AE1, 512);
  k_aeproj <<<16,   256, 0, stream>>>(We2, ae2w, ws + OFF_AE2, 2048);
  k_wsplit<true, true><<<dim3(256, 8), 256, 0, stream>>>(Wout, 256, 0, 8192, woh, wol);   // fp16 [256][8192]

  // ---- layer 1 (bf16 3-term, unchanged) ----
  k_asad      <<<4096, 256, 0, stream>>>(ws + OFF_X, ws + OFF_WS1, ws + OFF_WD1, ws + OFF_AS1, ws + OFF_AD1, 512);
  k_edge      <<<144,  256, 0, stream>>>(eattr, ws + OFF_LP, ei, ws + OFF_AS1, ws + OFF_AD1, ws + OFF_AE1, ws + OFF_EB);
  k_softmax   <<<1024, 256, 0, stream>>>(iws + I_RP, iws + I_EID, ws + OFF_EB, ws + OFF_AL);
  k_agg1_split<<<4096, 256, 0, stream>>>(ws + OFF_X, ws + OFF_AL, iws + I_RP, iws + I_EID, ei, z1hi, z1lo);
  // X dead; wt1 overlays it
  k_wsplit<false, true><<<dim3(16, 64), 256, 0, stream>>>(W1, 2048, 0, 512, wt1h, wt1l);  // bf16 [2048][512]
  k_gemm2<512, false, false, true, false, true, true><<<dim3(4, 32, 4), 256, 0, stream>>>(
      z1hi, z1lo, 2048, 512,  wt1h, wt1l, 512, 512*512,
      ws + OFF_X2, 2048, 512,  b1, 512);

  // ---- layer 2 attention ----
  k_asad   <<<4096, 256, 0, stream>>>(ws + OFF_X2, ws + OFF_WS2, ws + OFF_WD2, ws + OFF_AS2, ws + OFF_AD2, 2048);
  k_edge   <<<144,  256, 0, stream>>>(eattr, ws + OFF_LP, ei, ws + OFF_AS2, ws + OFF_AD2, ws + OFF_AE2, ws + OFF_EB);
  k_softmax<<<1024, 256, 0, stream>>>(iws + I_RP, iws + I_EID, ws + OFF_EB, ws + OFF_AL);

  // x2 fp32 -> fp16 hi/lo split (z1 regions dead); x2 fp32 dead afterwards
  k_splitx2<<<8192, 256, 0, stream>>>(ws + OFF_X2, x2hi, x2lo);

  // ---- layer 2 + fc, per head: H = x2@W2_h^T (fp16 MFMA), sparse agg of fp16 H, fp16 FC ----
  for (int h = 0; h < 4; ++h){
    k_wsplit<true, false><<<dim3(64, 64), 256, 0, stream>>>(W2, 8192, h*2048, 2048, whi, nullptr);
    k_gemm256 <<<dim3(8, 32), 512, 0, stream>>>(x2hi, x2lo, whi, Hb);
    k_agg2b   <<<4096, 256, 0, stream>>>(Hb, ws + OFF_AL, iws + I_RP, iws + I_EID, ei, x3, b2, h);
    if (h == 0)
      k_gemm2<512, true, true, true, false, false, false><<<dim3(2, 32, 4), 256, 0, stream>>>(
          x3, x3, 2048, 512,  woh + (size_t)h*2048, wol + (size_t)h*2048, 8192, 512,
          ws + OFF_YP, 256, (size_t)Nn*256,  nullptr, 0);
    else
      k_gemm2<512, true, true, true, true, false, false><<<dim3(2, 32, 4), 256, 0, stream>>>(
          x3, x3, 2048, 512,  woh + (size_t)h*2048, wol + (size_t)h*2048, 8192, 512,
          ws + OFF_YP, 256, (size_t)Nn*256,  nullptr, 0);
  }

  k_gsum<<<dim3(32, 8), 256, 0, stream>>>(ws + OFF_YP, bout, batch, ws + OFF_PART);
  k_gfin<<<8, 256, 0, stream>>>(ws + OFF_PART, batch, out);
}

// Round 9
// 735.514 us; speedup vs baseline: 4.0130x; 1.0145x over previous
//
#include <hip/hip_runtime.h>
#include <math.h>

constexpr int Nn  = 4096;
constexpr int Ne  = 32768;
constexpr int NEf = Ne + Nn;     // real edges + self loops

// ---------------- ws layout (float offsets) ----------------
// region reuse timeline:
//   R0 [0..2097152)          X fp32 (prep/L1) -> wt1 hi/lo bf16 (L1 gemm) -> whi fp16 [2048][2048] (L2 loop)
//   R1 [2097152..10485760)   z1 hi/lo bf16 (L1) -> x2hi/x2lo fp16 [4096][2048] (L2) -> part fp32 (final)
//   R2 [10485760..18874368)  X2 fp32 -> x3 fp16 [4096][2048] (L2 loop, after split)
//   R3 [18874368..23068672)  H fp16 [4096][2048] (L2 loop)
//   R4 [23068672..25165824)  (free)
//   R5 [25165824..27262976)  wtout hi/lo fp16 [256][8192]
//   R6 [27262976..31457280)  YP 4x [4096][256] fp32
constexpr size_t OFF_X    = 0;
constexpr size_t OFF_WT1H = 0;
constexpr size_t OFF_WT1L = 524288;
constexpr size_t OFF_Z1HI = 2097152;
constexpr size_t OFF_Z1LO = 6291456;
constexpr size_t OFF_X2HI = 2097152;
constexpr size_t OFF_X2LO = 6291456;
constexpr size_t OFF_PART = 2097152;     // 8*32*256 fp32 (final)
constexpr size_t OFF_X2   = 10485760;
constexpr size_t OFF_X3   = 10485760;    // ushort region (fp16), overlays dead X2
constexpr size_t OFF_H    = 18874368;    // ushort region (fp16) [4096][2048]
constexpr size_t OFF_WOH  = 25165824;    // ushort region [256][8192] fp16
constexpr size_t OFF_WOL  = 26214400;    // ushort region
constexpr size_t OFF_YP   = 27262976;
constexpr size_t OFF_LP  = 31457280;     // [N,16] self-loop edge attr
constexpr size_t OFF_WS1 = OFF_LP  + 65536;   // [512,4]
constexpr size_t OFF_WD1 = OFF_WS1 + 2048;    // [512,4]
constexpr size_t OFF_WS2 = OFF_WD1 + 2048;    // [2048,4]
constexpr size_t OFF_WD2 = OFF_WS2 + 8192;    // [2048,4]
constexpr size_t OFF_AE1 = OFF_WD2 + 8192;    // [16,4]
constexpr size_t OFF_AE2 = OFF_AE1 + 64;      // [16,4]
constexpr size_t OFF_AS1 = OFF_AE2 + 64;      // [N,4]
constexpr size_t OFF_AD1 = OFF_AS1 + 16384;
constexpr size_t OFF_AS2 = OFF_AD1 + 16384;
constexpr size_t OFF_AD2 = OFF_AS2 + 16384;
constexpr size_t OFF_EB  = OFF_AD2 + 16384;          // [Ef,4] logits
constexpr size_t OFF_AL  = OFF_EB  + (size_t)NEf*4;  // [Ef,4] alpha
constexpr size_t OFF_I   = OFF_AL  + (size_t)NEf*4;  // int region
constexpr size_t I_DEG = 0;       // [N]
constexpr size_t I_RP  = 4096;    // [N+1] (+pad)
constexpr size_t I_CUR = 8200;    // [N]
constexpr size_t I_EID = 12296;   // [Ef]
constexpr size_t WS_FLOATS = OFF_I + I_EID + (size_t)NEf + 64;

using bf16x8 = __bf16 __attribute__((ext_vector_type(8)));
using f16x8  = _Float16 __attribute__((ext_vector_type(8)));
using f32x4  = float __attribute__((ext_vector_type(4)));

__device__ __forceinline__ float wred64(float v){
#pragma unroll
  for (int o = 32; o > 0; o >>= 1) v += __shfl_down(v, o, 64);
  return v;
}
__device__ __forceinline__ float lrelu(float v, float s){ return v > 0.f ? v : s * v; }

__device__ __forceinline__ unsigned short f2bf(float x){  // RTNE
  unsigned int u = __float_as_uint(x);
  unsigned int r = (u + 0x7FFFu + ((u >> 16) & 1u)) >> 16;
  return (unsigned short)r;
}
__device__ __forceinline__ float bf2f(unsigned short h){
  return __uint_as_float((unsigned int)h << 16);
}
__device__ __forceinline__ void split2(float x, unsigned short& h, unsigned short& l){
  h = f2bf(x);
  l = f2bf(x - bf2f(h));
}
__device__ __forceinline__ unsigned short f2h(float x){
  _Float16 h = (_Float16)x;
  return __builtin_bit_cast(unsigned short, h);
}
__device__ __forceinline__ float h2f(unsigned short u){
  return (float)__builtin_bit_cast(_Float16, u);
}
__device__ __forceinline__ void split2h(float x, unsigned short& h, unsigned short& l){
  _Float16 hh = (_Float16)x;
  h = __builtin_bit_cast(unsigned short, hh);
  _Float16 ll = (_Float16)(x - (float)hh);
  l = __builtin_bit_cast(unsigned short, ll);
}
__device__ __forceinline__ void gload16(const void* g, void* l){
  __builtin_amdgcn_global_load_lds((const __attribute__((address_space(1))) void*)g,
                                   (__attribute__((address_space(3))) void*)l, 16, 0, 0);
}

// ---------------- small prep kernels ----------------
__global__ void k_concat(const float* __restrict__ xg, const float* __restrict__ ac,
                         const float* __restrict__ ti, float* __restrict__ x){
  int i = blockIdx.x * 256 + threadIdx.x;          // over N*512
  int n = i >> 9, c = i & 511;
  float v;
  if (c < 256)      v = xg[(size_t)n*256 + c];
  else if (c < 384) v = ac[(size_t)n*128 + (c-256)];
  else              v = ti[(size_t)n*128 + (c-384)];
  x[i] = v;
}

__global__ void k_count(const int* __restrict__ ei, int* __restrict__ deg){
  int e = blockIdx.x * 256 + threadIdx.x;
  if (e < Ne) atomicAdd(&deg[ei[Ne + e]], 1);
}

__global__ void k_scan(const int* __restrict__ deg, int* __restrict__ rowptr, int* __restrict__ cursor){
  __shared__ int sd[1024];
  int t = threadIdx.x;
  int v[4]; int s = 0;
#pragma unroll
  for (int i = 0; i < 4; i++){ v[i] = s; s += deg[t*4 + i] + 1; }   // +1 self loop
  sd[t] = s;
  __syncthreads();
  for (int off = 1; off < 1024; off <<= 1){
    int x = (t >= off) ? sd[t - off] : 0;
    __syncthreads();
    sd[t] += x;
    __syncthreads();
  }
  int base = (t == 0) ? 0 : sd[t - 1];
#pragma unroll
  for (int i = 0; i < 4; i++){ int rp = base + v[i]; rowptr[t*4 + i] = rp; cursor[t*4 + i] = rp; }
  if (t == 1023) rowptr[4096] = sd[1023];
}

__global__ void k_fill(const int* __restrict__ ei, int* __restrict__ cursor, int* __restrict__ eids){
  int e = blockIdx.x * 256 + threadIdx.x;
  if (e >= NEf) return;
  int d = (e < Ne) ? ei[Ne + e] : (e - Ne);
  int p = atomicAdd(&cursor[d], 1);
  eids[p] = e;
}

__global__ void k_sort(const int* __restrict__ rowptr, int* __restrict__ eids){
  int n = blockIdx.x * 256 + threadIdx.x;
  if (n >= Nn) return;
  int b = rowptr[n], e = rowptr[n + 1];
  for (int i = b + 1; i < e; i++){
    int key = eids[i]; int j = i - 1;
    while (j >= b && eids[j] > key){ eids[j+1] = eids[j]; j--; }
    eids[j+1] = key;
  }
}

__global__ void k_loopattr(const float* __restrict__ eattr, const int* __restrict__ rowptr,
                           const int* __restrict__ eids, float* __restrict__ lp){
  int idx = blockIdx.x * 256 + threadIdx.x;        // N*16
  int n = idx >> 4, a = idx & 15;
  if (n >= Nn) return;
  int b = rowptr[n], e = rowptr[n + 1];
  float s = 0.f; int cnt = 0;
  for (int j = b; j < e; ++j){
    int id = eids[j];
    if (id < Ne){ s += eattr[(size_t)id*16 + a]; cnt++; }
  }
  lp[(size_t)n*16 + a] = s / fmaxf((float)cnt, 1.f);
}

// Ws[k,h] = sum_c W[k, h*C+c]*a_s[h,c] ; Wd likewise.
__global__ void k_proj(const float* __restrict__ W, const float* __restrict__ a_s,
                       const float* __restrict__ a_d, float* __restrict__ Ws,
                       float* __restrict__ Wd, int K, int C){
  int gid = blockIdx.x * 256 + threadIdx.x;
  int wave = gid >> 6, lane = gid & 63;
  int h = wave & 3, k = wave >> 2;
  if (k >= K) return;
  const float* wrow = W + (size_t)k * (4*C) + (size_t)h * C;
  const float* ar = a_s + (size_t)h * C;
  const float* dr = a_d + (size_t)h * C;
  float ps = 0.f, pd = 0.f;
  for (int c = lane; c < C; c += 64){ float w = wrow[c]; ps += w * ar[c]; pd += w * dr[c]; }
  ps = wred64(ps); pd = wred64(pd);
  if (lane == 0){ Ws[k*4 + h] = ps; Wd[k*4 + h] = pd; }
}

// one wave per (k,h): outp[k*4+h] = dot(We[k, h*C:(h+1)*C], ae[h,:])
__global__ void k_aeproj(const float* __restrict__ We, const float* __restrict__ ae,
                         float* __restrict__ outp, int C){
  int gid = blockIdx.x * 256 + threadIdx.x;
  int wave = gid >> 6, lane = gid & 63;
  int h = wave & 3, k = wave >> 2;
  if (k >= 16) return;
  const float* wrow = We + (size_t)k * (4*C) + (size_t)h * C;
  const float* ar = ae + (size_t)h * C;
  float s = 0.f;
  for (int c = lane; c < C; c += 64) s += wrow[c] * ar[c];
  s = wred64(s);
  if (lane == 0) outp[k*4 + h] = s;
}

// as[n,h], ad[n,h] = x[n,:] @ Ws/Wd. Block per node.
__global__ __launch_bounds__(256) void k_asad(const float* __restrict__ x, const float* __restrict__ Ws,
                      const float* __restrict__ Wd, float* __restrict__ as_,
                      float* __restrict__ ad_, int D){
  int n = blockIdx.x, t = threadIdx.x;
  const float* row = x + (size_t)n * D;
  float p[8] = {0,0,0,0,0,0,0,0};
  for (int c = t; c < D; c += 256){
    float xv = row[c];
    float4 ws4 = *(const float4*)&Ws[c*4];
    float4 wd4 = *(const float4*)&Wd[c*4];
    p[0] += xv * ws4.x; p[1] += xv * ws4.y; p[2] += xv * ws4.z; p[3] += xv * ws4.w;
    p[4] += xv * wd4.x; p[5] += xv * wd4.y; p[6] += xv * wd4.z; p[7] += xv * wd4.w;
  }
  __shared__ float sm[4][8];
  int lane = t & 63, wid = t >> 6;
#pragma unroll
  for (int q = 0; q < 8; q++){
    float v = wred64(p[q]);
    if (lane == 0) sm[wid][q] = v;
  }
  __syncthreads();
  if (t < 8){
    float s = sm[0][t] + sm[1][t] + sm[2][t] + sm[3][t];
    if (t < 4) as_[(size_t)n*4 + t] = s;
    else       ad_[(size_t)n*4 + (t-4)] = s;
  }
}

__global__ void k_edge(const float* __restrict__ eattr, const float* __restrict__ lp,
                       const int* __restrict__ ei, const float* __restrict__ as_,
                       const float* __restrict__ ad_, const float* __restrict__ aep,
                       float* __restrict__ ebuf){
  int e = blockIdx.x * 256 + threadIdx.x;
  if (e >= NEf) return;
  int s, d; const float* ea;
  if (e < Ne){ s = ei[e]; d = ei[Ne + e]; ea = eattr + (size_t)e * 16; }
  else { s = e - Ne; d = e - Ne; ea = lp + (size_t)(e - Ne) * 16; }
  float eav[16];
#pragma unroll
  for (int k = 0; k < 16; k++) eav[k] = ea[k];
#pragma unroll
  for (int h = 0; h < 4; h++){
    float v = as_[(size_t)s*4 + h] + ad_[(size_t)d*4 + h];
#pragma unroll
    for (int k = 0; k < 16; k++) v += eav[k] * aep[k*4 + h];
    ebuf[(size_t)e*4 + h] = lrelu(v, 0.2f);
  }
}

// wave-per-node softmax: 4 waves/block, 1024 blocks.
__global__ __launch_bounds__(256) void k_softmax(const int* __restrict__ rowptr, const int* __restrict__ eids,
                          const float* __restrict__ ebuf, float* __restrict__ alpha){
  const int wid = threadIdx.x >> 6, lane = threadIdx.x & 63;
  const int n = blockIdx.x * 4 + wid;
  const int b = rowptr[n], e = rowptr[n + 1];
  float4 m = {-1e30f, -1e30f, -1e30f, -1e30f};
  for (int j = b + lane; j < e; j += 64){
    float4 ev = *(const float4*)&ebuf[(size_t)eids[j]*4];
    m.x = fmaxf(m.x, ev.x); m.y = fmaxf(m.y, ev.y);
    m.z = fmaxf(m.z, ev.z); m.w = fmaxf(m.w, ev.w);
  }
#pragma unroll
  for (int o = 32; o > 0; o >>= 1){
    m.x = fmaxf(m.x, __shfl_xor(m.x, o, 64));
    m.y = fmaxf(m.y, __shfl_xor(m.y, o, 64));
    m.z = fmaxf(m.z, __shfl_xor(m.z, o, 64));
    m.w = fmaxf(m.w, __shfl_xor(m.w, o, 64));
  }
  float4 s = {0.f, 0.f, 0.f, 0.f};
  for (int j = b + lane; j < e; j += 64){
    int eid = eids[j];
    float4 ev = *(const float4*)&ebuf[(size_t)eid*4];
    float4 ex = { expf(ev.x - m.x), expf(ev.y - m.y), expf(ev.z - m.z), expf(ev.w - m.w) };
    *(float4*)&alpha[(size_t)eid*4] = ex;
    s.x += ex.x; s.y += ex.y; s.z += ex.z; s.w += ex.w;
  }
#pragma unroll
  for (int o = 32; o > 0; o >>= 1){
    s.x += __shfl_xor(s.x, o, 64);
    s.y += __shfl_xor(s.y, o, 64);
    s.z += __shfl_xor(s.z, o, 64);
    s.w += __shfl_xor(s.w, o, 64);
  }
  float4 r = { 1.f/s.x, 1.f/s.y, 1.f/s.z, 1.f/s.w };
  for (int j = b + lane; j < e; j += 64){
    int eid = eids[j];
    float4 av = *(const float4*)&alpha[(size_t)eid*4];
    av.x *= r.x; av.y *= r.y; av.z *= r.z; av.w *= r.w;
    *(float4*)&alpha[(size_t)eid*4] = av;
  }
}

// z1[n, h*512+c] = sum_e alpha[e,h] * x[src(e),c], written bf16 hi/lo split
__global__ __launch_bounds__(256) void k_agg1_split(const float* __restrict__ x, const float* __restrict__ alpha,
                      const int* __restrict__ rowptr, const int* __restrict__ eids,
                      const int* __restrict__ ei, unsigned short* __restrict__ z1hi,
                      unsigned short* __restrict__ z1lo){
  int n = blockIdx.x, t = threadIdx.x;
  float2 a0 = {0,0}, a1 = {0,0}, a2 = {0,0}, a3 = {0,0};
  int b = rowptr[n], e = rowptr[n + 1];
  for (int j = b; j < e; ++j){
    int eid = eids[j];
    int s = (eid < Ne) ? ei[eid] : (eid - Ne);
    float4 av = *(const float4*)&alpha[(size_t)eid*4];
    float2 xv = *(const float2*)&x[(size_t)s*512 + t*2];
    a0.x += av.x*xv.x; a0.y += av.x*xv.y;
    a1.x += av.y*xv.x; a1.y += av.y*xv.y;
    a2.x += av.z*xv.x; a2.y += av.z*xv.y;
    a3.x += av.w*xv.x; a3.y += av.w*xv.y;
  }
  size_t base = (size_t)n*2048 + t*2;
  float2 av[4] = {a0, a1, a2, a3};
#pragma unroll
  for (int h = 0; h < 4; h++){
    ushort2 hh, ll;
    split2(av[h].x, hh.x, ll.x);
    split2(av[h].y, hh.y, ll.y);
    *(ushort2*)&z1hi[base + h*512] = hh;
    *(ushort2*)&z1lo[base + h*512] = ll;
  }
}

// x2 fp32 -> fp16 hi/lo split (one pass)
__global__ void k_splitx2(const float* __restrict__ x2, unsigned short* __restrict__ xh,
                          unsigned short* __restrict__ xl){
  int i = blockIdx.x * 256 + threadIdx.x;   // over (4096*2048)/4 float4s
  float4 v = ((const float4*)x2)[i];
  ushort4 h, l;
  split2h(v.x, h.x, l.x); split2h(v.y, h.y, l.y);
  split2h(v.z, h.z, l.z); split2h(v.w, h.w, l.w);
  ((ushort4*)xh)[i] = h;
  ((ushort4*)xl)[i] = l;
}

// x3[n,:] = lrelu( sum_e alpha[e,h]*H[src,:] + b2_h, 0.01 ), fp16 in/out. Block per dst node.
__global__ __launch_bounds__(256) void k_agg2b(const unsigned short* __restrict__ H,
                      const float* __restrict__ alpha,
                      const int* __restrict__ rowptr, const int* __restrict__ eids,
                      const int* __restrict__ ei, unsigned short* __restrict__ x3,
                      const float* __restrict__ b2, int h){
  int n = blockIdx.x, t = threadIdx.x;
  float acc[8] = {0,0,0,0,0,0,0,0};
  int b = rowptr[n], e = rowptr[n + 1];
  for (int j = b; j < e; ++j){
    int eid = eids[j];
    int s = (eid < Ne) ? ei[eid] : (eid - Ne);
    float a = alpha[(size_t)eid*4 + h];
    f16x8 hv = *(const f16x8*)&H[(size_t)s*2048 + t*8];
#pragma unroll
    for (int q = 0; q < 8; q++) acc[q] += a * (float)hv[q];
  }
  const float* bb = b2 + (size_t)h*2048 + t*8;
  ushort4 o0, o1;
  float4 b0 = *(const float4*)bb;
  float4 b1 = *(const float4*)(bb + 4);
  o0.x = f2h(lrelu(acc[0] + b0.x, 0.01f)); o0.y = f2h(lrelu(acc[1] + b0.y, 0.01f));
  o0.z = f2h(lrelu(acc[2] + b0.z, 0.01f)); o0.w = f2h(lrelu(acc[3] + b0.w, 0.01f));
  o1.x = f2h(lrelu(acc[4] + b1.x, 0.01f)); o1.y = f2h(lrelu(acc[5] + b1.y, 0.01f));
  o1.z = f2h(lrelu(acc[6] + b1.z, 0.01f)); o1.w = f2h(lrelu(acc[7] + b1.w, 0.01f));
  size_t base = (size_t)n*2048 + t*8;
  *(ushort4*)&x3[base]     = o0;
  *(ushort4*)&x3[base + 4] = o1;
}

// transpose + split: out[col][k] = split(W[k][coloff+col]); out stride K.
template<bool HALF, bool STORELO>
__global__ __launch_bounds__(256) void k_wsplit(const float* __restrict__ W, int ldw, int coloff, int K,
                       unsigned short* __restrict__ whi, unsigned short* __restrict__ wlo){
  __shared__ float tile[32][33];
  int bk = blockIdx.x * 32, bn = blockIdx.y * 32;
  int tx = threadIdx.x & 31, ty = threadIdx.x >> 5;
#pragma unroll
  for (int i = 0; i < 4; i++){
    int k = bk + ty + i*8;
    tile[ty + i*8][tx] = W[(size_t)k*ldw + coloff + bn + tx];
  }
  __syncthreads();
#pragma unroll
  for (int i = 0; i < 4; i++){
    int n = bn + ty + i*8;
    float v = tile[tx][ty + i*8];
    unsigned short hh, ll;
    if (HALF) split2h(v, hh, ll); else split2(v, hh, ll);
    whi[(size_t)n*K + bk + tx] = hh;
    if (STORELO) wlo[(size_t)n*K + bk + tx] = ll;
  }
}

// ---------------- L2 dense GEMM: H[4096][2048] = x2[4096][2048k] x W2h^T[2048n][2048k]
// fp16 2-term: C = Ah*Bh + Al*Bh. BM=128, BN=256, 8 waves, 2 phases x 16 MFMA per
// K-step(32), 3-buffer LDS (96KB), counted vmcnt(4). fp16 out.
// B bank-conflict fix (r9): phys chunk = logical ^ ((row>>1)&3) -> 8 distinct bank
// starts per 16 lanes (2-way, free). XCD-chunked block swizzle (T1): each XCD gets
// 4 contiguous row-panels -> A panel set fits its L2.
__global__ __launch_bounds__(512) void k_gemm256(
    const unsigned short* __restrict__ Ah, const unsigned short* __restrict__ Al,
    const unsigned short* __restrict__ Bh, unsigned short* __restrict__ Cout)
{
  __shared__ __align__(16) unsigned short lds[49152];   // 3 x (A 8192 + B 8192) ushorts
  const int t = threadIdx.x;
  // XCD-aware swizzle: grid 8x32 = 256 = 8 XCDs * 32. bid%8 = XCD (round-robin HW
  // assignment) -> give each XCD a contiguous 32-block chunk (4 row-panels x 8 cols).
  const int bid = blockIdx.y * 8 + blockIdx.x;
  const int sbid = (bid & 7) * 32 + (bid >> 3);
  const int brow = (sbid >> 3) * 128, bcol = (sbid & 7) * 256;
  const int w = t >> 6, lane = t & 63;
  const int wm = (w >> 2) * 64, wn = (w & 3) * 64;
  constexpr int BUF = 16384, BOFF = 8192;   // ushorts

  // A staging: row = i*64+(t>>3), phys chunk t&7, logical = phys^(row&7)
  const int asr = t >> 3;
  const int ascc = (t & 7) ^ (asr & 7);
  const unsigned short* asrc = (ascc < 4 ? Ah : Al) + (size_t)(brow + asr)*2048 + (size_t)(ascc & 3)*8;
  // B staging: row = i*128+(t>>2), phys chunk t&3, logical = phys^((row>>1)&3)
  const int bsr = t >> 2;
  const int bscc = (t & 3) ^ ((bsr >> 1) & 3);
  const unsigned short* bsrc = Bh + (size_t)(bcol + bsr)*2048 + (size_t)bscc*8;
  const int adst = w * 512;           // + buf*BUF + i*4096 (+ lane*16B implicit)
  const int bdst = BOFF + w * 512;

  // fragment read offsets (ushort units, within buffer)
  const int fr = lane & 15, kc = lane >> 4;
  const int aswz = (kc ^ (lane & 7)) * 8;
  const int bswz = (kc ^ ((lane >> 1) & 3)) * 8;   // row bits 1-2 = lane bits 1-2
  int aoff[4], boff[4];
#pragma unroll
  for (int m = 0; m < 4; m++) aoff[m] = (wm + m*16 + fr)*64 + aswz;
#pragma unroll
  for (int n = 0; n < 4; n++) boff[n] = BOFF + (wn + n*16 + fr)*32 + bswz;

  f32x4 acc[4][4];
#pragma unroll
  for (int m = 0; m < 4; m++)
#pragma unroll
    for (int n = 0; n < 4; n++) acc[m][n] = f32x4{0.f, 0.f, 0.f, 0.f};

  // prologue: stage tile 0 (buf0) FULLY FIRST, then tile 1 (buf1).
  // vmcnt counts oldest-first: vmcnt(4) => the 4 oldest (ALL of tile 0) complete.
  gload16(asrc,                        &lds[adst]);
  gload16(asrc + (size_t)64*2048,      &lds[4096 + adst]);
  gload16(bsrc,                        &lds[bdst]);
  gload16(bsrc + (size_t)128*2048,     &lds[4096 + bdst]);
  gload16(asrc + 32,                   &lds[BUF + adst]);
  gload16(asrc + (size_t)64*2048 + 32, &lds[BUF + 4096 + adst]);
  gload16(bsrc + 32,                   &lds[BUF + bdst]);
  gload16(bsrc + (size_t)128*2048 + 32,&lds[BUF + 4096 + bdst]);
  asm volatile("s_waitcnt vmcnt(4)" ::: "memory");   // tile 0 landed; tile 1 in flight
  __builtin_amdgcn_s_barrier();

  for (int kt = 0; kt < 64; ++kt){
    const int bufo = (kt % 3) * BUF;
    const int nbo  = ((kt + 2) % 3) * BUF;
    const size_t nko = (size_t)(kt + 2) * 32;
    const bool pf = (kt + 2) < 64;

    f16x8 ah[4], al[4];
    // ---- phase 0: A frags + B0,B1; prefetch A of tile kt+2
#pragma unroll
    for (int m = 0; m < 4; m++){
      ah[m] = *(const f16x8*)&lds[bufo + aoff[m]];
      al[m] = *(const f16x8*)&lds[bufo + (aoff[m] ^ 32)];
    }
    {
      f16x8 b0 = *(const f16x8*)&lds[bufo + boff[0]];
      f16x8 b1 = *(const f16x8*)&lds[bufo + boff[1]];
      if (pf){
        gload16(asrc + nko,                   &lds[nbo + adst]);
        gload16(asrc + (size_t)64*2048 + nko, &lds[nbo + 4096 + adst]);
      }
      __builtin_amdgcn_s_barrier();
      asm volatile("s_waitcnt lgkmcnt(0)");
      __builtin_amdgcn_s_setprio(1);
#pragma unroll
      for (int m = 0; m < 4; m++) acc[m][0] = __builtin_amdgcn_mfma_f32_16x16x32_f16(ah[m], b0, acc[m][0], 0, 0, 0);
#pragma unroll
      for (int m = 0; m < 4; m++) acc[m][0] = __builtin_amdgcn_mfma_f32_16x16x32_f16(al[m], b0, acc[m][0], 0, 0, 0);
#pragma unroll
      for (int m = 0; m < 4; m++) acc[m][1] = __builtin_amdgcn_mfma_f32_16x16x32_f16(ah[m], b1, acc[m][1], 0, 0, 0);
#pragma unroll
      for (int m = 0; m < 4; m++) acc[m][1] = __builtin_amdgcn_mfma_f32_16x16x32_f16(al[m], b1, acc[m][1], 0, 0, 0);
      __builtin_amdgcn_s_setprio(0);
      __builtin_amdgcn_s_barrier();
    }
    // ---- phase 1: B2,B3; prefetch B of tile kt+2
    {
      f16x8 b2 = *(const f16x8*)&lds[bufo + boff[2]];
      f16x8 b3 = *(const f16x8*)&lds[bufo + boff[3]];
      if (pf){
        gload16(bsrc + nko,                    &lds[nbo + bdst]);
        gload16(bsrc + (size_t)128*2048 + nko, &lds[nbo + 4096 + bdst]);
      }
      __builtin_amdgcn_s_barrier();
      asm volatile("s_waitcnt lgkmcnt(0)");
      __builtin_amdgcn_s_setprio(1);
#pragma unroll
      for (int m = 0; m < 4; m++) acc[m][2] = __builtin_amdgcn_mfma_f32_16x16x32_f16(ah[m], b2, acc[m][2], 0, 0, 0);
#pragma unroll
      for (int m = 0; m < 4; m++) acc[m][2] = __builtin_amdgcn_mfma_f32_16x16x32_f16(al[m], b2, acc[m][2], 0, 0, 0);
#pragma unroll
      for (int m = 0; m < 4; m++) acc[m][3] = __builtin_amdgcn_mfma_f32_16x16x32_f16(ah[m], b3, acc[m][3], 0, 0, 0);
#pragma unroll
      for (int m = 0; m < 4; m++) acc[m][3] = __builtin_amdgcn_mfma_f32_16x16x32_f16(al[m], b3, acc[m][3], 0, 0, 0);
      __builtin_amdgcn_s_setprio(0);
      __builtin_amdgcn_s_barrier();
    }
    // ---- end of K-step: tile kt+1 must be complete; keep tile kt+2's 4 loads in flight
    if (pf) asm volatile("s_waitcnt vmcnt(4)" ::: "memory");
    else    asm volatile("s_waitcnt vmcnt(0)" ::: "memory");
    __builtin_amdgcn_s_barrier();
  }

  // ---- epilogue: fp16 store. C/D frag: col=lane&15, row=(lane>>4)*4+reg
#pragma unroll
  for (int m = 0; m < 4; m++){
    const int row0 = brow + wm + m*16 + kc*4;
#pragma unroll
    for (int n = 0; n < 4; n++){
      const int col = bcol + wn + n*16 + fr;
#pragma unroll
      for (int r = 0; r < 4; r++)
        Cout[(size_t)(row0 + r)*2048 + col] = f2h(acc[m][n][r]);
    }
  }
}

// ---------------- MFMA GEMM (128x128): bf16 3-term, or fp16 exact-A 2-term ----------------
template<int KLEN, bool EXACTA, bool HALF, bool OUTF32, bool BETA1, bool ACT, bool HASBIAS>
__global__ __launch_bounds__(256) void k_gemm2(
    const unsigned short* __restrict__ Ah, const unsigned short* __restrict__ Al, int lda, size_t az,
    const unsigned short* __restrict__ Bh, const unsigned short* __restrict__ Bl, int ldb, size_t bz,
    void* __restrict__ Cout, int ldc, size_t cz,
    const float* __restrict__ bias, size_t biasz)
{
  __shared__ unsigned short lds[16384];   // A: [0,8192) ushorts, B: [8192,16384)
  const int t = threadIdx.x;
  const int z = blockIdx.z;
  const int brow = blockIdx.y * 128, bcol = blockIdx.x * 128;
  const int wid = t >> 6, lane = t & 63;
  const int wm = (wid >> 1) * 64, wn = (wid & 1) * 64;

  const int sr = t >> 3, sc = t & 7;
  const int scc = sc ^ (sr & 7);
  const unsigned short* asrc = (scc < 4 ? Ah : Al) + (size_t)(brow + sr)*lda + (size_t)z*az + (size_t)(scc & 3)*8;
  const unsigned short* bsrc = (scc < 4 ? Bh : Bl) + (size_t)(bcol + sr)*ldb + (size_t)z*bz + (size_t)(scc & 3)*8;
  unsigned short* adst = &lds[(size_t)wid * 512];
  unsigned short* bdst = &lds[8192 + (size_t)wid * 512];

  const int fr = lane & 15, kc = lane >> 4;
  const int swz = ((kc ^ (lane & 7)) << 3);
  int aoff[4], boff[4];
#pragma unroll
  for (int m = 0; m < 4; m++) aoff[m] = (wm + m*16 + fr)*64 + swz;
#pragma unroll
  for (int n = 0; n < 4; n++) boff[n] = 8192 + (wn + n*16 + fr)*64 + swz;

  f32x4 acc[4][4];
#pragma unroll
  for (int m = 0; m < 4; m++)
#pragma unroll
    for (int n = 0; n < 4; n++) acc[m][n] = f32x4{0.f, 0.f, 0.f, 0.f};

  for (int kt = 0; kt < KLEN/32; ++kt){
    const size_t ko = (size_t)kt * 32;
#pragma unroll
    for (int i = 0; i < 4; i++){
      gload16(asrc + (size_t)i*32*lda + ko, adst + i*2048);
      gload16(bsrc + (size_t)i*32*ldb + ko, bdst + i*2048);
    }
    __syncthreads();

    if (HALF){
      f16x8 ah[4], bh[4], bl[4];
#pragma unroll
      for (int m = 0; m < 4; m++) ah[m] = *(const f16x8*)&lds[aoff[m]];
#pragma unroll
      for (int n = 0; n < 4; n++){
        bh[n] = *(const f16x8*)&lds[boff[n]];
        bl[n] = *(const f16x8*)&lds[boff[n] ^ 32];
      }
#pragma unroll
      for (int m = 0; m < 4; m++)
#pragma unroll
        for (int n = 0; n < 4; n++){
          acc[m][n] = __builtin_amdgcn_mfma_f32_16x16x32_f16(ah[m], bh[n], acc[m][n], 0, 0, 0);
          acc[m][n] = __builtin_amdgcn_mfma_f32_16x16x32_f16(ah[m], bl[n], acc[m][n], 0, 0, 0);
        }
    } else {
      bf16x8 ah[4], al[4], bh[4], bl[4];
#pragma unroll
      for (int m = 0; m < 4; m++){
        ah[m] = *(const bf16x8*)&lds[aoff[m]];
        if (!EXACTA) al[m] = *(const bf16x8*)&lds[aoff[m] ^ 32];
      }
#pragma unroll
      for (int n = 0; n < 4; n++){
        bh[n] = *(const bf16x8*)&lds[boff[n]];
        bl[n] = *(const bf16x8*)&lds[boff[n] ^ 32];
      }
#pragma unroll
      for (int m = 0; m < 4; m++)
#pragma unroll
        for (int n = 0; n < 4; n++){
          acc[m][n] = __builtin_amdgcn_mfma_f32_16x16x32_bf16(ah[m], bh[n], acc[m][n], 0, 0, 0);
          acc[m][n] = __builtin_amdgcn_mfma_f32_16x16x32_bf16(ah[m], bl[n], acc[m][n], 0, 0, 0);
          if (!EXACTA)
            acc[m][n] = __builtin_amdgcn_mfma_f32_16x16x32_bf16(al[m], bh[n], acc[m][n], 0, 0, 0);
        }
    }
    __syncthreads();
  }

  float bv[4] = {0.f, 0.f, 0.f, 0.f};
  if (HASBIAS){
#pragma unroll
    for (int n = 0; n < 4; n++) bv[n] = bias[(size_t)z*biasz + bcol + wn + n*16 + fr];
  }
  float* Cf = (float*)Cout + (size_t)z*cz;
  unsigned short* Cb = (unsigned short*)Cout + (size_t)z*cz;
#pragma unroll
  for (int m = 0; m < 4; m++){
    const int row0 = brow + wm + m*16 + kc*4;
#pragma unroll
    for (int n = 0; n < 4; n++){
      const int col = bcol + wn + n*16 + fr;
#pragma unroll
      for (int r = 0; r < 4; r++){
        float v = acc[m][n][r] + bv[n];
        if (ACT) v = lrelu(v, 0.01f);
        if (OUTF32){
          float* cp = &Cf[(size_t)(row0 + r)*ldc + col];
          if (BETA1) v += *cp;
          *cp = v;
        } else {
          Cb[(size_t)(row0 + r)*ldc + col] = f2bf(v);
        }
      }
    }
  }
}

// stage 1: per (slice, graph) partial sums over stride-32 node slices
__global__ void k_gsum(const float* __restrict__ yp, const float* __restrict__ bout,
                       const int* __restrict__ batch, float* __restrict__ part){
  const int s = blockIdx.x, g = blockIdx.y, t = threadIdx.x;
  __shared__ int sb[2];
  if (t < 2){
    int key = g + t, lo = 0, hi = Nn;
    while (lo < hi){ int mid = (lo + hi) >> 1; if (batch[mid] < key) lo = mid + 1; else hi = mid; }
    sb[t] = lo;
  }
  __syncthreads();
  const int b = sb[0], e = sb[1];
  const size_t P = (size_t)Nn * 256;
  float acc = 0.f;
  float bt = bout[t];
  for (int n = b + s; n < e; n += 32){
    size_t i = (size_t)n*256 + t;
    float v = yp[i] + yp[P + i] + yp[2*P + i] + yp[3*P + i] + bt;
    acc += lrelu(v, 0.01f);
  }
  part[(size_t)(g*32 + s)*256 + t] = acc;
}

// stage 2: sum 32 slices, divide by count
__global__ void k_gfin(const float* __restrict__ part, const int* __restrict__ batch,
                       float* __restrict__ out){
  const int g = blockIdx.x, t = threadIdx.x;
  __shared__ int sb[2];
  if (t < 2){
    int key = g + t, lo = 0, hi = Nn;
    while (lo < hi){ int mid = (lo + hi) >> 1; if (batch[mid] < key) lo = mid + 1; else hi = mid; }
    sb[t] = lo;
  }
  __syncthreads();
  const int cnt = sb[1] - sb[0];
  float s = 0.f;
#pragma unroll
  for (int k = 0; k < 32; k++) s += part[(size_t)(g*32 + k)*256 + t];
  out[g*256 + t] = s / fmaxf((float)cnt, 1.f);
}

// ---------------- launch ----------------
extern "C" void kernel_launch(void* const* d_in, const int* in_sizes, int n_in,
                              void* d_out, int out_size, void* d_ws, size_t ws_size,
                              hipStream_t stream){
  const float* xg    = (const float*)d_in[0];
  const float* ac    = (const float*)d_in[1];
  const float* ti    = (const float*)d_in[2];
  const float* eattr = (const float*)d_in[3];
  const int*   ei    = (const int*)  d_in[4];
  const int*   batch = (const int*)  d_in[5];
  const float* W1    = (const float*)d_in[6];
  const float* as1w  = (const float*)d_in[7];
  const float* ad1w  = (const float*)d_in[8];
  const float* ae1w  = (const float*)d_in[9];
  const float* We1   = (const float*)d_in[10];
  const float* b1    = (const float*)d_in[11];
  const float* W2    = (const float*)d_in[12];
  const float* as2w  = (const float*)d_in[13];
  const float* ad2w  = (const float*)d_in[14];
  const float* ae2w  = (const float*)d_in[15];
  const float* We2   = (const float*)d_in[16];
  const float* b2    = (const float*)d_in[17];
  const float* Wout  = (const float*)d_in[18];
  const float* bout  = (const float*)d_in[19];
  float* out = (float*)d_out;
  float* ws  = (float*)d_ws;
  if (ws_size < WS_FLOATS * sizeof(float)) return;
  int* iws = (int*)(ws + OFF_I);

  unsigned short* z1hi = (unsigned short*)(ws + OFF_Z1HI);
  unsigned short* z1lo = (unsigned short*)(ws + OFF_Z1LO);
  unsigned short* wt1h = (unsigned short*)(ws + OFF_WT1H);
  unsigned short* wt1l = (unsigned short*)(ws + OFF_WT1L);
  unsigned short* x2hi = (unsigned short*)(ws + OFF_X2HI);
  unsigned short* x2lo = (unsigned short*)(ws + OFF_X2LO);
  unsigned short* whi  = (unsigned short*)(ws + OFF_X);
  unsigned short* woh  = (unsigned short*)(ws + OFF_WOH);
  unsigned short* wol  = (unsigned short*)(ws + OFF_WOL);
  unsigned short* Hb   = (unsigned short*)(ws + OFF_H);
  unsigned short* x3   = (unsigned short*)(ws + OFF_X3);

  hipMemsetAsync(iws + I_DEG, 0, Nn * sizeof(int), stream);
  k_concat <<<8192, 256, 0, stream>>>(xg, ac, ti, ws + OFF_X);
  k_count  <<<128,  256, 0, stream>>>(ei, iws + I_DEG);
  k_scan   <<<1,   1024, 0, stream>>>(iws + I_DEG, iws + I_RP, iws + I_CUR);
  k_fill   <<<144,  256, 0, stream>>>(ei, iws + I_CUR, iws + I_EID);
  k_sort   <<<16,   256, 0, stream>>>(iws + I_RP, iws + I_EID);
  k_loopattr<<<256, 256, 0, stream>>>(eattr, iws + I_RP, iws + I_EID, ws + OFF_LP);

  k_proj   <<<512,  256, 0, stream>>>(W1, as1w, ad1w, ws + OFF_WS1, ws + OFF_WD1, 512, 512);
  k_proj   <<<2048, 256, 0, stream>>>(W2, as2w, ad2w, ws + OFF_WS2, ws + OFF_WD2, 2048, 2048);
  k_aeproj <<<16,   256, 0, stream>>>(We1, ae1w, ws + OFF_AE1, 512);
  k_aeproj <<<16,   256, 0, stream>>>(We2, ae2w, ws + OFF_AE2, 2048);
  k_wsplit<true, true><<<dim3(256, 8), 256, 0, stream>>>(Wout, 256, 0, 8192, woh, wol);   // fp16 [256][8192]

  // ---- layer 1 (bf16 3-term, unchanged) ----
  k_asad      <<<4096, 256, 0, stream>>>(ws + OFF_X, ws + OFF_WS1, ws + OFF_WD1, ws + OFF_AS1, ws + OFF_AD1, 512);
  k_edge      <<<144,  256, 0, stream>>>(eattr, ws + OFF_LP, ei, ws + OFF_AS1, ws + OFF_AD1, ws + OFF_AE1, ws + OFF_EB);
  k_softmax   <<<1024, 256, 0, stream>>>(iws + I_RP, iws + I_EID, ws + OFF_EB, ws + OFF_AL);
  k_agg1_split<<<4096, 256, 0, stream>>>(ws + OFF_X, ws + OFF_AL, iws + I_RP, iws + I_EID, ei, z1hi, z1lo);
  // X dead; wt1 overlays it
  k_wsplit<false, true><<<dim3(16, 64), 256, 0, stream>>>(W1, 2048, 0, 512, wt1h, wt1l);  // bf16 [2048][512]
  k_gemm2<512, false, false, true, false, true, true><<<dim3(4, 32, 4), 256, 0, stream>>>(
      z1hi, z1lo, 2048, 512,  wt1h, wt1l, 512, 512*512,
      ws + OFF_X2, 2048, 512,  b1, 512);

  // ---- layer 2 attention ----
  k_asad   <<<4096, 256, 0, stream>>>(ws + OFF_X2, ws + OFF_WS2, ws + OFF_WD2, ws + OFF_AS2, ws + OFF_AD2, 2048);
  k_edge   <<<144,  256, 0, stream>>>(eattr, ws + OFF_LP, ei, ws + OFF_AS2, ws + OFF_AD2, ws + OFF_AE2, ws + OFF_EB);
  k_softmax<<<1024, 256, 0, stream>>>(iws + I_RP, iws + I_EID, ws + OFF_EB, ws + OFF_AL);

  // x2 fp32 -> fp16 hi/lo split (z1 regions dead); x2 fp32 dead afterwards
  k_splitx2<<<8192, 256, 0, stream>>>(ws + OFF_X2, x2hi, x2lo);

  // ---- layer 2 + fc, per head: H = x2@W2_h^T (fp16 MFMA), sparse agg of fp16 H, fp16 FC ----
  for (int h = 0; h < 4; ++h){
    k_wsplit<true, false><<<dim3(64, 64), 256, 0, stream>>>(W2, 8192, h*2048, 2048, whi, nullptr);
    k_gemm256 <<<dim3(8, 32), 512, 0, stream>>>(x2hi, x2lo, whi, Hb);
    k_agg2b   <<<4096, 256, 0, stream>>>(Hb, ws + OFF_AL, iws + I_RP, iws + I_EID, ei, x3, b2, h);
    if (h == 0)
      k_gemm2<512, true, true, true, false, false, false><<<dim3(2, 32, 4), 256, 0, stream>>>(
          x3, x3, 2048, 512,  woh + (size_t)h*2048, wol + (size_t)h*2048, 8192, 512,
          ws + OFF_YP, 256, (size_t)Nn*256,  nullptr, 0);
    else
      k_gemm2<512, true, true, true, true, false, false><<<dim3(2, 32, 4), 256, 0, stream>>>(
          x3, x3, 2048, 512,  woh + (size_t)h*2048, wol + (size_t)h*2048, 8192, 512,
          ws + OFF_YP, 256, (size_t)Nn*256,  nullptr, 0);
  }

  k_gsum<<<dim3(32, 8), 256, 0, stream>>>(ws + OFF_YP, bout, batch, ws + OFF_PART);
  k_gfin<<<8, 256, 0, stream>>>(ws + OFF_PART, batch, out);
}